// Round 1
// baseline (375.718 us; speedup 1.0000x reference)
//
#include <hip/hip_runtime.h>
#include <hip/hip_bf16.h>

#define D_MODEL 1024
#define NHEADS 16
#define HDIM 64
#define BATCH 8
#define SEQ 512
#define NROWS 4096          // BATCH*SEQ
#define SCALE 0.125f
#define LN_EPS 1e-5f

typedef __attribute__((ext_vector_type(8))) short bf16x8;      // 8 bf16 (4 VGPRs)
typedef __attribute__((ext_vector_type(4))) float f32x4;
typedef __attribute__((ext_vector_type(8))) unsigned short u16x8;

static __device__ __forceinline__ float bf2f(unsigned short u) {
    return __uint_as_float(((unsigned int)u) << 16);
}
static __device__ __forceinline__ unsigned short f2bf(float f) {
    unsigned int x = __float_as_uint(f);
    unsigned int r = (x + 0x7fffu + ((x >> 16) & 1u)) >> 16;   // RNE
    return (unsigned short)r;
}

// async 16B/lane global->LDS DMA; LDS dest = wave-uniform base + lane*16
#define GLOAD16(gp, lp)                                                        \
    __builtin_amdgcn_global_load_lds(                                          \
        (const __attribute__((address_space(1))) void*)(gp),                   \
        (__attribute__((address_space(3))) void*)(lp), 16, 0, 0)

// ---------------------------------------------------------------------------
// Bias helper: jax.image.resize(bias128, (512,512), 'bilinear')
// ---------------------------------------------------------------------------
static __device__ __forceinline__ float bias128(int a, int b) {
    float d = fabsf((float)(a - b));
    return expf(-d * 0.1f) - d * 0.05f;
}

// ---------------------------------------------------------------------------
// prep_kernel: fused LN (blocks 0..8191) + bias table (8192..9215) +
// Wqkv convert (9216..12287) + [hoisted Wout/Wgate convert (12288..14335)]
// ---------------------------------------------------------------------------
__global__ void prep_kernel(const float* __restrict__ dec, const float* __restrict__ enc,
                            const float* __restrict__ gamma, const float* __restrict__ beta,
                            const float* __restrict__ Wqkv,
                            const float* __restrict__ Wout, const float* __restrict__ Wgate,
                            unsigned short* __restrict__ q_ln, unsigned short* __restrict__ kv_ln,
                            float* __restrict__ bias, unsigned short* __restrict__ Wqkv_bf,
                            unsigned short* __restrict__ Wout_bf, unsigned short* __restrict__ Wgate_bf) {
    int blk = blockIdx.x;
    int t = threadIdx.x;
    if (blk >= 12288) {         // hoisted Wout/Wgate convert (only when launched)
        int idx = (blk - 12288) * 256 + t;
        const float* src; unsigned short* dst; int off;
        if (idx < 262144) { src = Wout; dst = Wout_bf; off = idx; }
        else              { src = Wgate; dst = Wgate_bf; off = idx - 262144; }
        float4 v = ((const float4*)src)[off];
        ushort4 u;
        u.x = f2bf(v.x); u.y = f2bf(v.y); u.z = f2bf(v.z); u.w = f2bf(v.w);
        ((ushort4*)dst)[off] = u;
        return;
    }
    if (blk >= 9216) {          // Wqkv convert
        int idx = (blk - 9216) * 256 + t;
        float4 v = ((const float4*)Wqkv)[idx];
        ushort4 u;
        u.x = f2bf(v.x); u.y = f2bf(v.y); u.z = f2bf(v.z); u.w = f2bf(v.w);
        ((ushort4*)Wqkv_bf)[idx] = u;
        return;
    }
    if (blk >= 8192) {          // bias
        int idx = (blk - 8192) * 256 + t;
        int qi = idx >> 9, kj = idx & 511;
        float fq = (qi + 0.5f) * 0.25f - 0.5f;
        float fk = (kj + 0.5f) * 0.25f - 0.5f;
        int iq = (int)floorf(fq); float tq = fq - (float)iq;
        int ik = (int)floorf(fk); float tk = fk - (float)ik;
        int iq0 = min(max(iq, 0), 127), iq1 = min(max(iq + 1, 0), 127);
        int ik0 = min(max(ik, 0), 127), ik1 = min(max(ik + 1, 0), 127);
        float v = (1.f - tq) * ((1.f - tk) * bias128(iq0, ik0) + tk * bias128(iq0, ik1))
                +        tq  * ((1.f - tk) * bias128(iq1, ik0) + tk * bias128(iq1, ik1));
        bias[idx] = v;
        return;
    }
    int row = blk;
    const float* src = (row < NROWS) ? dec + (size_t)row * D_MODEL
                                     : enc + (size_t)(row - NROWS) * D_MODEL;
    unsigned short* dst = (row < NROWS) ? q_ln + (size_t)row * D_MODEL
                                        : kv_ln + (size_t)(row - NROWS) * D_MODEL;
    float4 x = ((const float4*)src)[t];
    float s  = x.x + x.y + x.z + x.w;
    float ss = x.x * x.x + x.y * x.y + x.z * x.z + x.w * x.w;
    #pragma unroll
    for (int off = 32; off > 0; off >>= 1) {
        s  += __shfl_down(s, off);
        ss += __shfl_down(ss, off);
    }
    __shared__ float red_s[4], red_ss[4];
    int wid = t >> 6, lane = t & 63;
    if (lane == 0) { red_s[wid] = s; red_ss[wid] = ss; }
    __syncthreads();
    if (t == 0) {
        float S = red_s[0] + red_s[1] + red_s[2] + red_s[3];
        float SS = red_ss[0] + red_ss[1] + red_ss[2] + red_ss[3];
        red_s[0] = S; red_ss[0] = SS;
    }
    __syncthreads();
    float mu  = red_s[0] * (1.0f / 1024.0f);
    float var = red_ss[0] * (1.0f / 1024.0f) - mu * mu;
    float rstd = rsqrtf(var + LN_EPS);
    float4 g = ((const float4*)gamma)[t];
    float4 bb = ((const float4*)beta)[t];
    ushort4 u;
    u.x = f2bf((x.x - mu) * rstd * g.x + bb.x);
    u.y = f2bf((x.y - mu) * rstd * g.y + bb.y);
    u.z = f2bf((x.z - mu) * rstd * g.z + bb.z);
    u.w = f2bf((x.w - mu) * rstd * g.w + bb.w);
    ((ushort4*)dst)[t] = u;
}

// ---------------------------------------------------------------------------
// Wout + Wgate fp32 -> bf16 (fallback path when ws too small to hoist)
// ---------------------------------------------------------------------------
__global__ void convert_og(const float* __restrict__ Wout, const float* __restrict__ Wgate,
                           unsigned short* __restrict__ Wout_bf, unsigned short* __restrict__ Wgate_bf) {
    int idx = blockIdx.x * 256 + threadIdx.x;
    const float* src; unsigned short* dst; int off;
    if (idx < 262144) { src = (const float*)Wout; dst = Wout_bf; off = idx; }
    else              { src = (const float*)Wgate; dst = Wgate_bf; off = idx - 262144; }
    float4 v = ((const float4*)src)[off];
    ushort4 u;
    u.x = f2bf(v.x); u.y = f2bf(v.y); u.z = f2bf(v.z); u.w = f2bf(v.w);
    ((ushort4*)dst)[off] = u;
}

// ===========================================================================
// MFMA GEMM cores (bf16).
// out_gemm1/2: 64x128 tile, BK=128 (unchanged this round).
// qkv: NEW 128x128 tile, BK=64 (m97 structure, verified 912 TF at 4k^3):
//   4 waves, each owns 64x64 (4x4 16x16x32 fragments), 2 K-halves per step,
//   global_load_lds 16B staging with XOR swizzle (conflict-free reads).
// ===========================================================================
#define CSTR 136   // C-bounce row stride (multiple of 8 -> 16B-aligned rows)

struct alignas(16) Smem64B {
    unsigned short A[64 * 128];     // 16 KB
    unsigned short B[128 * 128];    // 32 KB
};

#define MF(a, b, d) __builtin_amdgcn_mfma_f32_16x16x32_bf16((a), (b), (d), 0, 0, 0)

#define GEMM_KH2B(kh)                                                          \
    {                                                                          \
        int pofs = (((kh) * 4 + quad) ^ c) * 8;                                \
        const unsigned short* Arow_ = &As2[(wr * 32 + c) * 128 + pofs];        \
        const unsigned short* Brow_ = &Bs2[(wc * 64 + c) * 128 + pofs];        \
        bf16x8 f0 = *(const bf16x8*)(Arow_);                                   \
        bf16x8 f1 = *(const bf16x8*)(Arow_ + 2048);                            \
        bf16x8 g0 = *(const bf16x8*)(Brow_);                                   \
        bf16x8 g1 = *(const bf16x8*)(Brow_ + 2048);                            \
        bf16x8 g2 = *(const bf16x8*)(Brow_ + 4096);                            \
        bf16x8 g3 = *(const bf16x8*)(Brow_ + 6144);                            \
        c00 = MF(f0, g0, c00); c01 = MF(f0, g1, c01); c02 = MF(f0, g2, c02); c03 = MF(f0, g3, c03); \
        c10 = MF(f1, g0, c10); c11 = MF(f1, g1, c11); c12 = MF(f1, g2, c12); c13 = MF(f1, g3, c13); \
    }

#define GEMM_BODY_64B(Aptr, Bptr)                                              \
    int wave = tid >> 6, lane = tid & 63, quad = lane >> 4, c = lane & 15;     \
    int wr = wave >> 1, wc = wave & 1;                                         \
    int l4 = lane >> 4, l15 = lane & 15;                                       \
    const unsigned short* Abase = (Aptr) + (size_t)(rt * 64) * 1024;           \
    const unsigned short* Bbase = (Bptr) + (size_t)(ct * 128) * 1024;          \
    int aoff0 = (wave * 16 +  0 + l4) * 1024 + ((l15 ^ ( 0 + l4)) * 8);        \
    int aoff1 = (wave * 16 +  4 + l4) * 1024 + ((l15 ^ ( 4 + l4)) * 8);        \
    int aoff2 = (wave * 16 +  8 + l4) * 1024 + ((l15 ^ ( 8 + l4)) * 8);        \
    int aoff3 = (wave * 16 + 12 + l4) * 1024 + ((l15 ^ (12 + l4)) * 8);        \
    int boff0 = (wave * 32 +  0 + l4) * 1024 + ((l15 ^ (( 0 + l4) & 15)) * 8); \
    int boff1 = (wave * 32 +  4 + l4) * 1024 + ((l15 ^ (( 4 + l4) & 15)) * 8); \
    int boff2 = (wave * 32 +  8 + l4) * 1024 + ((l15 ^ (( 8 + l4) & 15)) * 8); \
    int boff3 = (wave * 32 + 12 + l4) * 1024 + ((l15 ^ ((12 + l4) & 15)) * 8); \
    int boff4 = (wave * 32 + 16 + l4) * 1024 + ((l15 ^ ((16 + l4) & 15)) * 8); \
    int boff5 = (wave * 32 + 20 + l4) * 1024 + ((l15 ^ ((20 + l4) & 15)) * 8); \
    int boff6 = (wave * 32 + 24 + l4) * 1024 + ((l15 ^ ((24 + l4) & 15)) * 8); \
    int boff7 = (wave * 32 + 28 + l4) * 1024 + ((l15 ^ ((28 + l4) & 15)) * 8); \
    unsigned short* AsW = As2 + wave * 2048;                                   \
    unsigned short* BsW = Bs2 + wave * 4096;                                   \
    f32x4 c00 = (f32x4)0.f, c01 = (f32x4)0.f, c02 = (f32x4)0.f, c03 = (f32x4)0.f; \
    f32x4 c10 = (f32x4)0.f, c11 = (f32x4)0.f, c12 = (f32x4)0.f, c13 = (f32x4)0.f; \
    for (int kt = 0; kt < 8; ++kt) {                                           \
        int k0 = kt * 128;                                                     \
        __syncthreads();                                                       \
        GLOAD16(Abase + aoff0 + k0, AsW);                                      \
        GLOAD16(Abase + aoff1 + k0, AsW + 512);                                \
        GLOAD16(Abase + aoff2 + k0, AsW + 1024);                               \
        GLOAD16(Abase + aoff3 + k0, AsW + 1536);                               \
        GLOAD16(Bbase + boff0 + k0, BsW);                                      \
        GLOAD16(Bbase + boff1 + k0, BsW + 512);                                \
        GLOAD16(Bbase + boff2 + k0, BsW + 1024);                               \
        GLOAD16(Bbase + boff3 + k0, BsW + 1536);                               \
        GLOAD16(Bbase + boff4 + k0, BsW + 2048);                               \
        GLOAD16(Bbase + boff5 + k0, BsW + 2560);                               \
        GLOAD16(Bbase + boff6 + k0, BsW + 3072);                               \
        GLOAD16(Bbase + boff7 + k0, BsW + 3584);                               \
        __syncthreads();                                                       \
        GEMM_KH2B(0)                                                           \
        GEMM_KH2B(1)                                                           \
        GEMM_KH2B(2)                                                           \
        GEMM_KH2B(3)                                                           \
    }

// ---------------------------------------------------------------------------
// QKV GEMM: 128x128 tile, BK=64 (m97 structure) + fused RoPE epilogue.
// Q/K: (B,H,L,64) layout.  V: transposed (B,H,64,L) layout.
// Grid 768 (1-D) = 32 rt x 24 ct; XCD swizzle (768%8==0, bijective) +
// 4rt x 8ct super-tiles (A 1MB + B 2MB per group -> fits 4MB XCD L2).
// LDS: A[128][64] + B[128][64] = 32 KB, unioned with 34 KB C-bounce.
// ---------------------------------------------------------------------------
union alignas(16) SmemQ2 {
    struct { unsigned short A[128 * 64]; unsigned short B[128 * 64]; } ab;  // 32 KB
    unsigned short C[128 * CSTR];   // q/k RoPE bounce rows x 136, or v bounce [d=128][l=128]
};

__global__ __launch_bounds__(256, 1)
void qkv_gemm_mfma(const unsigned short* __restrict__ q_ln,
                   const unsigned short* __restrict__ kv_ln,
                   const unsigned short* __restrict__ Wb,
                   unsigned short* __restrict__ qo,
                   unsigned short* __restrict__ ko,
                   unsigned short* __restrict__ vo) {
    int bid = blockIdx.x;               // 0..767
    int wg = (bid & 7) * 96 + (bid >> 3);   // XCD-aware swizzle
    int g = wg >> 5, idx = wg & 31;         // 24 super-tiles of 32 blocks
    int ctg = g % 3, rtg = g / 3;           // ctg 0..2, rtg 0..7
    int ct = ctg * 8 + (idx & 7);           // 0..23
    int rt = rtg * 4 + (idx >> 3);          // 0..31
    int n0 = ct * 128;
    int section = n0 >> 10;                 // 0=q 1=k 2=v
    const unsigned short* A = (section == 0) ? q_ln : kv_ln;

    __shared__ SmemQ2 smem;
    unsigned short* As2 = smem.ab.A;
    unsigned short* Bs2 = smem.ab.B;
    int tid = threadIdx.x;
    int wave = tid >> 6, lane = tid & 63, quad = lane >> 4, c = lane & 15;
    int wr = wave >> 1, wc = wave & 1;
    int x7 = c & 7;

    const unsigned short* Abase = A + (size_t)(rt * 128) * 1024;
    const unsigned short* Bbase = Wb + (size_t)n0 * 1024;
    // staging: element e = q*256+tid -> row e>>3, slot e&7 holds global chunk
    // (slot ^ (row&7)); row&7 invariant across rounds (rows step by 32).
    int off0 = (tid >> 3) * 1024 + (((tid & 7) ^ ((tid >> 3) & 7)) * 8);
    unsigned short* AsW = As2 + wave * 512;
    unsigned short* BsW = Bs2 + wave * 512;

    f32x4 acc[4][4];
    #pragma unroll
    for (int i = 0; i < 4; ++i)
        #pragma unroll
        for (int j = 0; j < 4; ++j) acc[i][j] = (f32x4)0.f;

    for (int kt = 0; kt < 16; ++kt) {
        int k0 = kt * 64;
        __syncthreads();
        GLOAD16(Abase + off0 +     0 + k0, AsW);
        GLOAD16(Abase + off0 + 32768 + k0, AsW + 2048);
        GLOAD16(Abase + off0 + 65536 + k0, AsW + 4096);
        GLOAD16(Abase + off0 + 98304 + k0, AsW + 6144);
        GLOAD16(Bbase + off0 +     0 + k0, BsW);
        GLOAD16(Bbase + off0 + 32768 + k0, BsW + 2048);
        GLOAD16(Bbase + off0 + 65536 + k0, BsW + 4096);
        GLOAD16(Bbase + off0 + 98304 + k0, BsW + 6144);
        __syncthreads();
        #pragma unroll
        for (int kh = 0; kh < 2; ++kh) {
            int pofs = ((kh * 4 + quad) ^ x7) * 8;
            const unsigned short* Ar = As2 + (wr * 64 + c) * 64 + pofs;
            const unsigned short* Br = Bs2 + (wc * 64 + c) * 64 + pofs;
            bf16x8 a0 = *(const bf16x8*)(Ar);
            bf16x8 a1 = *(const bf16x8*)(Ar + 1024);
            bf16x8 a2 = *(const bf16x8*)(Ar + 2048);
            bf16x8 a3 = *(const bf16x8*)(Ar + 3072);
            bf16x8 b0 = *(const bf16x8*)(Br);
            bf16x8 b1 = *(const bf16x8*)(Br + 1024);
            bf16x8 b2 = *(const bf16x8*)(Br + 2048);
            bf16x8 b3 = *(const bf16x8*)(Br + 3072);
            acc[0][0] = MF(a0, b0, acc[0][0]); acc[0][1] = MF(a0, b1, acc[0][1]);
            acc[0][2] = MF(a0, b2, acc[0][2]); acc[0][3] = MF(a0, b3, acc[0][3]);
            acc[1][0] = MF(a1, b0, acc[1][0]); acc[1][1] = MF(a1, b1, acc[1][1]);
            acc[1][2] = MF(a1, b2, acc[1][2]); acc[1][3] = MF(a1, b3, acc[1][3]);
            acc[2][0] = MF(a2, b0, acc[2][0]); acc[2][1] = MF(a2, b1, acc[2][1]);
            acc[2][2] = MF(a2, b2, acc[2][2]); acc[2][3] = MF(a2, b3, acc[2][3]);
            acc[3][0] = MF(a3, b0, acc[3][0]); acc[3][1] = MF(a3, b1, acc[3][1]);
            acc[3][2] = MF(a3, b2, acc[3][2]); acc[3][3] = MF(a3, b3, acc[3][3]);
        }
    }

    __syncthreads();                    // all waves done reading As/Bs (union reuse)

    if (section == 2) {
        // V: bounce transposed — C[d_tile 0..127][l_local 0..127], stride CSTR
        #pragma unroll
        for (int i = 0; i < 4; ++i)
            #pragma unroll
            for (int j = 0; j < 4; ++j)
                #pragma unroll
                for (int r = 0; r < 4; ++r)
                    smem.C[(wc * 64 + j * 16 + c) * CSTR + (wr * 64 + i * 16 + quad * 4 + r)]
                        = f2bf(acc[i][j][r]);
        __syncthreads();
        int dr = tid >> 1, hh = tid & 1;    // dr 0..127 d-row; hh = l half
        int h = ((n0 & 1023) >> 6) + (dr >> 6);
        int d = dr & 63;
        int m0 = rt * 128;
        int bb = m0 >> 9, ll0 = (m0 & 511) + hh * 64;
        unsigned short* orow = vo + (((size_t)bb * NHEADS + h) * HDIM + d) * SEQ + ll0;
        const unsigned short* csrc = &smem.C[dr * CSTR + hh * 64];
        #pragma unroll
        for (int kc = 0; kc < 8; ++kc)
            *(u16x8*)(orow + kc * 8) = *(const u16x8*)(csrc + kc * 8);
        return;
    }

    // q/k: fused RoPE. Wave's 64-col span == one head; even half j=0/1, odd j=2/3.
    float inv0 = expf(-0.2878231366f * (float)c);          // 10000^(-c/32)
    float inv1 = expf(-0.2878231366f * (float)(16 + c));
    #pragma unroll
    for (int i = 0; i < 4; ++i)
        #pragma unroll
        for (int r = 0; r < 4; ++r) {
            int mloc = wr * 64 + i * 16 + quad * 4 + r;
            float fl = (float)((rt * 128 + mloc) & 511);
            float a0 = fl * inv0, a1 = fl * inv1;
            float c0 = cosf(a0), s0 = sinf(a0);
            float c1 = cosf(a1), s1 = sinf(a1);
            float e0 = acc[i][0][r], o0 = acc[i][2][r];
            float e1 = acc[i][1][r], o1 = acc[i][3][r];
            int crow = mloc * CSTR + wc * 64;
            smem.C[crow + c]      = f2bf(e0 * c0 - o0 * s0);
            smem.C[crow + 32 + c] = f2bf(e0 * s0 + o0 * c0);
            smem.C[crow + 16 + c] = f2bf(e1 * c1 - o1 * s1);
            smem.C[crow + 48 + c] = f2bf(e1 * s1 + o1 * c1);
        }
    __syncthreads();

    unsigned short* outp = (section == 0) ? qo : ko;
    int rr = tid >> 1;                  // row 0..127
    int ch = tid & 1;                   // head within tile
    int mm = rt * 128 + rr;
    int bb = mm >> 9, ll = mm & 511;
    int h = ((n0 & 1023) >> 6) + ch;
    unsigned short* orow = outp + (((size_t)bb * NHEADS + h) * SEQ + ll) * HDIM;
    const unsigned short* csrc = &smem.C[rr * CSTR + ch * 64];
    #pragma unroll
    for (int kc = 0; kc < 8; ++kc)
        *(u16x8*)(orow + kc * 8) = *(const u16x8*)(csrc + kc * 8);
}

// ---------------------------------------------------------------------------
// Projection 1 (MFMA, 64x128 tile, BK=128): t = att @ Wout^T + b_out -> bf16
// grid (8, 64) = 512 blocks
// ---------------------------------------------------------------------------
#define O1_REG(mb, reg, n, Acc)                                                \
    t_bf[(size_t)((mb) + (reg)) * 1024 + (n)] = f2bf(Acc[(reg)] + bo);
#define O1_TILE(i, j, Acc)                                                     \
    {                                                                          \
        int n = ct * 128 + wc * 64 + (j) * 16 + c;                             \
        float bo = b_out[n];                                                   \
        int mb = rt * 64 + wr * 32 + (i) * 16 + quad * 4;                      \
        O1_REG(mb, 0, n, Acc) O1_REG(mb, 1, n, Acc)                            \
        O1_REG(mb, 2, n, Acc) O1_REG(mb, 3, n, Acc)                            \
    }

__global__ __launch_bounds__(256, 1)
void out_gemm1_mfma(const unsigned short* __restrict__ att,
                    const unsigned short* __restrict__ Wob,
                    const float* __restrict__ b_out,
                    unsigned short* __restrict__ t_bf) {
    int ct = blockIdx.x, rt = blockIdx.y;
    __shared__ Smem64B smem2;
    unsigned short* As2 = smem2.A;
    unsigned short* Bs2 = smem2.B;
    int tid = threadIdx.x;

    GEMM_BODY_64B(att, Wob)

    O1_TILE(0, 0, c00) O1_TILE(0, 1, c01) O1_TILE(0, 2, c02) O1_TILE(0, 3, c03)
    O1_TILE(1, 0, c10) O1_TILE(1, 1, c11) O1_TILE(1, 2, c12) O1_TILE(1, 3, c13)
}

// ---------------------------------------------------------------------------
// Projection 2 (MFMA, 64x128 tile, BK=128): gz = t_bf @ Wgate^T + b_gate;
// out = sigmoid(gz)*t + (1-sigmoid)*residual   (t read back as bf16)
// ---------------------------------------------------------------------------
#define O2_REG(mb, reg, n, Acc)                                                \
    {                                                                          \
        float gz = Acc[(reg)] + bg;                                            \
        float g = 1.0f / (1.0f + expf(-gz));                                   \
        size_t idx = (size_t)((mb) + (reg)) * 1024 + (n);                      \
        float tv = bf2f(t_bf[idx]);                                            \
        float rv = residual[idx];                                              \
        out[idx] = g * tv + (1.0f - g) * rv;                                   \
    }
#define O2_TILE(i, j, Acc)                                                     \
    {                                                                          \
        int n = ct * 128 + wc * 64 + (j) * 16 + c;                             \
        float bg = b_gate[n];                                                  \
        int mb = rt * 64 + wr * 32 + (i) * 16 + quad * 4;                      \
        O2_REG(mb, 0, n, Acc) O2_REG(mb, 1, n, Acc)                            \
        O2_REG(mb, 2, n, Acc) O2_REG(mb, 3, n, Acc)                            \
    }

__global__ __launch_bounds__(256, 1)
void out_gemm2_mfma(const unsigned short* __restrict__ t_bf,
                    const unsigned short* __restrict__ Wgb,
                    const float* __restrict__ b_gate,
                    const float* __restrict__ residual,
                    float* __restrict__ out) {
    int ct = blockIdx.x, rt = blockIdx.y;
    __shared__ Smem64B smem2;
    unsigned short* As2 = smem2.A;
    unsigned short* Bs2 = smem2.B;
    int tid = threadIdx.x;

    GEMM_BODY_64B(t_bf, Wgb)

    O2_TILE(0, 0, c00) O2_TILE(0, 1, c01) O2_TILE(0, 2, c02) O2_TILE(0, 3, c03)
    O2_TILE(1, 0, c10) O2_TILE(1, 1, c11) O2_TILE(1, 2, c12) O2_TILE(1, 3, c13)
}

// ---------------------------------------------------------------------------
// Flash attention, bf16 MFMA (16x16x32). 128-row Q tile, 8 waves.
// R12: unnormalized streaming softmax (scores bounded: |s| < ~10).
// R15: K and Vt staged via global_load_lds w/ XOR swizzle (V pre-transposed
// in global by qkv) — no scalar transpose stores, no staging VGPR roundtrip.
// LDS rows 64 shorts, 8 slots; row r slot s holds chunk s^(r&7).
// ---------------------------------------------------------------------------
#define KSTR 72   // Ps stride only

__global__ __launch_bounds__(512)
void attn_kernel(const unsigned short* __restrict__ q,
                 const unsigned short* __restrict__ k,
                 const unsigned short* __restrict__ vt,
                 const float* __restrict__ bias,
                 unsigned short* __restrict__ attended) {
    int qt = blockIdx.x, h = blockIdx.y, b = blockIdx.z;
    __shared__ unsigned short Ks[64 * 64];
    __shared__ unsigned short Vs[64 * 64];
    __shared__ unsigned short Ps[128 * KSTR];
    __shared__ float lf[128];

    int tid = threadIdx.x;
    int wave = tid >> 6, lane = tid & 63;   // wave 0..7
    int quad = lane >> 4, c = lane & 15;
    int wb = wave * 16;                     // wave's q-row base, 0..112
    size_t headbase = (((size_t)b * NHEADS + h) * SEQ) * HDIM;  // == (b*16+h)*32768
    int q0 = qt * 128;

    const unsigned short* qrow = q + headbase + (size_t)(q0 + wb + c) * HDIM;
    bf16x8 aq0 = *(const bf16x8*)(qrow + quad * 8);
    bf16x8 aq1 = *(const bf16x8*)(qrow + 32 + quad * 8);

    // staging: wave w covers rows w*8..w*8+7 (8 rows x 64 shorts = 1 GLOAD16/lane)
    int srow = wave * 8 + (lane >> 3);
    int schunk = (lane & 7) ^ (srow & 7);
    unsigned short* KsW = Ks + wave * 512;
    unsigned short* VsW = Vs + wave * 512;
    const unsigned short* kgb = k + headbase + (size_t)srow * HDIM + schunk * 8;
    const unsigned short* vgb = vt + headbase + (size_t)srow * SEQ + schunk * 8;
    int x7 = c & 7;
    int p0 = (quad ^ x7) * 8;
    int p1 = ((4 + quad) ^ x7) * 8;

    f32x4 oacc[4];
    #pragma unroll
    for (int t = 0; t < 4; ++t) oacc[t] = (f32x4)0.f;
    float lrow[4];
    #pragma unroll
    for (int r = 0; r < 4; ++r) lrow[r] = 0.f;

    for (int kt = 0; kt < 8; ++kt) {
        int kv0 = kt * 64;
        __syncthreads();
        GLOAD16(kgb + (size_t)kv0 * HDIM, KsW);   // K rows kv0+srow
        GLOAD16(vgb + kv0, VsW);                  // Vt rows d=srow, cols kv0+
        __syncthreads();

        f32x4 sacc[4];
        #pragma unroll
        for (int nt = 0; nt < 4; ++nt) {
            const unsigned short* kbase = &Ks[(nt * 16 + c) * 64];
            bf16x8 b0 = *(const bf16x8*)(kbase + p0);
            bf16x8 b1 = *(const bf16x8*)(kbase + p1);
            f32x4 a = (f32x4)0.f;
            a = __builtin_amdgcn_mfma_f32_16x16x32_bf16(aq0, b0, a, 0, 0, 0);
            a = __builtin_amdgcn_mfma_f32_16x16x32_bf16(aq1, b1, a, 0, 0, 0);
            sacc[nt] = a;
        }

        const float* bbase = bias + (size_t)(q0 + wb + quad * 4) * 512 + kv0 + c;
        float tsum[4];
        #pragma unroll
        for (int r = 0; r < 4; ++r) tsum[r] = 0.f;
        #pragma unroll
        for (int nt = 0; nt < 4; ++nt)
            #pragma unroll
            for (int r = 0; r < 4; ++r) {
                float p = __expf(sacc[nt][r] * SCALE + bbase[(size_t)r * 512 + nt * 16]);
                tsum[r] += p;
                Ps[(wb + quad * 4 + r) * KSTR + nt * 16 + c] = f2bf(p);
            }
        #pragma unroll
        for (int r = 0; r < 4; ++r) {
            float t = tsum[r];
            t += __shfl_xor(t, 1);
            t += __shfl_xor(t, 2);
            t += __shfl_xor(t, 4);
            t += __shfl_xor(t, 8);
            lrow[r] += t;
        }

        bf16x8 pb0 = *(const bf16x8*)&Ps[(wb + c) * KSTR + quad * 8];
        bf16x8 pb1 = *(const bf16x8*)&Ps[(wb + c) * KSTR + 32 + quad * 8];
        #pragma unroll
        for (int t = 0; t < 4; ++t) {
            const unsigned short* vbase = &Vs[(t * 16 + c) * 64];
            bf16x8 a0 = *(const bf16x8*)(vbase + p0);
            bf16x8 a1 = *(const bf16x8*)(vbase + p1);
            oacc[t] = __builtin_amdgcn_mfma_f32_16x16x32_bf16(a0, pb0, oacc[t], 0, 0, 0);
            oacc[t] = __builtin_amdgcn_mfma_f32_16x16x32_bf16(a1, pb1, oacc[t], 0, 0, 0);
        }
    }

    if (c == 0) {
        f32x4 lv;
        lv[0] = lrow[0]; lv[1] = lrow[1]; lv[2] = lrow[2]; lv[3] = lrow[3];
        *(f32x4*)&lf[wb + quad * 4] = lv;
    }
    float invl = 1.0f / lf[wb + c];
    unsigned short* drow = attended + ((size_t)b * SEQ + (q0 + wb + c)) * D_MODEL + h * HDIM;
    #pragma unroll
    for (int t = 0; t < 4; ++t) {
        ushort4 o;
        o.x = f2bf(oacc[t][0] * invl);
        o.y = f2bf(oacc[t][1] * invl);
        o.z = f2bf(oacc[t][2] * invl);
        o.w = f2bf(oacc[t][3] * invl);
        *(ushort4*)(drow + t * 16 + quad * 4) = o;
    }
}

extern "C" void kernel_launch(void* const* d_in, const int* in_sizes, int n_in,
                              void* d_out, int out_size, void* d_ws, size_t ws_size,
                              hipStream_t stream) {
    const float* dec    = (const float*)d_in[0];
    const float* enc    = (const float*)d_in[1];
    const float* Wqkv   = (const float*)d_in[2];
    const float* Wout   = (const float*)d_in[3];
    const float* b_out  = (const float*)d_in[4];
    const float* Wgate  = (const float*)d_in[5];
    const float* b_gate = (const float*)d_in[6];
    const float* gamma  = (const float*)d_in[7];
    const float* beta   = (const float*)d_in[8];
    float* out = (float*)d_out;

    char* ws = (char*)d_ws;
    const size_t MB = 1024 * 1024;
    unsigned short* q_ln    = (unsigned short*)(ws + 0 * MB);
    unsigned short* kv_ln   = (unsigned short*)(ws + 8 * MB);
    unsigned short* qb      = (unsigned short*)(ws + 16 * MB);
    unsigned short* kb      = (unsigned short*)(ws + 24 * MB);
    unsigned short* vb      = (unsigned short*)(ws + 32 * MB);   // V^T (B,H,64,L)
    unsigned short* Wqkv_bf = (unsigned short*)(ws + 40 * MB);
    float*          bias    = (float*)(ws + 46 * MB);
    unsigned short* att     = (unsigned short*)(ws + 0 * MB);    // q_ln dead after qkv
    unsigned short* t_bf    = (unsigned short*)(ws + 24 * MB);   // kb dead after attn

    // Hoisted weight-convert needs 4 MB of never-aliased space at 47..51 MB.
    bool hoist = (ws_size >= 51 * MB);
    unsigned short* Wout_bf  = (unsigned short*)(ws + (hoist ? 47 * MB : 32 * MB));
    unsigned short* Wgate_bf = (unsigned short*)(ws + (hoist ? 49 * MB : 34 * MB));

    prep_kernel<<<hoist ? 14336 : 12288, 256, 0, stream>>>(
        dec, enc, gamma, beta, Wqkv, Wout, Wgate,
        q_ln, kv_ln, bias, Wqkv_bf, Wout_bf, Wgate_bf);
    qkv_gemm_mfma<<<768, 256, 0, stream>>>(q_ln, kv_ln, Wqkv_bf, qb, kb, vb);
    attn_kernel<<<dim3(4, 16, 8), 512, 0, stream>>>(qb, kb, vb, bias, att);
    if (!hoist)
        convert_og<<<2048, 256, 0, stream>>>(Wout, Wgate, Wout_bf, Wgate_bf);
    out_gemm1_mfma<<<dim3(8, 64), 256, 0, stream>>>(att, Wout_bf, b_out, t_bf);
    out_gemm2_mfma<<<dim3(8, 64), 256, 0, stream>>>(t_bf, Wgate_bf, b_gate, dec, out);
}

// Round 3
// 232.633 us; speedup vs baseline: 1.6151x; 1.6151x over previous
//
#include <hip/hip_runtime.h>
#include <hip/hip_bf16.h>

#define D_MODEL 1024
#define NHEADS 16
#define HDIM 64
#define BATCH 8
#define SEQ 512
#define NROWS 4096          // BATCH*SEQ
#define SCALE 0.125f
#define LN_EPS 1e-5f

typedef __attribute__((ext_vector_type(8))) short bf16x8;      // 8 bf16 (4 VGPRs)
typedef __attribute__((ext_vector_type(4))) float f32x4;
typedef __attribute__((ext_vector_type(8))) unsigned short u16x8;

static __device__ __forceinline__ float bf2f(unsigned short u) {
    return __uint_as_float(((unsigned int)u) << 16);
}
static __device__ __forceinline__ unsigned short f2bf(float f) {
    unsigned int x = __float_as_uint(f);
    unsigned int r = (x + 0x7fffu + ((x >> 16) & 1u)) >> 16;   // RNE
    return (unsigned short)r;
}

// async 16B/lane global->LDS DMA; LDS dest = wave-uniform base + lane*16
#define GLOAD16(gp, lp)                                                        \
    __builtin_amdgcn_global_load_lds(                                          \
        (const __attribute__((address_space(1))) void*)(gp),                   \
        (__attribute__((address_space(3))) void*)(lp), 16, 0, 0)

// ---------------------------------------------------------------------------
// Bias helper: jax.image.resize(bias128, (512,512), 'bilinear')
// ---------------------------------------------------------------------------
static __device__ __forceinline__ float bias128(int a, int b) {
    float d = fabsf((float)(a - b));
    return expf(-d * 0.1f) - d * 0.05f;
}

// ---------------------------------------------------------------------------
// prep_kernel: fused LN (blocks 0..8191) + bias table (8192..9215) +
// Wqkv convert (9216..12287) + [hoisted Wout/Wgate convert (12288..14335)]
// ---------------------------------------------------------------------------
__global__ void prep_kernel(const float* __restrict__ dec, const float* __restrict__ enc,
                            const float* __restrict__ gamma, const float* __restrict__ beta,
                            const float* __restrict__ Wqkv,
                            const float* __restrict__ Wout, const float* __restrict__ Wgate,
                            unsigned short* __restrict__ q_ln, unsigned short* __restrict__ kv_ln,
                            float* __restrict__ bias, unsigned short* __restrict__ Wqkv_bf,
                            unsigned short* __restrict__ Wout_bf, unsigned short* __restrict__ Wgate_bf) {
    int blk = blockIdx.x;
    int t = threadIdx.x;
    if (blk >= 12288) {         // hoisted Wout/Wgate convert (only when launched)
        int idx = (blk - 12288) * 256 + t;
        const float* src; unsigned short* dst; int off;
        if (idx < 262144) { src = Wout; dst = Wout_bf; off = idx; }
        else              { src = Wgate; dst = Wgate_bf; off = idx - 262144; }
        float4 v = ((const float4*)src)[off];
        ushort4 u;
        u.x = f2bf(v.x); u.y = f2bf(v.y); u.z = f2bf(v.z); u.w = f2bf(v.w);
        ((ushort4*)dst)[off] = u;
        return;
    }
    if (blk >= 9216) {          // Wqkv convert
        int idx = (blk - 9216) * 256 + t;
        float4 v = ((const float4*)Wqkv)[idx];
        ushort4 u;
        u.x = f2bf(v.x); u.y = f2bf(v.y); u.z = f2bf(v.z); u.w = f2bf(v.w);
        ((ushort4*)Wqkv_bf)[idx] = u;
        return;
    }
    if (blk >= 8192) {          // bias
        int idx = (blk - 8192) * 256 + t;
        int qi = idx >> 9, kj = idx & 511;
        float fq = (qi + 0.5f) * 0.25f - 0.5f;
        float fk = (kj + 0.5f) * 0.25f - 0.5f;
        int iq = (int)floorf(fq); float tq = fq - (float)iq;
        int ik = (int)floorf(fk); float tk = fk - (float)ik;
        int iq0 = min(max(iq, 0), 127), iq1 = min(max(iq + 1, 0), 127);
        int ik0 = min(max(ik, 0), 127), ik1 = min(max(ik + 1, 0), 127);
        float v = (1.f - tq) * ((1.f - tk) * bias128(iq0, ik0) + tk * bias128(iq0, ik1))
                +        tq  * ((1.f - tk) * bias128(iq1, ik0) + tk * bias128(iq1, ik1));
        bias[idx] = v;
        return;
    }
    int row = blk;
    const float* src = (row < NROWS) ? dec + (size_t)row * D_MODEL
                                     : enc + (size_t)(row - NROWS) * D_MODEL;
    unsigned short* dst = (row < NROWS) ? q_ln + (size_t)row * D_MODEL
                                        : kv_ln + (size_t)(row - NROWS) * D_MODEL;
    float4 x = ((const float4*)src)[t];
    float s  = x.x + x.y + x.z + x.w;
    float ss = x.x * x.x + x.y * x.y + x.z * x.z + x.w * x.w;
    #pragma unroll
    for (int off = 32; off > 0; off >>= 1) {
        s  += __shfl_down(s, off);
        ss += __shfl_down(ss, off);
    }
    __shared__ float red_s[4], red_ss[4];
    int wid = t >> 6, lane = t & 63;
    if (lane == 0) { red_s[wid] = s; red_ss[wid] = ss; }
    __syncthreads();
    if (t == 0) {
        float S = red_s[0] + red_s[1] + red_s[2] + red_s[3];
        float SS = red_ss[0] + red_ss[1] + red_ss[2] + red_ss[3];
        red_s[0] = S; red_ss[0] = SS;
    }
    __syncthreads();
    float mu  = red_s[0] * (1.0f / 1024.0f);
    float var = red_ss[0] * (1.0f / 1024.0f) - mu * mu;
    float rstd = rsqrtf(var + LN_EPS);
    float4 g = ((const float4*)gamma)[t];
    float4 bb = ((const float4*)beta)[t];
    ushort4 u;
    u.x = f2bf((x.x - mu) * rstd * g.x + bb.x);
    u.y = f2bf((x.y - mu) * rstd * g.y + bb.y);
    u.z = f2bf((x.z - mu) * rstd * g.z + bb.z);
    u.w = f2bf((x.w - mu) * rstd * g.w + bb.w);
    ((ushort4*)dst)[t] = u;
}

// ---------------------------------------------------------------------------
// Wout + Wgate fp32 -> bf16 (fallback path when ws too small to hoist)
// ---------------------------------------------------------------------------
__global__ void convert_og(const float* __restrict__ Wout, const float* __restrict__ Wgate,
                           unsigned short* __restrict__ Wout_bf, unsigned short* __restrict__ Wgate_bf) {
    int idx = blockIdx.x * 256 + threadIdx.x;
    const float* src; unsigned short* dst; int off;
    if (idx < 262144) { src = (const float*)Wout; dst = Wout_bf; off = idx; }
    else              { src = (const float*)Wgate; dst = Wgate_bf; off = idx - 262144; }
    float4 v = ((const float4*)src)[off];
    ushort4 u;
    u.x = f2bf(v.x); u.y = f2bf(v.y); u.z = f2bf(v.z); u.w = f2bf(v.w);
    ((ushort4*)dst)[off] = u;
}

// ===========================================================================
// MFMA GEMM cores (bf16).
// out_gemm1/2: 64x128 tile, BK=128 (unchanged).
// qkv: 128x128 tile, BK=64 (m97 structure). R16 (this session): accumulators
// MUST be named scalars (R7) — f32x4 acc[4][4] array spilled to scratch
// (WRITE_SIZE 24MB->780MB, MfmaUtil 19%->0.2%, 4.5x regression).
// ===========================================================================
#define CSTR 136   // C-bounce row stride (multiple of 8 -> 16B-aligned rows)

struct alignas(16) Smem64B {
    unsigned short A[64 * 128];     // 16 KB
    unsigned short B[128 * 128];    // 32 KB
};

#define MF(a, b, d) __builtin_amdgcn_mfma_f32_16x16x32_bf16((a), (b), (d), 0, 0, 0)

#define GEMM_KH2B(kh)                                                          \
    {                                                                          \
        int pofs = (((kh) * 4 + quad) ^ c) * 8;                                \
        const unsigned short* Arow_ = &As2[(wr * 32 + c) * 128 + pofs];        \
        const unsigned short* Brow_ = &Bs2[(wc * 64 + c) * 128 + pofs];        \
        bf16x8 f0 = *(const bf16x8*)(Arow_);                                   \
        bf16x8 f1 = *(const bf16x8*)(Arow_ + 2048);                            \
        bf16x8 g0 = *(const bf16x8*)(Brow_);                                   \
        bf16x8 g1 = *(const bf16x8*)(Brow_ + 2048);                            \
        bf16x8 g2 = *(const bf16x8*)(Brow_ + 4096);                            \
        bf16x8 g3 = *(const bf16x8*)(Brow_ + 6144);                            \
        c00 = MF(f0, g0, c00); c01 = MF(f0, g1, c01); c02 = MF(f0, g2, c02); c03 = MF(f0, g3, c03); \
        c10 = MF(f1, g0, c10); c11 = MF(f1, g1, c11); c12 = MF(f1, g2, c12); c13 = MF(f1, g3, c13); \
    }

#define GEMM_BODY_64B(Aptr, Bptr)                                              \
    int wave = tid >> 6, lane = tid & 63, quad = lane >> 4, c = lane & 15;     \
    int wr = wave >> 1, wc = wave & 1;                                         \
    int l4 = lane >> 4, l15 = lane & 15;                                       \
    const unsigned short* Abase = (Aptr) + (size_t)(rt * 64) * 1024;           \
    const unsigned short* Bbase = (Bptr) + (size_t)(ct * 128) * 1024;          \
    int aoff0 = (wave * 16 +  0 + l4) * 1024 + ((l15 ^ ( 0 + l4)) * 8);        \
    int aoff1 = (wave * 16 +  4 + l4) * 1024 + ((l15 ^ ( 4 + l4)) * 8);        \
    int aoff2 = (wave * 16 +  8 + l4) * 1024 + ((l15 ^ ( 8 + l4)) * 8);        \
    int aoff3 = (wave * 16 + 12 + l4) * 1024 + ((l15 ^ (12 + l4)) * 8);        \
    int boff0 = (wave * 32 +  0 + l4) * 1024 + ((l15 ^ (( 0 + l4) & 15)) * 8); \
    int boff1 = (wave * 32 +  4 + l4) * 1024 + ((l15 ^ (( 4 + l4) & 15)) * 8); \
    int boff2 = (wave * 32 +  8 + l4) * 1024 + ((l15 ^ (( 8 + l4) & 15)) * 8); \
    int boff3 = (wave * 32 + 12 + l4) * 1024 + ((l15 ^ ((12 + l4) & 15)) * 8); \
    int boff4 = (wave * 32 + 16 + l4) * 1024 + ((l15 ^ ((16 + l4) & 15)) * 8); \
    int boff5 = (wave * 32 + 20 + l4) * 1024 + ((l15 ^ ((20 + l4) & 15)) * 8); \
    int boff6 = (wave * 32 + 24 + l4) * 1024 + ((l15 ^ ((24 + l4) & 15)) * 8); \
    int boff7 = (wave * 32 + 28 + l4) * 1024 + ((l15 ^ ((28 + l4) & 15)) * 8); \
    unsigned short* AsW = As2 + wave * 2048;                                   \
    unsigned short* BsW = Bs2 + wave * 4096;                                   \
    f32x4 c00 = (f32x4)0.f, c01 = (f32x4)0.f, c02 = (f32x4)0.f, c03 = (f32x4)0.f; \
    f32x4 c10 = (f32x4)0.f, c11 = (f32x4)0.f, c12 = (f32x4)0.f, c13 = (f32x4)0.f; \
    for (int kt = 0; kt < 8; ++kt) {                                           \
        int k0 = kt * 128;                                                     \
        __syncthreads();                                                       \
        GLOAD16(Abase + aoff0 + k0, AsW);                                      \
        GLOAD16(Abase + aoff1 + k0, AsW + 512);                                \
        GLOAD16(Abase + aoff2 + k0, AsW + 1024);                               \
        GLOAD16(Abase + aoff3 + k0, AsW + 1536);                               \
        GLOAD16(Bbase + boff0 + k0, BsW);                                      \
        GLOAD16(Bbase + boff1 + k0, BsW + 512);                                \
        GLOAD16(Bbase + boff2 + k0, BsW + 1024);                               \
        GLOAD16(Bbase + boff3 + k0, BsW + 1536);                               \
        GLOAD16(Bbase + boff4 + k0, BsW + 2048);                               \
        GLOAD16(Bbase + boff5 + k0, BsW + 2560);                               \
        GLOAD16(Bbase + boff6 + k0, BsW + 3072);                               \
        GLOAD16(Bbase + boff7 + k0, BsW + 3584);                               \
        __syncthreads();                                                       \
        GEMM_KH2B(0)                                                           \
        GEMM_KH2B(1)                                                           \
        GEMM_KH2B(2)                                                           \
        GEMM_KH2B(3)                                                           \
    }

// ---------------------------------------------------------------------------
// QKV GEMM: 128x128 tile, BK=64 (m97 structure) + fused RoPE epilogue.
// Q/K: (B,H,L,64) layout.  V: transposed (B,H,64,L) layout.
// Grid 768 (1-D) = 32 rt x 24 ct; XCD swizzle (768%8==0, bijective) +
// 4rt x 8ct super-tiles (A 1MB + B 2MB per group -> fits 4MB XCD L2).
// LDS: A[128][64] + B[128][64] = 32 KB, unioned with 34 KB C-bounce.
// 16 NAMED f32x4 accumulators (R7/R16) — never an array.
// ---------------------------------------------------------------------------
union alignas(16) SmemQ2 {
    struct { unsigned short A[128 * 64]; unsigned short B[128 * 64]; } ab;  // 32 KB
    unsigned short C[128 * CSTR];   // q/k RoPE bounce rows x 136, or v bounce [d=128][l=128]
};

// one K-half (K=32) of the 128x128 wave-stage: 8 fragment loads + 16 MFMA
#define QKV_KH(kh)                                                             \
    {                                                                          \
        int pofs = (((kh) * 4 + quad) ^ x7) * 8;                               \
        const unsigned short* Ar_ = As2 + (wr * 64 + c) * 64 + pofs;           \
        const unsigned short* Br_ = Bs2 + (wc * 64 + c) * 64 + pofs;           \
        bf16x8 a0 = *(const bf16x8*)(Ar_);                                     \
        bf16x8 a1 = *(const bf16x8*)(Ar_ + 1024);                              \
        bf16x8 a2 = *(const bf16x8*)(Ar_ + 2048);                              \
        bf16x8 a3 = *(const bf16x8*)(Ar_ + 3072);                              \
        bf16x8 b0 = *(const bf16x8*)(Br_);                                     \
        bf16x8 b1 = *(const bf16x8*)(Br_ + 1024);                              \
        bf16x8 b2 = *(const bf16x8*)(Br_ + 2048);                              \
        bf16x8 b3 = *(const bf16x8*)(Br_ + 3072);                              \
        q00 = MF(a0, b0, q00); q01 = MF(a0, b1, q01); q02 = MF(a0, b2, q02); q03 = MF(a0, b3, q03); \
        q10 = MF(a1, b0, q10); q11 = MF(a1, b1, q11); q12 = MF(a1, b2, q12); q13 = MF(a1, b3, q13); \
        q20 = MF(a2, b0, q20); q21 = MF(a2, b1, q21); q22 = MF(a2, b2, q22); q23 = MF(a2, b3, q23); \
        q30 = MF(a3, b0, q30); q31 = MF(a3, b1, q31); q32 = MF(a3, b2, q32); q33 = MF(a3, b3, q33); \
    }

// V epilogue: bounce transposed — C[d 0..127][l_local 0..127], stride CSTR
#define QV_REG(i, j, reg, Acc)                                                 \
    smem.C[(wc * 64 + (j) * 16 + c) * CSTR + (wr * 64 + (i) * 16 + quad * 4 + (reg))] = f2bf(Acc[(reg)]);
#define QV_TILE(i, j, Acc)                                                     \
    QV_REG(i, j, 0, Acc) QV_REG(i, j, 1, Acc)                                  \
    QV_REG(i, j, 2, Acc) QV_REG(i, j, 3, Acc)

// RoPE epilogue: A0/A1 = even-half cols (d=c / d=16+c), A2/A3 odd-half
#define QR_REG(i, reg, A0, A1, A2, A3)                                         \
    {                                                                          \
        int mloc = wr * 64 + (i) * 16 + quad * 4 + (reg);                      \
        int crow = mloc * CSTR + wc * 64;                                      \
        float fl = (float)((rt * 128 + mloc) & 511);                           \
        float aa0 = fl * inv0, aa1 = fl * inv1;                                \
        float cc0 = cosf(aa0), ss0 = sinf(aa0);                                \
        float cc1 = cosf(aa1), ss1 = sinf(aa1);                                \
        float e0 = A0[(reg)], o0 = A2[(reg)];                                  \
        float e1 = A1[(reg)], o1 = A3[(reg)];                                  \
        smem.C[crow + c]      = f2bf(e0 * cc0 - o0 * ss0);                     \
        smem.C[crow + 32 + c] = f2bf(e0 * ss0 + o0 * cc0);                     \
        smem.C[crow + 16 + c] = f2bf(e1 * cc1 - o1 * ss1);                     \
        smem.C[crow + 48 + c] = f2bf(e1 * ss1 + o1 * cc1);                     \
    }
#define QR_ROW(i, A0, A1, A2, A3)                                              \
    QR_REG(i, 0, A0, A1, A2, A3) QR_REG(i, 1, A0, A1, A2, A3)                  \
    QR_REG(i, 2, A0, A1, A2, A3) QR_REG(i, 3, A0, A1, A2, A3)

__global__ __launch_bounds__(256, 1)
void qkv_gemm_mfma(const unsigned short* __restrict__ q_ln,
                   const unsigned short* __restrict__ kv_ln,
                   const unsigned short* __restrict__ Wb,
                   unsigned short* __restrict__ qo,
                   unsigned short* __restrict__ ko,
                   unsigned short* __restrict__ vo) {
    int bid = blockIdx.x;               // 0..767
    int wg = (bid & 7) * 96 + (bid >> 3);   // XCD-aware swizzle
    int g = wg >> 5, idx = wg & 31;         // 24 super-tiles of 32 blocks
    int ctg = g % 3, rtg = g / 3;           // ctg 0..2, rtg 0..7
    int ct = ctg * 8 + (idx & 7);           // 0..23
    int rt = rtg * 4 + (idx >> 3);          // 0..31
    int n0 = ct * 128;
    int section = n0 >> 10;                 // 0=q 1=k 2=v
    const unsigned short* A = (section == 0) ? q_ln : kv_ln;

    __shared__ SmemQ2 smem;
    unsigned short* As2 = smem.ab.A;
    unsigned short* Bs2 = smem.ab.B;
    int tid = threadIdx.x;
    int wave = tid >> 6, lane = tid & 63, quad = lane >> 4, c = lane & 15;
    int wr = wave >> 1, wc = wave & 1;
    int x7 = c & 7;

    const unsigned short* Abase = A + (size_t)(rt * 128) * 1024;
    const unsigned short* Bbase = Wb + (size_t)n0 * 1024;
    // staging: element e = g*2048 + wave*512 + lane*8 -> LDS row e>>6, slot (e>>3)&7;
    // global src chunk = slot ^ (row&7); row&7 invariant across g (rows step by 32).
    int off0 = (tid >> 3) * 1024 + (((tid & 7) ^ ((tid >> 3) & 7)) * 8);
    unsigned short* AsW = As2 + wave * 512;
    unsigned short* BsW = Bs2 + wave * 512;

    f32x4 q00 = (f32x4)0.f, q01 = (f32x4)0.f, q02 = (f32x4)0.f, q03 = (f32x4)0.f;
    f32x4 q10 = (f32x4)0.f, q11 = (f32x4)0.f, q12 = (f32x4)0.f, q13 = (f32x4)0.f;
    f32x4 q20 = (f32x4)0.f, q21 = (f32x4)0.f, q22 = (f32x4)0.f, q23 = (f32x4)0.f;
    f32x4 q30 = (f32x4)0.f, q31 = (f32x4)0.f, q32 = (f32x4)0.f, q33 = (f32x4)0.f;

    for (int kt = 0; kt < 16; ++kt) {
        int k0 = kt * 64;
        __syncthreads();
        GLOAD16(Abase + off0 +     0 + k0, AsW);
        GLOAD16(Abase + off0 + 32768 + k0, AsW + 2048);
        GLOAD16(Abase + off0 + 65536 + k0, AsW + 4096);
        GLOAD16(Abase + off0 + 98304 + k0, AsW + 6144);
        GLOAD16(Bbase + off0 +     0 + k0, BsW);
        GLOAD16(Bbase + off0 + 32768 + k0, BsW + 2048);
        GLOAD16(Bbase + off0 + 65536 + k0, BsW + 4096);
        GLOAD16(Bbase + off0 + 98304 + k0, BsW + 6144);
        __syncthreads();
        QKV_KH(0)
        QKV_KH(1)
    }

    __syncthreads();                    // all waves done reading As/Bs (union reuse)

    if (section == 2) {
        QV_TILE(0, 0, q00) QV_TILE(0, 1, q01) QV_TILE(0, 2, q02) QV_TILE(0, 3, q03)
        QV_TILE(1, 0, q10) QV_TILE(1, 1, q11) QV_TILE(1, 2, q12) QV_TILE(1, 3, q13)
        QV_TILE(2, 0, q20) QV_TILE(2, 1, q21) QV_TILE(2, 2, q22) QV_TILE(2, 3, q23)
        QV_TILE(3, 0, q30) QV_TILE(3, 1, q31) QV_TILE(3, 2, q32) QV_TILE(3, 3, q33)
        __syncthreads();
        int dr = tid >> 1, hh = tid & 1;    // dr 0..127 d-row; hh = l half
        int h = ((n0 & 1023) >> 6) + (dr >> 6);
        int d = dr & 63;
        int m0 = rt * 128;
        int bb = m0 >> 9, ll0 = (m0 & 511) + hh * 64;
        unsigned short* orow = vo + (((size_t)bb * NHEADS + h) * HDIM + d) * SEQ + ll0;
        const unsigned short* csrc = &smem.C[dr * CSTR + hh * 64];
        #pragma unroll
        for (int kc = 0; kc < 8; ++kc)
            *(u16x8*)(orow + kc * 8) = *(const u16x8*)(csrc + kc * 8);
        return;
    }

    // q/k: fused RoPE. Wave's 64-col span == one head; even half j=0/1, odd j=2/3.
    float inv0 = expf(-0.2878231366f * (float)c);          // 10000^(-c/32)
    float inv1 = expf(-0.2878231366f * (float)(16 + c));
    QR_ROW(0, q00, q01, q02, q03)
    QR_ROW(1, q10, q11, q12, q13)
    QR_ROW(2, q20, q21, q22, q23)
    QR_ROW(3, q30, q31, q32, q33)
    __syncthreads();

    unsigned short* outp = (section == 0) ? qo : ko;
    int rr = tid >> 1;                  // row 0..127
    int ch = tid & 1;                   // head within tile
    int mm = rt * 128 + rr;
    int bb = mm >> 9, ll = mm & 511;
    int h = ((n0 & 1023) >> 6) + ch;
    unsigned short* orow = outp + (((size_t)bb * NHEADS + h) * SEQ + ll) * HDIM;
    const unsigned short* csrc = &smem.C[rr * CSTR + ch * 64];
    #pragma unroll
    for (int kc = 0; kc < 8; ++kc)
        *(u16x8*)(orow + kc * 8) = *(const u16x8*)(csrc + kc * 8);
}

// ---------------------------------------------------------------------------
// Projection 1 (MFMA, 64x128 tile, BK=128): t = att @ Wout^T + b_out -> bf16
// grid (8, 64) = 512 blocks
// ---------------------------------------------------------------------------
#define O1_REG(mb, reg, n, Acc)                                                \
    t_bf[(size_t)((mb) + (reg)) * 1024 + (n)] = f2bf(Acc[(reg)] + bo);
#define O1_TILE(i, j, Acc)                                                     \
    {                                                                          \
        int n = ct * 128 + wc * 64 + (j) * 16 + c;                             \
        float bo = b_out[n];                                                   \
        int mb = rt * 64 + wr * 32 + (i) * 16 + quad * 4;                      \
        O1_REG(mb, 0, n, Acc) O1_REG(mb, 1, n, Acc)                            \
        O1_REG(mb, 2, n, Acc) O1_REG(mb, 3, n, Acc)                            \
    }

__global__ __launch_bounds__(256, 1)
void out_gemm1_mfma(const unsigned short* __restrict__ att,
                    const unsigned short* __restrict__ Wob,
                    const float* __restrict__ b_out,
                    unsigned short* __restrict__ t_bf) {
    int ct = blockIdx.x, rt = blockIdx.y;
    __shared__ Smem64B smem2;
    unsigned short* As2 = smem2.A;
    unsigned short* Bs2 = smem2.B;
    int tid = threadIdx.x;

    GEMM_BODY_64B(att, Wob)

    O1_TILE(0, 0, c00) O1_TILE(0, 1, c01) O1_TILE(0, 2, c02) O1_TILE(0, 3, c03)
    O1_TILE(1, 0, c10) O1_TILE(1, 1, c11) O1_TILE(1, 2, c12) O1_TILE(1, 3, c13)
}

// ---------------------------------------------------------------------------
// Projection 2 (MFMA, 64x128 tile, BK=128): gz = t_bf @ Wgate^T + b_gate;
// out = sigmoid(gz)*t + (1-sigmoid)*residual   (t read back as bf16)
// ---------------------------------------------------------------------------
#define O2_REG(mb, reg, n, Acc)                                                \
    {                                                                          \
        float gz = Acc[(reg)] + bg;                                            \
        float g = 1.0f / (1.0f + expf(-gz));                                   \
        size_t idx = (size_t)((mb) + (reg)) * 1024 + (n);                      \
        float tv = bf2f(t_bf[idx]);                                            \
        float rv = residual[idx];                                              \
        out[idx] = g * tv + (1.0f - g) * rv;                                   \
    }
#define O2_TILE(i, j, Acc)                                                     \
    {                                                                          \
        int n = ct * 128 + wc * 64 + (j) * 16 + c;                             \
        float bg = b_gate[n];                                                  \
        int mb = rt * 64 + wr * 32 + (i) * 16 + quad * 4;                      \
        O2_REG(mb, 0, n, Acc) O2_REG(mb, 1, n, Acc)                            \
        O2_REG(mb, 2, n, Acc) O2_REG(mb, 3, n, Acc)                            \
    }

__global__ __launch_bounds__(256, 1)
void out_gemm2_mfma(const unsigned short* __restrict__ t_bf,
                    const unsigned short* __restrict__ Wgb,
                    const float* __restrict__ b_gate,
                    const float* __restrict__ residual,
                    float* __restrict__ out) {
    int ct = blockIdx.x, rt = blockIdx.y;
    __shared__ Smem64B smem2;
    unsigned short* As2 = smem2.A;
    unsigned short* Bs2 = smem2.B;
    int tid = threadIdx.x;

    GEMM_BODY_64B(t_bf, Wgb)

    O2_TILE(0, 0, c00) O2_TILE(0, 1, c01) O2_TILE(0, 2, c02) O2_TILE(0, 3, c03)
    O2_TILE(1, 0, c10) O2_TILE(1, 1, c11) O2_TILE(1, 2, c12) O2_TILE(1, 3, c13)
}

// ---------------------------------------------------------------------------
// Flash attention, bf16 MFMA (16x16x32). 128-row Q tile, 8 waves.
// R12: unnormalized streaming softmax (scores bounded: |s| < ~10).
// R15: K and Vt staged via global_load_lds w/ XOR swizzle (V pre-transposed
// in global by qkv) — no scalar transpose stores, no staging VGPR roundtrip.
// LDS rows 64 shorts, 8 slots; row r slot s holds chunk s^(r&7).
// ---------------------------------------------------------------------------
#define KSTR 72   // Ps stride only

__global__ __launch_bounds__(512)
void attn_kernel(const unsigned short* __restrict__ q,
                 const unsigned short* __restrict__ k,
                 const unsigned short* __restrict__ vt,
                 const float* __restrict__ bias,
                 unsigned short* __restrict__ attended) {
    int qt = blockIdx.x, h = blockIdx.y, b = blockIdx.z;
    __shared__ unsigned short Ks[64 * 64];
    __shared__ unsigned short Vs[64 * 64];
    __shared__ unsigned short Ps[128 * KSTR];
    __shared__ float lf[128];

    int tid = threadIdx.x;
    int wave = tid >> 6, lane = tid & 63;   // wave 0..7
    int quad = lane >> 4, c = lane & 15;
    int wb = wave * 16;                     // wave's q-row base, 0..112
    size_t headbase = (((size_t)b * NHEADS + h) * SEQ) * HDIM;  // == (b*16+h)*32768
    int q0 = qt * 128;

    const unsigned short* qrow = q + headbase + (size_t)(q0 + wb + c) * HDIM;
    bf16x8 aq0 = *(const bf16x8*)(qrow + quad * 8);
    bf16x8 aq1 = *(const bf16x8*)(qrow + 32 + quad * 8);

    // staging: wave w covers rows w*8..w*8+7 (8 rows x 64 shorts = 1 GLOAD16/lane)
    int srow = wave * 8 + (lane >> 3);
    int schunk = (lane & 7) ^ (srow & 7);
    unsigned short* KsW = Ks + wave * 512;
    unsigned short* VsW = Vs + wave * 512;
    const unsigned short* kgb = k + headbase + (size_t)srow * HDIM + schunk * 8;
    const unsigned short* vgb = vt + headbase + (size_t)srow * SEQ + schunk * 8;
    int x7 = c & 7;
    int p0 = (quad ^ x7) * 8;
    int p1 = ((4 + quad) ^ x7) * 8;

    f32x4 oacc[4];
    #pragma unroll
    for (int t = 0; t < 4; ++t) oacc[t] = (f32x4)0.f;
    float lrow[4];
    #pragma unroll
    for (int r = 0; r < 4; ++r) lrow[r] = 0.f;

    for (int kt = 0; kt < 8; ++kt) {
        int kv0 = kt * 64;
        __syncthreads();
        GLOAD16(kgb + (size_t)kv0 * HDIM, KsW);   // K rows kv0+srow
        GLOAD16(vgb + kv0, VsW);                  // Vt rows d=srow, cols kv0+
        __syncthreads();

        f32x4 sacc[4];
        #pragma unroll
        for (int nt = 0; nt < 4; ++nt) {
            const unsigned short* kbase = &Ks[(nt * 16 + c) * 64];
            bf16x8 b0 = *(const bf16x8*)(kbase + p0);
            bf16x8 b1 = *(const bf16x8*)(kbase + p1);
            f32x4 a = (f32x4)0.f;
            a = __builtin_amdgcn_mfma_f32_16x16x32_bf16(aq0, b0, a, 0, 0, 0);
            a = __builtin_amdgcn_mfma_f32_16x16x32_bf16(aq1, b1, a, 0, 0, 0);
            sacc[nt] = a;
        }

        const float* bbase = bias + (size_t)(q0 + wb + quad * 4) * 512 + kv0 + c;
        float tsum[4];
        #pragma unroll
        for (int r = 0; r < 4; ++r) tsum[r] = 0.f;
        #pragma unroll
        for (int nt = 0; nt < 4; ++nt)
            #pragma unroll
            for (int r = 0; r < 4; ++r) {
                float p = __expf(sacc[nt][r] * SCALE + bbase[(size_t)r * 512 + nt * 16]);
                tsum[r] += p;
                Ps[(wb + quad * 4 + r) * KSTR + nt * 16 + c] = f2bf(p);
            }
        #pragma unroll
        for (int r = 0; r < 4; ++r) {
            float t = tsum[r];
            t += __shfl_xor(t, 1);
            t += __shfl_xor(t, 2);
            t += __shfl_xor(t, 4);
            t += __shfl_xor(t, 8);
            lrow[r] += t;
        }

        bf16x8 pb0 = *(const bf16x8*)&Ps[(wb + c) * KSTR + quad * 8];
        bf16x8 pb1 = *(const bf16x8*)&Ps[(wb + c) * KSTR + 32 + quad * 8];
        #pragma unroll
        for (int t = 0; t < 4; ++t) {
            const unsigned short* vbase = &Vs[(t * 16 + c) * 64];
            bf16x8 a0 = *(const bf16x8*)(vbase + p0);
            bf16x8 a1 = *(const bf16x8*)(vbase + p1);
            oacc[t] = __builtin_amdgcn_mfma_f32_16x16x32_bf16(a0, pb0, oacc[t], 0, 0, 0);
            oacc[t] = __builtin_amdgcn_mfma_f32_16x16x32_bf16(a1, pb1, oacc[t], 0, 0, 0);
        }
    }

    if (c == 0) {
        f32x4 lv;
        lv[0] = lrow[0]; lv[1] = lrow[1]; lv[2] = lrow[2]; lv[3] = lrow[3];
        *(f32x4*)&lf[wb + quad * 4] = lv;
    }
    float invl = 1.0f / lf[wb + c];
    unsigned short* drow = attended + ((size_t)b * SEQ + (q0 + wb + c)) * D_MODEL + h * HDIM;
    #pragma unroll
    for (int t = 0; t < 4; ++t) {
        ushort4 o;
        o.x = f2bf(oacc[t][0] * invl);
        o.y = f2bf(oacc[t][1] * invl);
        o.z = f2bf(oacc[t][2] * invl);
        o.w = f2bf(oacc[t][3] * invl);
        *(ushort4*)(drow + t * 16 + quad * 4) = o;
    }
}

extern "C" void kernel_launch(void* const* d_in, const int* in_sizes, int n_in,
                              void* d_out, int out_size, void* d_ws, size_t ws_size,
                              hipStream_t stream) {
    const float* dec    = (const float*)d_in[0];
    const float* enc    = (const float*)d_in[1];
    const float* Wqkv   = (const float*)d_in[2];
    const float* Wout   = (const float*)d_in[3];
    const float* b_out  = (const float*)d_in[4];
    const float* Wgate  = (const float*)d_in[5];
    const float* b_gate = (const float*)d_in[6];
    const float* gamma  = (const float*)d_in[7];
    const float* beta   = (const float*)d_in[8];
    float* out = (float*)d_out;

    char* ws = (char*)d_ws;
    const size_t MB = 1024 * 1024;
    unsigned short* q_ln    = (unsigned short*)(ws + 0 * MB);
    unsigned short* kv_ln   = (unsigned short*)(ws + 8 * MB);
    unsigned short* qb      = (unsigned short*)(ws + 16 * MB);
    unsigned short* kb      = (unsigned short*)(ws + 24 * MB);
    unsigned short* vb      = (unsigned short*)(ws + 32 * MB);   // V^T (B,H,64,L)
    unsigned short* Wqkv_bf = (unsigned short*)(ws + 40 * MB);
    float*          bias    = (float*)(ws + 46 * MB);
    unsigned short* att     = (unsigned short*)(ws + 0 * MB);    // q_ln dead after qkv
    unsigned short* t_bf    = (unsigned short*)(ws + 24 * MB);   // kb dead after attn

    // Hoisted weight-convert needs 4 MB of never-aliased space at 47..51 MB.
    bool hoist = (ws_size >= 51 * MB);
    unsigned short* Wout_bf  = (unsigned short*)(ws + (hoist ? 47 * MB : 32 * MB));
    unsigned short* Wgate_bf = (unsigned short*)(ws + (hoist ? 49 * MB : 34 * MB));

    prep_kernel<<<hoist ? 14336 : 12288, 256, 0, stream>>>(
        dec, enc, gamma, beta, Wqkv, Wout, Wgate,
        q_ln, kv_ln, bias, Wqkv_bf, Wout_bf, Wgate_bf);
    qkv_gemm_mfma<<<768, 256, 0, stream>>>(q_ln, kv_ln, Wqkv_bf, qb, kb, vb);
    attn_kernel<<<dim3(4, 16, 8), 512, 0, stream>>>(qb, kb, vb, bias, att);
    if (!hoist)
        convert_og<<<2048, 256, 0, stream>>>(Wout, Wgate, Wout_bf, Wgate_bf);
    out_gemm1_mfma<<<dim3(8, 64), 256, 0, stream>>>(att, Wout_bf, b_out, t_bf);
    out_gemm2_mfma<<<dim3(8, 64), 256, 0, stream>>>(t_bf, Wgate_bf, b_gate, dec, out);
}

// Round 4
// 224.534 us; speedup vs baseline: 1.6733x; 1.0361x over previous
//
#include <hip/hip_runtime.h>
#include <hip/hip_bf16.h>

#define D_MODEL 1024
#define NHEADS 16
#define HDIM 64
#define BATCH 8
#define SEQ 512
#define NROWS 4096          // BATCH*SEQ
#define SCALE 0.125f
#define LN_EPS 1e-5f

typedef __attribute__((ext_vector_type(8))) short bf16x8;      // 8 bf16 (4 VGPRs)
typedef __attribute__((ext_vector_type(4))) float f32x4;
typedef __attribute__((ext_vector_type(8))) unsigned short u16x8;

static __device__ __forceinline__ float bf2f(unsigned short u) {
    return __uint_as_float(((unsigned int)u) << 16);
}
static __device__ __forceinline__ unsigned short f2bf(float f) {
    unsigned int x = __float_as_uint(f);
    unsigned int r = (x + 0x7fffu + ((x >> 16) & 1u)) >> 16;   // RNE
    return (unsigned short)r;
}

// async 16B/lane global->LDS DMA; LDS dest = wave-uniform base + lane*16
#define GLOAD16(gp, lp)                                                        \
    __builtin_amdgcn_global_load_lds(                                          \
        (const __attribute__((address_space(1))) void*)(gp),                   \
        (__attribute__((address_space(3))) void*)(lp), 16, 0, 0)

// ---------------------------------------------------------------------------
// Bias helper: jax.image.resize(bias128, (512,512), 'bilinear')
// ---------------------------------------------------------------------------
static __device__ __forceinline__ float bias128(int a, int b) {
    float d = fabsf((float)(a - b));
    return expf(-d * 0.1f) - d * 0.05f;
}

// ---------------------------------------------------------------------------
// prep_kernel: fused LN (blocks 0..8191) + bias table (8192..9215) +
// Wqkv convert (9216..12287) + [hoisted Wout/Wgate convert (12288..14335)]
// ---------------------------------------------------------------------------
__global__ void prep_kernel(const float* __restrict__ dec, const float* __restrict__ enc,
                            const float* __restrict__ gamma, const float* __restrict__ beta,
                            const float* __restrict__ Wqkv,
                            const float* __restrict__ Wout, const float* __restrict__ Wgate,
                            unsigned short* __restrict__ q_ln, unsigned short* __restrict__ kv_ln,
                            float* __restrict__ bias, unsigned short* __restrict__ Wqkv_bf,
                            unsigned short* __restrict__ Wout_bf, unsigned short* __restrict__ Wgate_bf) {
    int blk = blockIdx.x;
    int t = threadIdx.x;
    if (blk >= 12288) {         // hoisted Wout/Wgate convert (only when launched)
        int idx = (blk - 12288) * 256 + t;
        const float* src; unsigned short* dst; int off;
        if (idx < 262144) { src = Wout; dst = Wout_bf; off = idx; }
        else              { src = Wgate; dst = Wgate_bf; off = idx - 262144; }
        float4 v = ((const float4*)src)[off];
        ushort4 u;
        u.x = f2bf(v.x); u.y = f2bf(v.y); u.z = f2bf(v.z); u.w = f2bf(v.w);
        ((ushort4*)dst)[off] = u;
        return;
    }
    if (blk >= 9216) {          // Wqkv convert
        int idx = (blk - 9216) * 256 + t;
        float4 v = ((const float4*)Wqkv)[idx];
        ushort4 u;
        u.x = f2bf(v.x); u.y = f2bf(v.y); u.z = f2bf(v.z); u.w = f2bf(v.w);
        ((ushort4*)Wqkv_bf)[idx] = u;
        return;
    }
    if (blk >= 8192) {          // bias
        int idx = (blk - 8192) * 256 + t;
        int qi = idx >> 9, kj = idx & 511;
        float fq = (qi + 0.5f) * 0.25f - 0.5f;
        float fk = (kj + 0.5f) * 0.25f - 0.5f;
        int iq = (int)floorf(fq); float tq = fq - (float)iq;
        int ik = (int)floorf(fk); float tk = fk - (float)ik;
        int iq0 = min(max(iq, 0), 127), iq1 = min(max(iq + 1, 0), 127);
        int ik0 = min(max(ik, 0), 127), ik1 = min(max(ik + 1, 0), 127);
        float v = (1.f - tq) * ((1.f - tk) * bias128(iq0, ik0) + tk * bias128(iq0, ik1))
                +        tq  * ((1.f - tk) * bias128(iq1, ik0) + tk * bias128(iq1, ik1));
        bias[idx] = v;
        return;
    }
    int row = blk;
    const float* src = (row < NROWS) ? dec + (size_t)row * D_MODEL
                                     : enc + (size_t)(row - NROWS) * D_MODEL;
    unsigned short* dst = (row < NROWS) ? q_ln + (size_t)row * D_MODEL
                                        : kv_ln + (size_t)(row - NROWS) * D_MODEL;
    float4 x = ((const float4*)src)[t];
    float s  = x.x + x.y + x.z + x.w;
    float ss = x.x * x.x + x.y * x.y + x.z * x.z + x.w * x.w;
    #pragma unroll
    for (int off = 32; off > 0; off >>= 1) {
        s  += __shfl_down(s, off);
        ss += __shfl_down(ss, off);
    }
    __shared__ float red_s[4], red_ss[4];
    int wid = t >> 6, lane = t & 63;
    if (lane == 0) { red_s[wid] = s; red_ss[wid] = ss; }
    __syncthreads();
    if (t == 0) {
        float S = red_s[0] + red_s[1] + red_s[2] + red_s[3];
        float SS = red_ss[0] + red_ss[1] + red_ss[2] + red_ss[3];
        red_s[0] = S; red_ss[0] = SS;
    }
    __syncthreads();
    float mu  = red_s[0] * (1.0f / 1024.0f);
    float var = red_ss[0] * (1.0f / 1024.0f) - mu * mu;
    float rstd = rsqrtf(var + LN_EPS);
    float4 g = ((const float4*)gamma)[t];
    float4 bb = ((const float4*)beta)[t];
    ushort4 u;
    u.x = f2bf((x.x - mu) * rstd * g.x + bb.x);
    u.y = f2bf((x.y - mu) * rstd * g.y + bb.y);
    u.z = f2bf((x.z - mu) * rstd * g.z + bb.z);
    u.w = f2bf((x.w - mu) * rstd * g.w + bb.w);
    ((ushort4*)dst)[t] = u;
}

// ---------------------------------------------------------------------------
// Wout + Wgate fp32 -> bf16 (fallback path when ws too small to hoist)
// ---------------------------------------------------------------------------
__global__ void convert_og(const float* __restrict__ Wout, const float* __restrict__ Wgate,
                           unsigned short* __restrict__ Wout_bf, unsigned short* __restrict__ Wgate_bf) {
    int idx = blockIdx.x * 256 + threadIdx.x;
    const float* src; unsigned short* dst; int off;
    if (idx < 262144) { src = (const float*)Wout; dst = Wout_bf; off = idx; }
    else              { src = (const float*)Wgate; dst = Wgate_bf; off = idx - 262144; }
    float4 v = ((const float4*)src)[off];
    ushort4 u;
    u.x = f2bf(v.x); u.y = f2bf(v.y); u.z = f2bf(v.z); u.w = f2bf(v.w);
    ((ushort4*)dst)[off] = u;
}

// ===========================================================================
// MFMA GEMM core (bf16): 64x128 tile, BK=128, wave tile 32x64, 8 K-iters,
// 32 MFMA/wave-stage. Permanent lessons: R7 named scalars; R8 no manual
// prefetch; R9 global_load_lds + XOR swizzle (0 conflicts); R13/R14 BK=128.
// R15: V written pre-transposed (B,H,D,L) by qkv; attn stages K/Vt via
// global_load_lds with the same swizzle (kills scalar transpose stores).
// R16: f32x4 acc ARRAYS spill to scratch (WRITE_SIZE 24->780MB, 4.5x slow);
// accumulators must be NAMED scalars. R17: 128^2/BK=64 tile is latency-bound
// at K=1024 (376 TF < 515 TF of 64x128/BK=128) — tile ladder from K=4096
// does NOT transfer to small K; keep 64x128/BK=128 here.
// ===========================================================================
#define CSTR 136   // C-bounce row stride (multiple of 8 -> 16B-aligned rows)

struct alignas(16) Smem64B {
    unsigned short A[64 * 128];     // 16 KB
    unsigned short B[128 * 128];    // 32 KB
};

union alignas(16) Smem64Q {
    struct { unsigned short A[64 * 128]; unsigned short B[128 * 128]; } ab;  // 48 KB
    unsigned short C[64 * CSTR];    // q/k bounce: 64 rows x 136
    unsigned short Ct[128 * 72];    // v bounce (transposed): 128 d-rows x 72
};

#define MF(a, b, d) __builtin_amdgcn_mfma_f32_16x16x32_bf16((a), (b), (d), 0, 0, 0)

#define GEMM_KH2B(kh)                                                          \
    {                                                                          \
        int pofs = (((kh) * 4 + quad) ^ c) * 8;                                \
        const unsigned short* Arow_ = &As2[(wr * 32 + c) * 128 + pofs];        \
        const unsigned short* Brow_ = &Bs2[(wc * 64 + c) * 128 + pofs];        \
        bf16x8 f0 = *(const bf16x8*)(Arow_);                                   \
        bf16x8 f1 = *(const bf16x8*)(Arow_ + 2048);                            \
        bf16x8 g0 = *(const bf16x8*)(Brow_);                                   \
        bf16x8 g1 = *(const bf16x8*)(Brow_ + 2048);                            \
        bf16x8 g2 = *(const bf16x8*)(Brow_ + 4096);                            \
        bf16x8 g3 = *(const bf16x8*)(Brow_ + 6144);                            \
        c00 = MF(f0, g0, c00); c01 = MF(f0, g1, c01); c02 = MF(f0, g2, c02); c03 = MF(f0, g3, c03); \
        c10 = MF(f1, g0, c10); c11 = MF(f1, g1, c11); c12 = MF(f1, g2, c12); c13 = MF(f1, g3, c13); \
    }

#define GEMM_BODY_64B(Aptr, Bptr)                                              \
    int wave = tid >> 6, lane = tid & 63, quad = lane >> 4, c = lane & 15;     \
    int wr = wave >> 1, wc = wave & 1;                                         \
    int l4 = lane >> 4, l15 = lane & 15;                                       \
    const unsigned short* Abase = (Aptr) + (size_t)(rt * 64) * 1024;           \
    const unsigned short* Bbase = (Bptr) + (size_t)(ct * 128) * 1024;          \
    int aoff0 = (wave * 16 +  0 + l4) * 1024 + ((l15 ^ ( 0 + l4)) * 8);        \
    int aoff1 = (wave * 16 +  4 + l4) * 1024 + ((l15 ^ ( 4 + l4)) * 8);        \
    int aoff2 = (wave * 16 +  8 + l4) * 1024 + ((l15 ^ ( 8 + l4)) * 8);        \
    int aoff3 = (wave * 16 + 12 + l4) * 1024 + ((l15 ^ (12 + l4)) * 8);        \
    int boff0 = (wave * 32 +  0 + l4) * 1024 + ((l15 ^ (( 0 + l4) & 15)) * 8); \
    int boff1 = (wave * 32 +  4 + l4) * 1024 + ((l15 ^ (( 4 + l4) & 15)) * 8); \
    int boff2 = (wave * 32 +  8 + l4) * 1024 + ((l15 ^ (( 8 + l4) & 15)) * 8); \
    int boff3 = (wave * 32 + 12 + l4) * 1024 + ((l15 ^ ((12 + l4) & 15)) * 8); \
    int boff4 = (wave * 32 + 16 + l4) * 1024 + ((l15 ^ ((16 + l4) & 15)) * 8); \
    int boff5 = (wave * 32 + 20 + l4) * 1024 + ((l15 ^ ((20 + l4) & 15)) * 8); \
    int boff6 = (wave * 32 + 24 + l4) * 1024 + ((l15 ^ ((24 + l4) & 15)) * 8); \
    int boff7 = (wave * 32 + 28 + l4) * 1024 + ((l15 ^ ((28 + l4) & 15)) * 8); \
    unsigned short* AsW = As2 + wave * 2048;                                   \
    unsigned short* BsW = Bs2 + wave * 4096;                                   \
    f32x4 c00 = (f32x4)0.f, c01 = (f32x4)0.f, c02 = (f32x4)0.f, c03 = (f32x4)0.f; \
    f32x4 c10 = (f32x4)0.f, c11 = (f32x4)0.f, c12 = (f32x4)0.f, c13 = (f32x4)0.f; \
    for (int kt = 0; kt < 8; ++kt) {                                           \
        int k0 = kt * 128;                                                     \
        __syncthreads();                                                       \
        GLOAD16(Abase + aoff0 + k0, AsW);                                      \
        GLOAD16(Abase + aoff1 + k0, AsW + 512);                                \
        GLOAD16(Abase + aoff2 + k0, AsW + 1024);                               \
        GLOAD16(Abase + aoff3 + k0, AsW + 1536);                               \
        GLOAD16(Bbase + boff0 + k0, BsW);                                      \
        GLOAD16(Bbase + boff1 + k0, BsW + 512);                                \
        GLOAD16(Bbase + boff2 + k0, BsW + 1024);                               \
        GLOAD16(Bbase + boff3 + k0, BsW + 1536);                               \
        GLOAD16(Bbase + boff4 + k0, BsW + 2048);                               \
        GLOAD16(Bbase + boff5 + k0, BsW + 2560);                               \
        GLOAD16(Bbase + boff6 + k0, BsW + 3072);                               \
        GLOAD16(Bbase + boff7 + k0, BsW + 3584);                               \
        __syncthreads();                                                       \
        GEMM_KH2B(0)                                                           \
        GEMM_KH2B(1)                                                           \
        GEMM_KH2B(2)                                                           \
        GEMM_KH2B(3)                                                           \
    }

// ---------------------------------------------------------------------------
// QKV GEMM (MFMA, 64x128 tile, BK=128) + fused RoPE, LDS-bounce epilogue.
// Q/K: (B,H,L,64) layout.  V: transposed (B,H,64,L) layout (R15).
// Grid 1536 (1-D), swizzled into 8(ct)x4(rt) super-tiles for L2 locality.
// ---------------------------------------------------------------------------
#define QROPE_REG(i, reg, A0, A1, A2, A3)                                      \
    {                                                                          \
        int mloc = wr * 32 + (i) * 16 + quad * 4 + (reg);                      \
        int crow = mloc * CSTR + wc * 64;                                      \
        float fl = (float)((rt * 64 + mloc) & 511);                            \
        float aa0 = fl * inv0, aa1 = fl * inv1;                                \
        float c0 = cosf(aa0), s0 = sinf(aa0);                                  \
        float c1 = cosf(aa1), s1 = sinf(aa1);                                  \
        float e0 = A0[(reg)], o0 = A2[(reg)];                                  \
        float e1 = A1[(reg)], o1 = A3[(reg)];                                  \
        smemq.C[crow + c]      = f2bf(e0 * c0 - o0 * s0);                      \
        smemq.C[crow + 32 + c] = f2bf(e0 * s0 + o0 * c0);                      \
        smemq.C[crow + 16 + c] = f2bf(e1 * c1 - o1 * s1);                      \
        smemq.C[crow + 48 + c] = f2bf(e1 * s1 + o1 * c1);                      \
    }
#define QROPE_ROW(i, A0, A1, A2, A3)                                           \
    QROPE_REG(i, 0, A0, A1, A2, A3) QROPE_REG(i, 1, A0, A1, A2, A3)            \
    QROPE_REG(i, 2, A0, A1, A2, A3) QROPE_REG(i, 3, A0, A1, A2, A3)

// V: bounce transposed — Ct[dcol][l_local], stride 72
#define QVSECT_REG(i, j, reg, Acc)                                             \
    smemq.Ct[(wc * 64 + (j) * 16 + c) * 72 + (wr * 32 + (i) * 16 + quad * 4 + (reg))] = f2bf(Acc[(reg)]);
#define QVSECT_TILE(i, j, Acc)                                                 \
    QVSECT_REG(i, j, 0, Acc) QVSECT_REG(i, j, 1, Acc)                          \
    QVSECT_REG(i, j, 2, Acc) QVSECT_REG(i, j, 3, Acc)

__global__ __launch_bounds__(256, 1)
void qkv_gemm_mfma(const unsigned short* __restrict__ q_ln,
                   const unsigned short* __restrict__ kv_ln,
                   const unsigned short* __restrict__ Wb,
                   unsigned short* __restrict__ qo,
                   unsigned short* __restrict__ ko,
                   unsigned short* __restrict__ vo) {
    int bid = blockIdx.x;               // 0..1535
    int st = bid >> 5, in = bid & 31;   // 48 super-tiles of 32 blocks
    int stc = st % 3, str = st / 3;     // stc 0..2, str 0..15
    int ct = stc * 8 + (in & 7);        // 0..23
    int rt = str * 4 + (in >> 3);       // 0..63
    int n0 = ct * 128;
    int section = n0 >> 10;             // 0=q 1=k 2=v
    const unsigned short* A = (section == 0) ? q_ln : kv_ln;

    __shared__ Smem64Q smemq;
    unsigned short* As2 = smemq.ab.A;
    unsigned short* Bs2 = smemq.ab.B;
    int tid = threadIdx.x;

    GEMM_BODY_64B(A, Wb)

    __syncthreads();                    // all waves done reading As/Bs
    if (section == 2) {
        QVSECT_TILE(0, 0, c00) QVSECT_TILE(0, 1, c01) QVSECT_TILE(0, 2, c02) QVSECT_TILE(0, 3, c03)
        QVSECT_TILE(1, 0, c10) QVSECT_TILE(1, 1, c11) QVSECT_TILE(1, 2, c12) QVSECT_TILE(1, 3, c13)
        __syncthreads();
        // store: 128 d-rows x 64 contiguous l
        int dr = tid >> 1, hh = tid & 1;
        int h = ((n0 & 1023) >> 6) + (dr >> 6);
        int d = dr & 63;
        int mmb = rt * 64;
        int bb = mmb >> 9, ll0 = mmb & 511;
        unsigned short* orow = vo + (((size_t)bb * NHEADS + h) * HDIM + d) * SEQ + ll0 + hh * 32;
        const unsigned short* csrc = &smemq.Ct[dr * 72 + hh * 32];
        #pragma unroll
        for (int kc = 0; kc < 4; ++kc)
            *(u16x8*)(orow + kc * 8) = *(const u16x8*)(csrc + kc * 8);
        return;
    }

    float inv0 = expf(-0.2878231366f * (float)c);          // 10000^(-c/32)
    float inv1 = expf(-0.2878231366f * (float)(16 + c));
    QROPE_ROW(0, c00, c01, c02, c03)
    QROPE_ROW(1, c10, c11, c12, c13)
    __syncthreads();

    unsigned short* outp = (section == 0) ? qo : ko;
    int rr = tid >> 2;                  // row 0..63
    int ch = (tid >> 1) & 1;            // head-half 0/1
    int sub = tid & 1;                  // 32-short half within head
    int mm = rt * 64 + rr;
    int bb = mm >> 9, ll = mm & 511;
    int h = ((n0 & 1023) >> 6) + ch;
    unsigned short* orow = outp + (((size_t)bb * NHEADS + h) * SEQ + ll) * HDIM + sub * 32;
    const unsigned short* csrc = &smemq.C[rr * CSTR + ch * 64 + sub * 32];
    #pragma unroll
    for (int kc = 0; kc < 4; ++kc)
        *(u16x8*)(orow + kc * 8) = *(const u16x8*)(csrc + kc * 8);
}

// ---------------------------------------------------------------------------
// Projection 1 (MFMA, 64x128 tile, BK=128): t = att @ Wout^T + b_out -> bf16
// grid (8, 64) = 512 blocks
// ---------------------------------------------------------------------------
#define O1_REG(mb, reg, n, Acc)                                                \
    t_bf[(size_t)((mb) + (reg)) * 1024 + (n)] = f2bf(Acc[(reg)] + bo);
#define O1_TILE(i, j, Acc)                                                     \
    {                                                                          \
        int n = ct * 128 + wc * 64 + (j) * 16 + c;                             \
        float bo = b_out[n];                                                   \
        int mb = rt * 64 + wr * 32 + (i) * 16 + quad * 4;                      \
        O1_REG(mb, 0, n, Acc) O1_REG(mb, 1, n, Acc)                            \
        O1_REG(mb, 2, n, Acc) O1_REG(mb, 3, n, Acc)                            \
    }

__global__ __launch_bounds__(256, 1)
void out_gemm1_mfma(const unsigned short* __restrict__ att,
                    const unsigned short* __restrict__ Wob,
                    const float* __restrict__ b_out,
                    unsigned short* __restrict__ t_bf) {
    int ct = blockIdx.x, rt = blockIdx.y;
    __shared__ Smem64B smem2;
    unsigned short* As2 = smem2.A;
    unsigned short* Bs2 = smem2.B;
    int tid = threadIdx.x;

    GEMM_BODY_64B(att, Wob)

    O1_TILE(0, 0, c00) O1_TILE(0, 1, c01) O1_TILE(0, 2, c02) O1_TILE(0, 3, c03)
    O1_TILE(1, 0, c10) O1_TILE(1, 1, c11) O1_TILE(1, 2, c12) O1_TILE(1, 3, c13)
}

// ---------------------------------------------------------------------------
// Projection 2 (MFMA, 64x128 tile, BK=128): gz = t_bf @ Wgate^T + b_gate;
// out = sigmoid(gz)*t + (1-sigmoid)*residual   (t read back as bf16)
// ---------------------------------------------------------------------------
#define O2_REG(mb, reg, n, Acc)                                                \
    {                                                                          \
        float gz = Acc[(reg)] + bg;                                            \
        float g = 1.0f / (1.0f + expf(-gz));                                   \
        size_t idx = (size_t)((mb) + (reg)) * 1024 + (n);                      \
        float tv = bf2f(t_bf[idx]);                                            \
        float rv = residual[idx];                                              \
        out[idx] = g * tv + (1.0f - g) * rv;                                   \
    }
#define O2_TILE(i, j, Acc)                                                     \
    {                                                                          \
        int n = ct * 128 + wc * 64 + (j) * 16 + c;                             \
        float bg = b_gate[n];                                                  \
        int mb = rt * 64 + wr * 32 + (i) * 16 + quad * 4;                      \
        O2_REG(mb, 0, n, Acc) O2_REG(mb, 1, n, Acc)                            \
        O2_REG(mb, 2, n, Acc) O2_REG(mb, 3, n, Acc)                            \
    }

__global__ __launch_bounds__(256, 1)
void out_gemm2_mfma(const unsigned short* __restrict__ t_bf,
                    const unsigned short* __restrict__ Wgb,
                    const float* __restrict__ b_gate,
                    const float* __restrict__ residual,
                    float* __restrict__ out) {
    int ct = blockIdx.x, rt = blockIdx.y;
    __shared__ Smem64B smem2;
    unsigned short* As2 = smem2.A;
    unsigned short* Bs2 = smem2.B;
    int tid = threadIdx.x;

    GEMM_BODY_64B(t_bf, Wgb)

    O2_TILE(0, 0, c00) O2_TILE(0, 1, c01) O2_TILE(0, 2, c02) O2_TILE(0, 3, c03)
    O2_TILE(1, 0, c10) O2_TILE(1, 1, c11) O2_TILE(1, 2, c12) O2_TILE(1, 3, c13)
}

// ---------------------------------------------------------------------------
// Flash attention, bf16 MFMA (16x16x32). 128-row Q tile, 8 waves.
// R12: unnormalized streaming softmax (scores bounded: |s| < ~10).
// R15: K and Vt staged via global_load_lds w/ XOR swizzle.
// R18 (this round): KV tile 64 -> 128: halves barrier pairs (8->4),
// doubles MFMA per phase (32/wave); LDS 35 -> 68 KB (still 2 blocks/CU,
// grid-limited). Same chunk^(row&7) involution, extended to 16-chunk V rows.
// ---------------------------------------------------------------------------
#define KSTR 136   // Ps stride (128 cols + 8 pad; 16B-aligned rows)

__global__ __launch_bounds__(512)
void attn_kernel(const unsigned short* __restrict__ q,
                 const unsigned short* __restrict__ k,
                 const unsigned short* __restrict__ vt,
                 const float* __restrict__ bias,
                 unsigned short* __restrict__ attended) {
    int qt = blockIdx.x, h = blockIdx.y, b = blockIdx.z;
    __shared__ unsigned short Ks[128 * 64];   // 16 KB: kv-rows x d
    __shared__ unsigned short Vs[64 * 128];   // 16 KB: d-rows x kv
    __shared__ unsigned short Ps[128 * KSTR]; // 34 KB
    __shared__ float lf[128];

    int tid = threadIdx.x;
    int wave = tid >> 6, lane = tid & 63;   // wave 0..7
    int quad = lane >> 4, c = lane & 15;
    int wb = wave * 16;                     // wave's q-row base, 0..112
    size_t headbase = (((size_t)b * NHEADS + h) * SEQ) * HDIM;  // == (b*16+h)*32768
    int q0 = qt * 128;

    const unsigned short* qrow = q + headbase + (size_t)(q0 + wb + c) * HDIM;
    bf16x8 aq0 = *(const bf16x8*)(qrow + quad * 8);
    bf16x8 aq1 = *(const bf16x8*)(qrow + 32 + quad * 8);

    // K staging: 2 GLOAD16 cover 128 kv-rows x 64 d (rows 0..63, 64..127)
    int srK = wave * 8 + (lane >> 3);          // 0..63
    int scK = (lane & 7) ^ (srK & 7);          // 8 chunks/row, XOR row&7
    const unsigned short* kgb = k + headbase + (size_t)srK * HDIM + scK * 8;
    unsigned short* KsW = Ks + wave * 512;
    // V staging: 2 GLOAD16 cover 64 d-rows x 128 kv (rows 0..31, 32..63)
    int srV = wave * 4 + (lane >> 4);          // 0..31
    int scV = (lane & 15) ^ (srV & 7);         // 16 chunks/row, XOR row&7 (low 3 bits)
    const unsigned short* vgb = vt + headbase + (size_t)srV * SEQ + scV * 8;
    unsigned short* VsW = Vs + wave * 512;

    int x7 = c & 7;
    int p0 = (quad ^ x7) * 8;
    int p1 = ((4 + quad) ^ x7) * 8;

    f32x4 oacc[4];
    #pragma unroll
    for (int t = 0; t < 4; ++t) oacc[t] = (f32x4)0.f;
    float lrow[4];
    #pragma unroll
    for (int r = 0; r < 4; ++r) lrow[r] = 0.f;

    for (int kt = 0; kt < 4; ++kt) {
        int kv0 = kt * 128;
        __syncthreads();
        GLOAD16(kgb + (size_t)kv0 * HDIM, KsW);              // K rows kv0+0..63
        GLOAD16(kgb + (size_t)(kv0 + 64) * HDIM, KsW + 4096);// K rows kv0+64..127
        GLOAD16(vgb + kv0, VsW);                             // Vt d-rows 0..31
        GLOAD16(vgb + 32 * SEQ + kv0, VsW + 4096);           // Vt d-rows 32..63
        __syncthreads();

        // QK^T: 8 nt-subtiles of 16 kv each
        f32x4 sacc[8];
        #pragma unroll
        for (int nt = 0; nt < 8; ++nt) {
            const unsigned short* kbase = &Ks[(nt * 16 + c) * 64];
            bf16x8 b0 = *(const bf16x8*)(kbase + p0);
            bf16x8 b1 = *(const bf16x8*)(kbase + p1);
            f32x4 a = (f32x4)0.f;
            a = __builtin_amdgcn_mfma_f32_16x16x32_bf16(aq0, b0, a, 0, 0, 0);
            a = __builtin_amdgcn_mfma_f32_16x16x32_bf16(aq1, b1, a, 0, 0, 0);
            sacc[nt] = a;
        }

        const float* bbase = bias + (size_t)(q0 + wb + quad * 4) * 512 + kv0 + c;
        float tsum[4];
        #pragma unroll
        for (int r = 0; r < 4; ++r) tsum[r] = 0.f;
        #pragma unroll
        for (int nt = 0; nt < 8; ++nt)
            #pragma unroll
            for (int r = 0; r < 4; ++r) {
                float p = __expf(sacc[nt][r] * SCALE + bbase[(size_t)r * 512 + nt * 16]);
                tsum[r] += p;
                Ps[(wb + quad * 4 + r) * KSTR + nt * 16 + c] = f2bf(p);
            }
        #pragma unroll
        for (int r = 0; r < 4; ++r) {
            float t = tsum[r];
            t += __shfl_xor(t, 1);
            t += __shfl_xor(t, 2);
            t += __shfl_xor(t, 4);
            t += __shfl_xor(t, 8);
            lrow[r] += t;
        }

        // PV: P fragments (within-wave rows) x Vt, 4 K=32 slices over 128 kv
        bf16x8 pb0 = *(const bf16x8*)&Ps[(wb + c) * KSTR + quad * 8];
        bf16x8 pb1 = *(const bf16x8*)&Ps[(wb + c) * KSTR + 32 + quad * 8];
        bf16x8 pb2 = *(const bf16x8*)&Ps[(wb + c) * KSTR + 64 + quad * 8];
        bf16x8 pb3 = *(const bf16x8*)&Ps[(wb + c) * KSTR + 96 + quad * 8];
        #pragma unroll
        for (int t = 0; t < 4; ++t) {
            const unsigned short* vbase = &Vs[(t * 16 + c) * 128];
            bf16x8 a0 = *(const bf16x8*)(vbase + ((( 0 + quad) ^ x7) * 8));
            bf16x8 a1 = *(const bf16x8*)(vbase + ((( 4 + quad) ^ x7) * 8));
            bf16x8 a2 = *(const bf16x8*)(vbase + ((( 8 + quad) ^ x7) * 8));
            bf16x8 a3 = *(const bf16x8*)(vbase + (((12 + quad) ^ x7) * 8));
            oacc[t] = __builtin_amdgcn_mfma_f32_16x16x32_bf16(a0, pb0, oacc[t], 0, 0, 0);
            oacc[t] = __builtin_amdgcn_mfma_f32_16x16x32_bf16(a1, pb1, oacc[t], 0, 0, 0);
            oacc[t] = __builtin_amdgcn_mfma_f32_16x16x32_bf16(a2, pb2, oacc[t], 0, 0, 0);
            oacc[t] = __builtin_amdgcn_mfma_f32_16x16x32_bf16(a3, pb3, oacc[t], 0, 0, 0);
        }
    }

    if (c == 0) {
        f32x4 lv;
        lv[0] = lrow[0]; lv[1] = lrow[1]; lv[2] = lrow[2]; lv[3] = lrow[3];
        *(f32x4*)&lf[wb + quad * 4] = lv;
    }
    float invl = 1.0f / lf[wb + c];
    unsigned short* drow = attended + ((size_t)b * SEQ + (q0 + wb + c)) * D_MODEL + h * HDIM;
    #pragma unroll
    for (int t = 0; t < 4; ++t) {
        ushort4 o;
        o.x = f2bf(oacc[t][0] * invl);
        o.y = f2bf(oacc[t][1] * invl);
        o.z = f2bf(oacc[t][2] * invl);
        o.w = f2bf(oacc[t][3] * invl);
        *(ushort4*)(drow + t * 16 + quad * 4) = o;
    }
}

extern "C" void kernel_launch(void* const* d_in, const int* in_sizes, int n_in,
                              void* d_out, int out_size, void* d_ws, size_t ws_size,
                              hipStream_t stream) {
    const float* dec    = (const float*)d_in[0];
    const float* enc    = (const float*)d_in[1];
    const float* Wqkv   = (const float*)d_in[2];
    const float* Wout   = (const float*)d_in[3];
    const float* b_out  = (const float*)d_in[4];
    const float* Wgate  = (const float*)d_in[5];
    const float* b_gate = (const float*)d_in[6];
    const float* gamma  = (const float*)d_in[7];
    const float* beta   = (const float*)d_in[8];
    float* out = (float*)d_out;

    char* ws = (char*)d_ws;
    const size_t MB = 1024 * 1024;
    unsigned short* q_ln    = (unsigned short*)(ws + 0 * MB);
    unsigned short* kv_ln   = (unsigned short*)(ws + 8 * MB);
    unsigned short* qb      = (unsigned short*)(ws + 16 * MB);
    unsigned short* kb      = (unsigned short*)(ws + 24 * MB);
    unsigned short* vb      = (unsigned short*)(ws + 32 * MB);   // V^T (B,H,64,L)
    unsigned short* Wqkv_bf = (unsigned short*)(ws + 40 * MB);
    float*          bias    = (float*)(ws + 46 * MB);
    unsigned short* att     = (unsigned short*)(ws + 0 * MB);    // q_ln dead after qkv
    unsigned short* t_bf    = (unsigned short*)(ws + 24 * MB);   // kb dead after attn

    // Hoisted weight-convert needs 4 MB of never-aliased space at 47..51 MB.
    bool hoist = (ws_size >= 51 * MB);
    unsigned short* Wout_bf  = (unsigned short*)(ws + (hoist ? 47 * MB : 32 * MB));
    unsigned short* Wgate_bf = (unsigned short*)(ws + (hoist ? 49 * MB : 34 * MB));

    prep_kernel<<<hoist ? 14336 : 12288, 256, 0, stream>>>(
        dec, enc, gamma, beta, Wqkv, Wout, Wgate,
        q_ln, kv_ln, bias, Wqkv_bf, Wout_bf, Wgate_bf);
    qkv_gemm_mfma<<<1536, 256, 0, stream>>>(q_ln, kv_ln, Wqkv_bf, qb, kb, vb);
    attn_kernel<<<dim3(4, 16, 8), 512, 0, stream>>>(qb, kb, vb, bias, att);
    if (!hoist)
        convert_og<<<2048, 256, 0, stream>>>(Wout, Wgate, Wout_bf, Wgate_bf);
    out_gemm1_mfma<<<dim3(8, 64), 256, 0, stream>>>(att, Wout_bf, b_out, t_bf);
    out_gemm2_mfma<<<dim3(8, 64), 256, 0, stream>>>(t_bf, Wgate_bf, b_gate, dec, out);
}

// Round 5
// 208.892 us; speedup vs baseline: 1.7986x; 1.0749x over previous
//
#include <hip/hip_runtime.h>
#include <hip/hip_bf16.h>

#define D_MODEL 1024
#define NHEADS 16
#define HDIM 64
#define BATCH 8
#define SEQ 512
#define NROWS 4096          // BATCH*SEQ
#define SCALE 0.125f
#define LN_EPS 1e-5f

typedef __attribute__((ext_vector_type(8))) short bf16x8;      // 8 bf16 (4 VGPRs)
typedef __attribute__((ext_vector_type(4))) float f32x4;
typedef __attribute__((ext_vector_type(8))) unsigned short u16x8;

static __device__ __forceinline__ float bf2f(unsigned short u) {
    return __uint_as_float(((unsigned int)u) << 16);
}
static __device__ __forceinline__ unsigned short f2bf(float f) {
    unsigned int x = __float_as_uint(f);
    unsigned int r = (x + 0x7fffu + ((x >> 16) & 1u)) >> 16;   // RNE
    return (unsigned short)r;
}

// async 16B/lane global->LDS DMA; LDS dest = wave-uniform base + lane*16
#define GLOAD16(gp, lp)                                                        \
    __builtin_amdgcn_global_load_lds(                                          \
        (const __attribute__((address_space(1))) void*)(gp),                   \
        (__attribute__((address_space(3))) void*)(lp), 16, 0, 0)

// ---------------------------------------------------------------------------
// Bias helper: jax.image.resize(bias128, (512,512), 'bilinear')
// ---------------------------------------------------------------------------
static __device__ __forceinline__ float bias128(int a, int b) {
    float d = fabsf((float)(a - b));
    return expf(-d * 0.1f) - d * 0.05f;
}

// ---------------------------------------------------------------------------
// prep_kernel: fused LN (blocks 0..8191) + bias table (8192..9215) +
// Wqkv convert (9216..12287) + [hoisted Wout/Wgate convert (12288..14335)]
// ---------------------------------------------------------------------------
__global__ void prep_kernel(const float* __restrict__ dec, const float* __restrict__ enc,
                            const float* __restrict__ gamma, const float* __restrict__ beta,
                            const float* __restrict__ Wqkv,
                            const float* __restrict__ Wout, const float* __restrict__ Wgate,
                            unsigned short* __restrict__ q_ln, unsigned short* __restrict__ kv_ln,
                            float* __restrict__ bias, unsigned short* __restrict__ Wqkv_bf,
                            unsigned short* __restrict__ Wout_bf, unsigned short* __restrict__ Wgate_bf) {
    int blk = blockIdx.x;
    int t = threadIdx.x;
    if (blk >= 12288) {         // hoisted Wout/Wgate convert (only when launched)
        int idx = (blk - 12288) * 256 + t;
        const float* src; unsigned short* dst; int off;
        if (idx < 262144) { src = Wout; dst = Wout_bf; off = idx; }
        else              { src = Wgate; dst = Wgate_bf; off = idx - 262144; }
        float4 v = ((const float4*)src)[off];
        ushort4 u;
        u.x = f2bf(v.x); u.y = f2bf(v.y); u.z = f2bf(v.z); u.w = f2bf(v.w);
        ((ushort4*)dst)[off] = u;
        return;
    }
    if (blk >= 9216) {          // Wqkv convert
        int idx = (blk - 9216) * 256 + t;
        float4 v = ((const float4*)Wqkv)[idx];
        ushort4 u;
        u.x = f2bf(v.x); u.y = f2bf(v.y); u.z = f2bf(v.z); u.w = f2bf(v.w);
        ((ushort4*)Wqkv_bf)[idx] = u;
        return;
    }
    if (blk >= 8192) {          // bias
        int idx = (blk - 8192) * 256 + t;
        int qi = idx >> 9, kj = idx & 511;
        float fq = (qi + 0.5f) * 0.25f - 0.5f;
        float fk = (kj + 0.5f) * 0.25f - 0.5f;
        int iq = (int)floorf(fq); float tq = fq - (float)iq;
        int ik = (int)floorf(fk); float tk = fk - (float)ik;
        int iq0 = min(max(iq, 0), 127), iq1 = min(max(iq + 1, 0), 127);
        int ik0 = min(max(ik, 0), 127), ik1 = min(max(ik + 1, 0), 127);
        float v = (1.f - tq) * ((1.f - tk) * bias128(iq0, ik0) + tk * bias128(iq0, ik1))
                +        tq  * ((1.f - tk) * bias128(iq1, ik0) + tk * bias128(iq1, ik1));
        bias[idx] = v;
        return;
    }
    int row = blk;
    const float* src = (row < NROWS) ? dec + (size_t)row * D_MODEL
                                     : enc + (size_t)(row - NROWS) * D_MODEL;
    unsigned short* dst = (row < NROWS) ? q_ln + (size_t)row * D_MODEL
                                        : kv_ln + (size_t)(row - NROWS) * D_MODEL;
    float4 x = ((const float4*)src)[t];
    float s  = x.x + x.y + x.z + x.w;
    float ss = x.x * x.x + x.y * x.y + x.z * x.z + x.w * x.w;
    #pragma unroll
    for (int off = 32; off > 0; off >>= 1) {
        s  += __shfl_down(s, off);
        ss += __shfl_down(ss, off);
    }
    __shared__ float red_s[4], red_ss[4];
    int wid = t >> 6, lane = t & 63;
    if (lane == 0) { red_s[wid] = s; red_ss[wid] = ss; }
    __syncthreads();
    if (t == 0) {
        float S = red_s[0] + red_s[1] + red_s[2] + red_s[3];
        float SS = red_ss[0] + red_ss[1] + red_ss[2] + red_ss[3];
        red_s[0] = S; red_ss[0] = SS;
    }
    __syncthreads();
    float mu  = red_s[0] * (1.0f / 1024.0f);
    float var = red_ss[0] * (1.0f / 1024.0f) - mu * mu;
    float rstd = rsqrtf(var + LN_EPS);
    float4 g = ((const float4*)gamma)[t];
    float4 bb = ((const float4*)beta)[t];
    ushort4 u;
    u.x = f2bf((x.x - mu) * rstd * g.x + bb.x);
    u.y = f2bf((x.y - mu) * rstd * g.y + bb.y);
    u.z = f2bf((x.z - mu) * rstd * g.z + bb.z);
    u.w = f2bf((x.w - mu) * rstd * g.w + bb.w);
    ((ushort4*)dst)[t] = u;
}

// ---------------------------------------------------------------------------
// Wout + Wgate fp32 -> bf16 (fallback path when ws too small to hoist)
// ---------------------------------------------------------------------------
__global__ void convert_og(const float* __restrict__ Wout, const float* __restrict__ Wgate,
                           unsigned short* __restrict__ Wout_bf, unsigned short* __restrict__ Wgate_bf) {
    int idx = blockIdx.x * 256 + threadIdx.x;
    const float* src; unsigned short* dst; int off;
    if (idx < 262144) { src = (const float*)Wout; dst = Wout_bf; off = idx; }
    else              { src = (const float*)Wgate; dst = Wgate_bf; off = idx - 262144; }
    float4 v = ((const float4*)src)[off];
    ushort4 u;
    u.x = f2bf(v.x); u.y = f2bf(v.y); u.z = f2bf(v.z); u.w = f2bf(v.w);
    ((ushort4*)dst)[off] = u;
}

// ===========================================================================
// MFMA GEMM cores (bf16). Permanent lessons:
// R7/R16: accumulators and frags NAMED scalars (arrays spill to scratch).
// R9: global_load_lds + XOR swizzle (0 conflicts).
// R17: 128^2/BK=64 latency-bound at K=1024 — keep 64x128 tile here.
// R18 FAILED: attn KVBLK=128 regressed ~14us (reverted to KVBLK=64).
// R19 (this round, qkv only): 2-phase double-buffered BK=64 K-loop
// (prefetch k+1 before compute k, ONE barrier/step) + XCD-contiguous
// swizzle with ct-major super-tile grouping (B-panel 2MB L2-resident/XCD).
// ===========================================================================
#define CSTR 136   // C-bounce row stride (multiple of 8 -> 16B-aligned rows)

struct alignas(16) Smem64B {
    unsigned short A[64 * 128];     // 16 KB
    unsigned short B[128 * 128];    // 32 KB
};

#define MF(a, b, d) __builtin_amdgcn_mfma_f32_16x16x32_bf16((a), (b), (d), 0, 0, 0)

#define GEMM_KH2B(kh)                                                          \
    {                                                                          \
        int pofs = (((kh) * 4 + quad) ^ c) * 8;                                \
        const unsigned short* Arow_ = &As2[(wr * 32 + c) * 128 + pofs];        \
        const unsigned short* Brow_ = &Bs2[(wc * 64 + c) * 128 + pofs];        \
        bf16x8 f0 = *(const bf16x8*)(Arow_);                                   \
        bf16x8 f1 = *(const bf16x8*)(Arow_ + 2048);                            \
        bf16x8 g0 = *(const bf16x8*)(Brow_);                                   \
        bf16x8 g1 = *(const bf16x8*)(Brow_ + 2048);                            \
        bf16x8 g2 = *(const bf16x8*)(Brow_ + 4096);                            \
        bf16x8 g3 = *(const bf16x8*)(Brow_ + 6144);                            \
        c00 = MF(f0, g0, c00); c01 = MF(f0, g1, c01); c02 = MF(f0, g2, c02); c03 = MF(f0, g3, c03); \
        c10 = MF(f1, g0, c10); c11 = MF(f1, g1, c11); c12 = MF(f1, g2, c12); c13 = MF(f1, g3, c13); \
    }

#define GEMM_BODY_64B(Aptr, Bptr)                                              \
    int wave = tid >> 6, lane = tid & 63, quad = lane >> 4, c = lane & 15;     \
    int wr = wave >> 1, wc = wave & 1;                                         \
    int l4 = lane >> 4, l15 = lane & 15;                                       \
    const unsigned short* Abase = (Aptr) + (size_t)(rt * 64) * 1024;           \
    const unsigned short* Bbase = (Bptr) + (size_t)(ct * 128) * 1024;          \
    int aoff0 = (wave * 16 +  0 + l4) * 1024 + ((l15 ^ ( 0 + l4)) * 8);        \
    int aoff1 = (wave * 16 +  4 + l4) * 1024 + ((l15 ^ ( 4 + l4)) * 8);        \
    int aoff2 = (wave * 16 +  8 + l4) * 1024 + ((l15 ^ ( 8 + l4)) * 8);        \
    int aoff3 = (wave * 16 + 12 + l4) * 1024 + ((l15 ^ (12 + l4)) * 8);        \
    int boff0 = (wave * 32 +  0 + l4) * 1024 + ((l15 ^ (( 0 + l4) & 15)) * 8); \
    int boff1 = (wave * 32 +  4 + l4) * 1024 + ((l15 ^ (( 4 + l4) & 15)) * 8); \
    int boff2 = (wave * 32 +  8 + l4) * 1024 + ((l15 ^ (( 8 + l4) & 15)) * 8); \
    int boff3 = (wave * 32 + 12 + l4) * 1024 + ((l15 ^ ((12 + l4) & 15)) * 8); \
    int boff4 = (wave * 32 + 16 + l4) * 1024 + ((l15 ^ ((16 + l4) & 15)) * 8); \
    int boff5 = (wave * 32 + 20 + l4) * 1024 + ((l15 ^ ((20 + l4) & 15)) * 8); \
    int boff6 = (wave * 32 + 24 + l4) * 1024 + ((l15 ^ ((24 + l4) & 15)) * 8); \
    int boff7 = (wave * 32 + 28 + l4) * 1024 + ((l15 ^ ((28 + l4) & 15)) * 8); \
    unsigned short* AsW = As2 + wave * 2048;                                   \
    unsigned short* BsW = Bs2 + wave * 4096;                                   \
    f32x4 c00 = (f32x4)0.f, c01 = (f32x4)0.f, c02 = (f32x4)0.f, c03 = (f32x4)0.f; \
    f32x4 c10 = (f32x4)0.f, c11 = (f32x4)0.f, c12 = (f32x4)0.f, c13 = (f32x4)0.f; \
    for (int kt = 0; kt < 8; ++kt) {                                           \
        int k0 = kt * 128;                                                     \
        __syncthreads();                                                       \
        GLOAD16(Abase + aoff0 + k0, AsW);                                      \
        GLOAD16(Abase + aoff1 + k0, AsW + 512);                                \
        GLOAD16(Abase + aoff2 + k0, AsW + 1024);                               \
        GLOAD16(Abase + aoff3 + k0, AsW + 1536);                               \
        GLOAD16(Bbase + boff0 + k0, BsW);                                      \
        GLOAD16(Bbase + boff1 + k0, BsW + 512);                                \
        GLOAD16(Bbase + boff2 + k0, BsW + 1024);                               \
        GLOAD16(Bbase + boff3 + k0, BsW + 1536);                               \
        GLOAD16(Bbase + boff4 + k0, BsW + 2048);                               \
        GLOAD16(Bbase + boff5 + k0, BsW + 2560);                               \
        GLOAD16(Bbase + boff6 + k0, BsW + 3072);                               \
        GLOAD16(Bbase + boff7 + k0, BsW + 3584);                               \
        __syncthreads();                                                       \
        GEMM_KH2B(0)                                                           \
        GEMM_KH2B(1)                                                           \
        GEMM_KH2B(2)                                                           \
        GEMM_KH2B(3)                                                           \
    }

// ---------------------------------------------------------------------------
// QKV GEMM (R19): 64x128 tile, BK=64 double-buffered (2-phase), fused RoPE.
// Q/K: (B,H,L,64) layout.  V: transposed (B,H,64,L) layout (R15).
// Grid 1536: XCD-contiguous swizzle, ct-major super-tiles (8ct x 4rt).
// LDS: A[2][64x64] + B[2][128x64] = 48 KB, unioned with C-bounce.
// ---------------------------------------------------------------------------
union alignas(16) SmemQD {
    struct { unsigned short A[2][64 * 64]; unsigned short B[2][128 * 64]; } ab;  // 48 KB
    unsigned short C[64 * CSTR];    // q/k bounce: 64 rows x 136
    unsigned short Ct[128 * 72];    // v bounce (transposed): 128 d-rows x 72
};

// stage one BK=64 tile into (pA,pB): A 64x64 (2 loads), B 128x64 (4 loads)
#define QSTAGE(pA, pB, k0)                                                     \
    GLOAD16(Ab + (k0),          (pA) + stW);                                   \
    GLOAD16(Ab + 32768 + (k0),  (pA) + stW + 2048);                            \
    GLOAD16(Bb + (k0),          (pB) + stW);                                   \
    GLOAD16(Bb + 32768 + (k0),  (pB) + stW + 2048);                            \
    GLOAD16(Bb + 65536 + (k0),  (pB) + stW + 4096);                            \
    GLOAD16(Bb + 98304 + (k0),  (pB) + stW + 6144);

// one K-half (K=32) of a BK=64 step on buffers (pA,pB): 6 frag loads + 8 MFMA
#define QKH(pA, pB, kh)                                                        \
    {                                                                          \
        int pofs = (((kh) * 4 + quad) ^ x7) * 8;                               \
        const unsigned short* Ar_ = (pA) + (wr * 32 + c) * 64 + pofs;          \
        const unsigned short* Br_ = (pB) + (wc * 64 + c) * 64 + pofs;          \
        bf16x8 f0 = *(const bf16x8*)(Ar_);                                     \
        bf16x8 f1 = *(const bf16x8*)(Ar_ + 1024);                              \
        bf16x8 g0 = *(const bf16x8*)(Br_);                                     \
        bf16x8 g1 = *(const bf16x8*)(Br_ + 1024);                              \
        bf16x8 g2 = *(const bf16x8*)(Br_ + 2048);                              \
        bf16x8 g3 = *(const bf16x8*)(Br_ + 3072);                              \
        c00 = MF(f0, g0, c00); c01 = MF(f0, g1, c01); c02 = MF(f0, g2, c02); c03 = MF(f0, g3, c03); \
        c10 = MF(f1, g0, c10); c11 = MF(f1, g1, c11); c12 = MF(f1, g2, c12); c13 = MF(f1, g3, c13); \
    }

#define QROPE_REG(i, reg, A0, A1, A2, A3)                                      \
    {                                                                          \
        int mloc = wr * 32 + (i) * 16 + quad * 4 + (reg);                      \
        int crow = mloc * CSTR + wc * 64;                                      \
        float fl = (float)((rt * 64 + mloc) & 511);                            \
        float aa0 = fl * inv0, aa1 = fl * inv1;                                \
        float c0 = cosf(aa0), s0 = sinf(aa0);                                  \
        float c1 = cosf(aa1), s1 = sinf(aa1);                                  \
        float e0 = A0[(reg)], o0 = A2[(reg)];                                  \
        float e1 = A1[(reg)], o1 = A3[(reg)];                                  \
        smemq.C[crow + c]      = f2bf(e0 * c0 - o0 * s0);                      \
        smemq.C[crow + 32 + c] = f2bf(e0 * s0 + o0 * c0);                      \
        smemq.C[crow + 16 + c] = f2bf(e1 * c1 - o1 * s1);                      \
        smemq.C[crow + 48 + c] = f2bf(e1 * s1 + o1 * c1);                      \
    }
#define QROPE_ROW(i, A0, A1, A2, A3)                                           \
    QROPE_REG(i, 0, A0, A1, A2, A3) QROPE_REG(i, 1, A0, A1, A2, A3)            \
    QROPE_REG(i, 2, A0, A1, A2, A3) QROPE_REG(i, 3, A0, A1, A2, A3)

// V: bounce transposed — Ct[dcol][l_local], stride 72
#define QVSECT_REG(i, j, reg, Acc)                                             \
    smemq.Ct[(wc * 64 + (j) * 16 + c) * 72 + (wr * 32 + (i) * 16 + quad * 4 + (reg))] = f2bf(Acc[(reg)]);
#define QVSECT_TILE(i, j, Acc)                                                 \
    QVSECT_REG(i, j, 0, Acc) QVSECT_REG(i, j, 1, Acc)                          \
    QVSECT_REG(i, j, 2, Acc) QVSECT_REG(i, j, 3, Acc)

__global__ __launch_bounds__(256, 1)
void qkv_gemm_mfma(const unsigned short* __restrict__ q_ln,
                   const unsigned short* __restrict__ kv_ln,
                   const unsigned short* __restrict__ Wb,
                   unsigned short* __restrict__ qo,
                   unsigned short* __restrict__ ko,
                   unsigned short* __restrict__ vo) {
    int bid = blockIdx.x;                     // 0..1535
    int wg = (bid & 7) * 192 + (bid >> 3);    // XCD-contiguous (bijective, 1536%8==0)
    int st = wg >> 5, in = wg & 31;           // 48 super-tiles of 32 blocks
    int stc = st >> 4, str = st & 15;         // ct-major: stc 0..2 (= section), str 0..15
    int ct = stc * 8 + (in & 7);              // 0..23
    int rt = str * 4 + (in >> 3);             // 0..63
    int n0 = ct * 128;
    int section = stc;                        // 0=q 1=k 2=v
    const unsigned short* A = (section == 0) ? q_ln : kv_ln;

    __shared__ SmemQD smemq;
    int tid = threadIdx.x;
    int wave = tid >> 6, lane = tid & 63, quad = lane >> 4, c = lane & 15;
    int wr = wave >> 1, wc = wave & 1;
    int x7 = c & 7;

    // staging source: thread t covers row t>>3, slot t&7 holds chunk (t&7)^((t>>3)&7)
    int soff = (tid >> 3) * 1024 + (((tid & 7) ^ ((tid >> 3) & 7)) * 8);
    const unsigned short* Ab = A + (size_t)(rt * 64) * 1024 + soff;
    const unsigned short* Bb = Wb + (size_t)n0 * 1024 + soff;
    int stW = wave * 512;
    unsigned short* A0 = smemq.ab.A[0];
    unsigned short* A1 = smemq.ab.A[1];
    unsigned short* B0 = smemq.ab.B[0];
    unsigned short* B1 = smemq.ab.B[1];

    f32x4 c00 = (f32x4)0.f, c01 = (f32x4)0.f, c02 = (f32x4)0.f, c03 = (f32x4)0.f;
    f32x4 c10 = (f32x4)0.f, c11 = (f32x4)0.f, c12 = (f32x4)0.f, c13 = (f32x4)0.f;

    // 2-phase double-buffered K-loop: 16 steps of BK=64, ONE barrier per step.
    QSTAGE(A0, B0, 0)
    __syncthreads();
    for (int kt2 = 0; kt2 < 8; ++kt2) {
        QSTAGE(A1, B1, (kt2 * 2 + 1) * 64)    // prefetch odd step
        QKH(A0, B0, 0) QKH(A0, B0, 1)         // compute even step
        __syncthreads();
        if (kt2 < 7) { QSTAGE(A0, B0, (kt2 * 2 + 2) * 64) }  // prefetch next even
        QKH(A1, B1, 0) QKH(A1, B1, 1)         // compute odd step
        __syncthreads();
    }

    // epilogue (identical to verified round-0; last loop barrier precedes it)
    if (section == 2) {
        QVSECT_TILE(0, 0, c00) QVSECT_TILE(0, 1, c01) QVSECT_TILE(0, 2, c02) QVSECT_TILE(0, 3, c03)
        QVSECT_TILE(1, 0, c10) QVSECT_TILE(1, 1, c11) QVSECT_TILE(1, 2, c12) QVSECT_TILE(1, 3, c13)
        __syncthreads();
        // store: 128 d-rows x 64 contiguous l
        int dr = tid >> 1, hh = tid & 1;
        int h = ((n0 & 1023) >> 6) + (dr >> 6);
        int d = dr & 63;
        int mmb = rt * 64;
        int bb = mmb >> 9, ll0 = mmb & 511;
        unsigned short* orow = vo + (((size_t)bb * NHEADS + h) * HDIM + d) * SEQ + ll0 + hh * 32;
        const unsigned short* csrc = &smemq.Ct[dr * 72 + hh * 32];
        #pragma unroll
        for (int kc = 0; kc < 4; ++kc)
            *(u16x8*)(orow + kc * 8) = *(const u16x8*)(csrc + kc * 8);
        return;
    }

    float inv0 = expf(-0.2878231366f * (float)c);          // 10000^(-c/32)
    float inv1 = expf(-0.2878231366f * (float)(16 + c));
    QROPE_ROW(0, c00, c01, c02, c03)
    QROPE_ROW(1, c10, c11, c12, c13)
    __syncthreads();

    unsigned short* outp = (section == 0) ? qo : ko;
    int rr = tid >> 2;                  // row 0..63
    int ch = (tid >> 1) & 1;            // head-half 0/1
    int sub = tid & 1;                  // 32-short half within head
    int mm = rt * 64 + rr;
    int bb = mm >> 9, ll = mm & 511;
    int h = ((n0 & 1023) >> 6) + ch;
    unsigned short* orow = outp + (((size_t)bb * NHEADS + h) * SEQ + ll) * HDIM + sub * 32;
    const unsigned short* csrc = &smemq.C[rr * CSTR + ch * 64 + sub * 32];
    #pragma unroll
    for (int kc = 0; kc < 4; ++kc)
        *(u16x8*)(orow + kc * 8) = *(const u16x8*)(csrc + kc * 8);
}

// ---------------------------------------------------------------------------
// Projection 1 (MFMA, 64x128 tile, BK=128): t = att @ Wout^T + b_out -> bf16
// grid (8, 64) = 512 blocks
// ---------------------------------------------------------------------------
#define O1_REG(mb, reg, n, Acc)                                                \
    t_bf[(size_t)((mb) + (reg)) * 1024 + (n)] = f2bf(Acc[(reg)] + bo);
#define O1_TILE(i, j, Acc)                                                     \
    {                                                                          \
        int n = ct * 128 + wc * 64 + (j) * 16 + c;                             \
        float bo = b_out[n];                                                   \
        int mb = rt * 64 + wr * 32 + (i) * 16 + quad * 4;                      \
        O1_REG(mb, 0, n, Acc) O1_REG(mb, 1, n, Acc)                            \
        O1_REG(mb, 2, n, Acc) O1_REG(mb, 3, n, Acc)                            \
    }

__global__ __launch_bounds__(256, 1)
void out_gemm1_mfma(const unsigned short* __restrict__ att,
                    const unsigned short* __restrict__ Wob,
                    const float* __restrict__ b_out,
                    unsigned short* __restrict__ t_bf) {
    int ct = blockIdx.x, rt = blockIdx.y;
    __shared__ Smem64B smem2;
    unsigned short* As2 = smem2.A;
    unsigned short* Bs2 = smem2.B;
    int tid = threadIdx.x;

    GEMM_BODY_64B(att, Wob)

    O1_TILE(0, 0, c00) O1_TILE(0, 1, c01) O1_TILE(0, 2, c02) O1_TILE(0, 3, c03)
    O1_TILE(1, 0, c10) O1_TILE(1, 1, c11) O1_TILE(1, 2, c12) O1_TILE(1, 3, c13)
}

// ---------------------------------------------------------------------------
// Projection 2 (MFMA, 64x128 tile, BK=128): gz = t_bf @ Wgate^T + b_gate;
// out = sigmoid(gz)*t + (1-sigmoid)*residual   (t read back as bf16)
// ---------------------------------------------------------------------------
#define O2_REG(mb, reg, n, Acc)                                                \
    {                                                                          \
        float gz = Acc[(reg)] + bg;                                            \
        float g = 1.0f / (1.0f + expf(-gz));                                   \
        size_t idx = (size_t)((mb) + (reg)) * 1024 + (n);                      \
        float tv = bf2f(t_bf[idx]);                                            \
        float rv = residual[idx];                                              \
        out[idx] = g * tv + (1.0f - g) * rv;                                   \
    }
#define O2_TILE(i, j, Acc)                                                     \
    {                                                                          \
        int n = ct * 128 + wc * 64 + (j) * 16 + c;                             \
        float bg = b_gate[n];                                                  \
        int mb = rt * 64 + wr * 32 + (i) * 16 + quad * 4;                      \
        O2_REG(mb, 0, n, Acc) O2_REG(mb, 1, n, Acc)                            \
        O2_REG(mb, 2, n, Acc) O2_REG(mb, 3, n, Acc)                            \
    }

__global__ __launch_bounds__(256, 1)
void out_gemm2_mfma(const unsigned short* __restrict__ t_bf,
                    const unsigned short* __restrict__ Wgb,
                    const float* __restrict__ b_gate,
                    const float* __restrict__ residual,
                    float* __restrict__ out) {
    int ct = blockIdx.x, rt = blockIdx.y;
    __shared__ Smem64B smem2;
    unsigned short* As2 = smem2.A;
    unsigned short* Bs2 = smem2.B;
    int tid = threadIdx.x;

    GEMM_BODY_64B(t_bf, Wgb)

    O2_TILE(0, 0, c00) O2_TILE(0, 1, c01) O2_TILE(0, 2, c02) O2_TILE(0, 3, c03)
    O2_TILE(1, 0, c10) O2_TILE(1, 1, c11) O2_TILE(1, 2, c12) O2_TILE(1, 3, c13)
}

// ---------------------------------------------------------------------------
// Flash attention, bf16 MFMA (16x16x32). 128-row Q tile, 8 waves.
// R12: unnormalized streaming softmax (scores bounded: |s| < ~10).
// R15: K and Vt staged via global_load_lds w/ XOR swizzle (V pre-transposed
// in global by qkv). R18: KVBLK=128 regressed — this is the KVBLK=64 version.
// LDS rows 64 shorts, 8 slots; row r slot s holds chunk s^(r&7).
// ---------------------------------------------------------------------------
#define KSTR 72   // Ps stride only

__global__ __launch_bounds__(512)
void attn_kernel(const unsigned short* __restrict__ q,
                 const unsigned short* __restrict__ k,
                 const unsigned short* __restrict__ vt,
                 const float* __restrict__ bias,
                 unsigned short* __restrict__ attended) {
    int qt = blockIdx.x, h = blockIdx.y, b = blockIdx.z;
    __shared__ unsigned short Ks[64 * 64];
    __shared__ unsigned short Vs[64 * 64];
    __shared__ unsigned short Ps[128 * KSTR];
    __shared__ float lf[128];

    int tid = threadIdx.x;
    int wave = tid >> 6, lane = tid & 63;   // wave 0..7
    int quad = lane >> 4, c = lane & 15;
    int wb = wave * 16;                     // wave's q-row base, 0..112
    size_t headbase = (((size_t)b * NHEADS + h) * SEQ) * HDIM;  // == (b*16+h)*32768
    int q0 = qt * 128;

    const unsigned short* qrow = q + headbase + (size_t)(q0 + wb + c) * HDIM;
    bf16x8 aq0 = *(const bf16x8*)(qrow + quad * 8);
    bf16x8 aq1 = *(const bf16x8*)(qrow + 32 + quad * 8);

    // staging: wave w covers rows w*8..w*8+7 (8 rows x 64 shorts = 1 GLOAD16/lane)
    int srow = wave * 8 + (lane >> 3);
    int schunk = (lane & 7) ^ (srow & 7);
    unsigned short* KsW = Ks + wave * 512;
    unsigned short* VsW = Vs + wave * 512;
    const unsigned short* kgb = k + headbase + (size_t)srow * HDIM + schunk * 8;
    const unsigned short* vgb = vt + headbase + (size_t)srow * SEQ + schunk * 8;
    int x7 = c & 7;
    int p0 = (quad ^ x7) * 8;
    int p1 = ((4 + quad) ^ x7) * 8;

    f32x4 oacc[4];
    #pragma unroll
    for (int t = 0; t < 4; ++t) oacc[t] = (f32x4)0.f;
    float lrow[4];
    #pragma unroll
    for (int r = 0; r < 4; ++r) lrow[r] = 0.f;

    for (int kt = 0; kt < 8; ++kt) {
        int kv0 = kt * 64;
        __syncthreads();
        GLOAD16(kgb + (size_t)kv0 * HDIM, KsW);   // K rows kv0+srow
        GLOAD16(vgb + kv0, VsW);                  // Vt rows d=srow, cols kv0+
        __syncthreads();

        f32x4 sacc[4];
        #pragma unroll
        for (int nt = 0; nt < 4; ++nt) {
            const unsigned short* kbase = &Ks[(nt * 16 + c) * 64];
            bf16x8 b0 = *(const bf16x8*)(kbase + p0);
            bf16x8 b1 = *(const bf16x8*)(kbase + p1);
            f32x4 a = (f32x4)0.f;
            a = __builtin_amdgcn_mfma_f32_16x16x32_bf16(aq0, b0, a, 0, 0, 0);
            a = __builtin_amdgcn_mfma_f32_16x16x32_bf16(aq1, b1, a, 0, 0, 0);
            sacc[nt] = a;
        }

        const float* bbase = bias + (size_t)(q0 + wb + quad * 4) * 512 + kv0 + c;
        float tsum[4];
        #pragma unroll
        for (int r = 0; r < 4; ++r) tsum[r] = 0.f;
        #pragma unroll
        for (int nt = 0; nt < 4; ++nt)
            #pragma unroll
            for (int r = 0; r < 4; ++r) {
                float p = __expf(sacc[nt][r] * SCALE + bbase[(size_t)r * 512 + nt * 16]);
                tsum[r] += p;
                Ps[(wb + quad * 4 + r) * KSTR + nt * 16 + c] = f2bf(p);
            }
        #pragma unroll
        for (int r = 0; r < 4; ++r) {
            float t = tsum[r];
            t += __shfl_xor(t, 1);
            t += __shfl_xor(t, 2);
            t += __shfl_xor(t, 4);
            t += __shfl_xor(t, 8);
            lrow[r] += t;
        }

        bf16x8 pb0 = *(const bf16x8*)&Ps[(wb + c) * KSTR + quad * 8];
        bf16x8 pb1 = *(const bf16x8*)&Ps[(wb + c) * KSTR + 32 + quad * 8];
        #pragma unroll
        for (int t = 0; t < 4; ++t) {
            const unsigned short* vbase = &Vs[(t * 16 + c) * 64];
            bf16x8 a0 = *(const bf16x8*)(vbase + p0);
            bf16x8 a1 = *(const bf16x8*)(vbase + p1);
            oacc[t] = __builtin_amdgcn_mfma_f32_16x16x32_bf16(a0, pb0, oacc[t], 0, 0, 0);
            oacc[t] = __builtin_amdgcn_mfma_f32_16x16x32_bf16(a1, pb1, oacc[t], 0, 0, 0);
        }
    }

    if (c == 0) {
        f32x4 lv;
        lv[0] = lrow[0]; lv[1] = lrow[1]; lv[2] = lrow[2]; lv[3] = lrow[3];
        *(f32x4*)&lf[wb + quad * 4] = lv;
    }
    float invl = 1.0f / lf[wb + c];
    unsigned short* drow = attended + ((size_t)b * SEQ + (q0 + wb + c)) * D_MODEL + h * HDIM;
    #pragma unroll
    for (int t = 0; t < 4; ++t) {
        ushort4 o;
        o.x = f2bf(oacc[t][0] * invl);
        o.y = f2bf(oacc[t][1] * invl);
        o.z = f2bf(oacc[t][2] * invl);
        o.w = f2bf(oacc[t][3] * invl);
        *(ushort4*)(drow + t * 16 + quad * 4) = o;
    }
}

extern "C" void kernel_launch(void* const* d_in, const int* in_sizes, int n_in,
                              void* d_out, int out_size, void* d_ws, size_t ws_size,
                              hipStream_t stream) {
    const float* dec    = (const float*)d_in[0];
    const float* enc    = (const float*)d_in[1];
    const float* Wqkv   = (const float*)d_in[2];
    const float* Wout   = (const float*)d_in[3];
    const float* b_out  = (const float*)d_in[4];
    const float* Wgate  = (const float*)d_in[5];
    const float* b_gate = (const float*)d_in[6];
    const float* gamma  = (const float*)d_in[7];
    const float* beta   = (const float*)d_in[8];
    float* out = (float*)d_out;

    char* ws = (char*)d_ws;
    const size_t MB = 1024 * 1024;
    unsigned short* q_ln    = (unsigned short*)(ws + 0 * MB);
    unsigned short* kv_ln   = (unsigned short*)(ws + 8 * MB);
    unsigned short* qb      = (unsigned short*)(ws + 16 * MB);
    unsigned short* kb      = (unsigned short*)(ws + 24 * MB);
    unsigned short* vb      = (unsigned short*)(ws + 32 * MB);   // V^T (B,H,64,L)
    unsigned short* Wqkv_bf = (unsigned short*)(ws + 40 * MB);
    float*          bias    = (float*)(ws + 46 * MB);
    unsigned short* att     = (unsigned short*)(ws + 0 * MB);    // q_ln dead after qkv
    unsigned short* t_bf    = (unsigned short*)(ws + 24 * MB);   // kb dead after attn

    // Hoisted weight-convert needs 4 MB of never-aliased space at 47..51 MB.
    bool hoist = (ws_size >= 51 * MB);
    unsigned short* Wout_bf  = (unsigned short*)(ws + (hoist ? 47 * MB : 32 * MB));
    unsigned short* Wgate_bf = (unsigned short*)(ws + (hoist ? 49 * MB : 34 * MB));

    prep_kernel<<<hoist ? 14336 : 12288, 256, 0, stream>>>(
        dec, enc, gamma, beta, Wqkv, Wout, Wgate,
        q_ln, kv_ln, bias, Wqkv_bf, Wout_bf, Wgate_bf);
    qkv_gemm_mfma<<<1536, 256, 0, stream>>>(q_ln, kv_ln, Wqkv_bf, qb, kb, vb);
    attn_kernel<<<dim3(4, 16, 8), 512, 0, stream>>>(qb, kb, vb, bias, att);
    if (!hoist)
        convert_og<<<2048, 256, 0, stream>>>(Wout, Wgate, Wout_bf, Wgate_bf);
    out_gemm1_mfma<<<dim3(8, 64), 256, 0, stream>>>(att, Wout_bf, b_out, t_bf);
    out_gemm2_mfma<<<dim3(8, 64), 256, 0, stream>>>(t_bf, Wgate_bf, b_gate, dec, out);
}

// Round 6
// 208.293 us; speedup vs baseline: 1.8038x; 1.0029x over previous
//
#include <hip/hip_runtime.h>
#include <hip/hip_bf16.h>

#define D_MODEL 1024
#define NHEADS 16
#define HDIM 64
#define BATCH 8
#define SEQ 512
#define NROWS 4096          // BATCH*SEQ
#define SCALE 0.125f
#define LN_EPS 1e-5f

typedef __attribute__((ext_vector_type(8))) short bf16x8;      // 8 bf16 (4 VGPRs)
typedef __attribute__((ext_vector_type(4))) float f32x4;
typedef __attribute__((ext_vector_type(8))) unsigned short u16x8;

static __device__ __forceinline__ float bf2f(unsigned short u) {
    return __uint_as_float(((unsigned int)u) << 16);
}
static __device__ __forceinline__ unsigned short f2bf(float f) {
    unsigned int x = __float_as_uint(f);
    unsigned int r = (x + 0x7fffu + ((x >> 16) & 1u)) >> 16;   // RNE
    return (unsigned short)r;
}

// async 16B/lane global->LDS DMA; LDS dest = wave-uniform base + lane*16
#define GLOAD16(gp, lp)                                                        \
    __builtin_amdgcn_global_load_lds(                                          \
        (const __attribute__((address_space(1))) void*)(gp),                   \
        (__attribute__((address_space(3))) void*)(lp), 16, 0, 0)

// R20: counted-vmcnt pipeline primitives (T4). Raw s_barrier does NOT drain
// vmcnt (unlike __syncthreads), so prefetch loads stay in flight across it.
#define VMW(n) asm volatile("s_waitcnt vmcnt(" #n ")" ::: "memory")
#define RBAR() __builtin_amdgcn_s_barrier()

// ---------------------------------------------------------------------------
// Bias helper: jax.image.resize(bias128, (512,512), 'bilinear')
// ---------------------------------------------------------------------------
static __device__ __forceinline__ float bias128(int a, int b) {
    float d = fabsf((float)(a - b));
    return expf(-d * 0.1f) - d * 0.05f;
}

// ---------------------------------------------------------------------------
// prep_kernel: fused LN (blocks 0..8191) + bias table (8192..9215) +
// Wqkv convert (9216..12287) + [hoisted Wout/Wgate convert (12288..14335)]
// ---------------------------------------------------------------------------
__global__ void prep_kernel(const float* __restrict__ dec, const float* __restrict__ enc,
                            const float* __restrict__ gamma, const float* __restrict__ beta,
                            const float* __restrict__ Wqkv,
                            const float* __restrict__ Wout, const float* __restrict__ Wgate,
                            unsigned short* __restrict__ q_ln, unsigned short* __restrict__ kv_ln,
                            float* __restrict__ bias, unsigned short* __restrict__ Wqkv_bf,
                            unsigned short* __restrict__ Wout_bf, unsigned short* __restrict__ Wgate_bf) {
    int blk = blockIdx.x;
    int t = threadIdx.x;
    if (blk >= 12288) {         // hoisted Wout/Wgate convert (only when launched)
        int idx = (blk - 12288) * 256 + t;
        const float* src; unsigned short* dst; int off;
        if (idx < 262144) { src = Wout; dst = Wout_bf; off = idx; }
        else              { src = Wgate; dst = Wgate_bf; off = idx - 262144; }
        float4 v = ((const float4*)src)[off];
        ushort4 u;
        u.x = f2bf(v.x); u.y = f2bf(v.y); u.z = f2bf(v.z); u.w = f2bf(v.w);
        ((ushort4*)dst)[off] = u;
        return;
    }
    if (blk >= 9216) {          // Wqkv convert
        int idx = (blk - 9216) * 256 + t;
        float4 v = ((const float4*)Wqkv)[idx];
        ushort4 u;
        u.x = f2bf(v.x); u.y = f2bf(v.y); u.z = f2bf(v.z); u.w = f2bf(v.w);
        ((ushort4*)Wqkv_bf)[idx] = u;
        return;
    }
    if (blk >= 8192) {          // bias
        int idx = (blk - 8192) * 256 + t;
        int qi = idx >> 9, kj = idx & 511;
        float fq = (qi + 0.5f) * 0.25f - 0.5f;
        float fk = (kj + 0.5f) * 0.25f - 0.5f;
        int iq = (int)floorf(fq); float tq = fq - (float)iq;
        int ik = (int)floorf(fk); float tk = fk - (float)ik;
        int iq0 = min(max(iq, 0), 127), iq1 = min(max(iq + 1, 0), 127);
        int ik0 = min(max(ik, 0), 127), ik1 = min(max(ik + 1, 0), 127);
        float v = (1.f - tq) * ((1.f - tk) * bias128(iq0, ik0) + tk * bias128(iq0, ik1))
                +        tq  * ((1.f - tk) * bias128(iq1, ik0) + tk * bias128(iq1, ik1));
        bias[idx] = v;
        return;
    }
    int row = blk;
    const float* src = (row < NROWS) ? dec + (size_t)row * D_MODEL
                                     : enc + (size_t)(row - NROWS) * D_MODEL;
    unsigned short* dst = (row < NROWS) ? q_ln + (size_t)row * D_MODEL
                                        : kv_ln + (size_t)(row - NROWS) * D_MODEL;
    float4 x = ((const float4*)src)[t];
    float s  = x.x + x.y + x.z + x.w;
    float ss = x.x * x.x + x.y * x.y + x.z * x.z + x.w * x.w;
    #pragma unroll
    for (int off = 32; off > 0; off >>= 1) {
        s  += __shfl_down(s, off);
        ss += __shfl_down(ss, off);
    }
    __shared__ float red_s[4], red_ss[4];
    int wid = t >> 6, lane = t & 63;
    if (lane == 0) { red_s[wid] = s; red_ss[wid] = ss; }
    __syncthreads();
    if (t == 0) {
        float S = red_s[0] + red_s[1] + red_s[2] + red_s[3];
        float SS = red_ss[0] + red_ss[1] + red_ss[2] + red_ss[3];
        red_s[0] = S; red_ss[0] = SS;
    }
    __syncthreads();
    float mu  = red_s[0] * (1.0f / 1024.0f);
    float var = red_ss[0] * (1.0f / 1024.0f) - mu * mu;
    float rstd = rsqrtf(var + LN_EPS);
    float4 g = ((const float4*)gamma)[t];
    float4 bb = ((const float4*)beta)[t];
    ushort4 u;
    u.x = f2bf((x.x - mu) * rstd * g.x + bb.x);
    u.y = f2bf((x.y - mu) * rstd * g.y + bb.y);
    u.z = f2bf((x.z - mu) * rstd * g.z + bb.z);
    u.w = f2bf((x.w - mu) * rstd * g.w + bb.w);
    ((ushort4*)dst)[t] = u;
}

// ---------------------------------------------------------------------------
// Wout + Wgate fp32 -> bf16 (fallback path when ws too small to hoist)
// ---------------------------------------------------------------------------
__global__ void convert_og(const float* __restrict__ Wout, const float* __restrict__ Wgate,
                           unsigned short* __restrict__ Wout_bf, unsigned short* __restrict__ Wgate_bf) {
    int idx = blockIdx.x * 256 + threadIdx.x;
    const float* src; unsigned short* dst; int off;
    if (idx < 262144) { src = (const float*)Wout; dst = Wout_bf; off = idx; }
    else              { src = (const float*)Wgate; dst = Wgate_bf; off = idx - 262144; }
    float4 v = ((const float4*)src)[off];
    ushort4 u;
    u.x = f2bf(v.x); u.y = f2bf(v.y); u.z = f2bf(v.z); u.w = f2bf(v.w);
    ((ushort4*)dst)[off] = u;
}

// ===========================================================================
// MFMA GEMM cores (bf16). Permanent lessons:
// R7/R16: accumulators and frags NAMED scalars (arrays spill to scratch).
// R9: global_load_lds + XOR swizzle (0 conflicts).
// R17: 128^2/BK=64 latency-bound at K=1024 — keep 64x128 tile here.
// R18 FAILED: attn KVBLK=128 regressed (reverted to KVBLK=64).
// R19: XCD-contiguous swizzle + ct-major grouping: FETCH 73->30MB; but
// __syncthreads-based dbuf did NOT speed up (vmcnt(0) drain at every barrier
// kills the prefetch — guide T3/T4: the gain IS the counted vmcnt).
// R20 (this round): counted s_waitcnt vmcnt(N) + raw s_barrier in qkv (N=6)
// and attn (N=2, Ks/Vs double-buffered).
// ===========================================================================
#define CSTR 136   // C-bounce row stride (multiple of 8 -> 16B-aligned rows)

struct alignas(16) Smem64B {
    unsigned short A[64 * 128];     // 16 KB
    unsigned short B[128 * 128];    // 32 KB
};

#define MF(a, b, d) __builtin_amdgcn_mfma_f32_16x16x32_bf16((a), (b), (d), 0, 0, 0)

#define GEMM_KH2B(kh)                                                          \
    {                                                                          \
        int pofs = (((kh) * 4 + quad) ^ c) * 8;                                \
        const unsigned short* Arow_ = &As2[(wr * 32 + c) * 128 + pofs];        \
        const unsigned short* Brow_ = &Bs2[(wc * 64 + c) * 128 + pofs];        \
        bf16x8 f0 = *(const bf16x8*)(Arow_);                                   \
        bf16x8 f1 = *(const bf16x8*)(Arow_ + 2048);                            \
        bf16x8 g0 = *(const bf16x8*)(Brow_);                                   \
        bf16x8 g1 = *(const bf16x8*)(Brow_ + 2048);                            \
        bf16x8 g2 = *(const bf16x8*)(Brow_ + 4096);                            \
        bf16x8 g3 = *(const bf16x8*)(Brow_ + 6144);                            \
        c00 = MF(f0, g0, c00); c01 = MF(f0, g1, c01); c02 = MF(f0, g2, c02); c03 = MF(f0, g3, c03); \
        c10 = MF(f1, g0, c10); c11 = MF(f1, g1, c11); c12 = MF(f1, g2, c12); c13 = MF(f1, g3, c13); \
    }

#define GEMM_BODY_64B(Aptr, Bptr)                                              \
    int wave = tid >> 6, lane = tid & 63, quad = lane >> 4, c = lane & 15;     \
    int wr = wave >> 1, wc = wave & 1;                                         \
    int l4 = lane >> 4, l15 = lane & 15;                                       \
    const unsigned short* Abase = (Aptr) + (size_t)(rt * 64) * 1024;           \
    const unsigned short* Bbase = (Bptr) + (size_t)(ct * 128) * 1024;          \
    int aoff0 = (wave * 16 +  0 + l4) * 1024 + ((l15 ^ ( 0 + l4)) * 8);        \
    int aoff1 = (wave * 16 +  4 + l4) * 1024 + ((l15 ^ ( 4 + l4)) * 8);        \
    int aoff2 = (wave * 16 +  8 + l4) * 1024 + ((l15 ^ ( 8 + l4)) * 8);        \
    int aoff3 = (wave * 16 + 12 + l4) * 1024 + ((l15 ^ (12 + l4)) * 8);        \
    int boff0 = (wave * 32 +  0 + l4) * 1024 + ((l15 ^ (( 0 + l4) & 15)) * 8); \
    int boff1 = (wave * 32 +  4 + l4) * 1024 + ((l15 ^ (( 4 + l4) & 15)) * 8); \
    int boff2 = (wave * 32 +  8 + l4) * 1024 + ((l15 ^ (( 8 + l4) & 15)) * 8); \
    int boff3 = (wave * 32 + 12 + l4) * 1024 + ((l15 ^ ((12 + l4) & 15)) * 8); \
    int boff4 = (wave * 32 + 16 + l4) * 1024 + ((l15 ^ ((16 + l4) & 15)) * 8); \
    int boff5 = (wave * 32 + 20 + l4) * 1024 + ((l15 ^ ((20 + l4) & 15)) * 8); \
    int boff6 = (wave * 32 + 24 + l4) * 1024 + ((l15 ^ ((24 + l4) & 15)) * 8); \
    int boff7 = (wave * 32 + 28 + l4) * 1024 + ((l15 ^ ((28 + l4) & 15)) * 8); \
    unsigned short* AsW = As2 + wave * 2048;                                   \
    unsigned short* BsW = Bs2 + wave * 4096;                                   \
    f32x4 c00 = (f32x4)0.f, c01 = (f32x4)0.f, c02 = (f32x4)0.f, c03 = (f32x4)0.f; \
    f32x4 c10 = (f32x4)0.f, c11 = (f32x4)0.f, c12 = (f32x4)0.f, c13 = (f32x4)0.f; \
    for (int kt = 0; kt < 8; ++kt) {                                           \
        int k0 = kt * 128;                                                     \
        __syncthreads();                                                       \
        GLOAD16(Abase + aoff0 + k0, AsW);                                      \
        GLOAD16(Abase + aoff1 + k0, AsW + 512);                                \
        GLOAD16(Abase + aoff2 + k0, AsW + 1024);                               \
        GLOAD16(Abase + aoff3 + k0, AsW + 1536);                               \
        GLOAD16(Bbase + boff0 + k0, BsW);                                      \
        GLOAD16(Bbase + boff1 + k0, BsW + 512);                                \
        GLOAD16(Bbase + boff2 + k0, BsW + 1024);                               \
        GLOAD16(Bbase + boff3 + k0, BsW + 1536);                               \
        GLOAD16(Bbase + boff4 + k0, BsW + 2048);                               \
        GLOAD16(Bbase + boff5 + k0, BsW + 2560);                               \
        GLOAD16(Bbase + boff6 + k0, BsW + 3072);                               \
        GLOAD16(Bbase + boff7 + k0, BsW + 3584);                               \
        __syncthreads();                                                       \
        GEMM_KH2B(0)                                                           \
        GEMM_KH2B(1)                                                           \
        GEMM_KH2B(2)                                                           \
        GEMM_KH2B(3)                                                           \
    }

// ---------------------------------------------------------------------------
// QKV GEMM (R20): 64x128 tile, BK=64 dbuf, counted-vmcnt pipeline, fused RoPE.
// Q/K: (B,H,L,64) layout.  V: transposed (B,H,64,L) layout (R15).
// Grid 1536: XCD-contiguous swizzle, ct-major super-tiles (8ct x 4rt).
// LDS: A[2][64x64] + B[2][128x64] = 48 KB, unioned with C-bounce.
// ---------------------------------------------------------------------------
union alignas(16) SmemQD {
    struct { unsigned short A[2][64 * 64]; unsigned short B[2][128 * 64]; } ab;  // 48 KB
    unsigned short C[64 * CSTR];    // q/k bounce: 64 rows x 136
    unsigned short Ct[128 * 72];    // v bounce (transposed): 128 d-rows x 72
};

// stage one BK=64 tile into (pA,pB): A 64x64 (2 loads), B 128x64 (4 loads)
#define QSTAGE(pA, pB, k0)                                                     \
    GLOAD16(Ab + (k0),          (pA) + stW);                                   \
    GLOAD16(Ab + 32768 + (k0),  (pA) + stW + 2048);                            \
    GLOAD16(Bb + (k0),          (pB) + stW);                                   \
    GLOAD16(Bb + 32768 + (k0),  (pB) + stW + 2048);                            \
    GLOAD16(Bb + 65536 + (k0),  (pB) + stW + 4096);                            \
    GLOAD16(Bb + 98304 + (k0),  (pB) + stW + 6144);

// one K-half (K=32) of a BK=64 step on buffers (pA,pB): 6 frag loads + 8 MFMA
#define QKH(pA, pB, kh)                                                        \
    {                                                                          \
        int pofs = (((kh) * 4 + quad) ^ x7) * 8;                               \
        const unsigned short* Ar_ = (pA) + (wr * 32 + c) * 64 + pofs;          \
        const unsigned short* Br_ = (pB) + (wc * 64 + c) * 64 + pofs;          \
        bf16x8 f0 = *(const bf16x8*)(Ar_);                                     \
        bf16x8 f1 = *(const bf16x8*)(Ar_ + 1024);                              \
        bf16x8 g0 = *(const bf16x8*)(Br_);                                     \
        bf16x8 g1 = *(const bf16x8*)(Br_ + 1024);                              \
        bf16x8 g2 = *(const bf16x8*)(Br_ + 2048);                              \
        bf16x8 g3 = *(const bf16x8*)(Br_ + 3072);                              \
        c00 = MF(f0, g0, c00); c01 = MF(f0, g1, c01); c02 = MF(f0, g2, c02); c03 = MF(f0, g3, c03); \
        c10 = MF(f1, g0, c10); c11 = MF(f1, g1, c11); c12 = MF(f1, g2, c12); c13 = MF(f1, g3, c13); \
    }

#define QROPE_REG(i, reg, A0, A1, A2, A3)                                      \
    {                                                                          \
        int mloc = wr * 32 + (i) * 16 + quad * 4 + (reg);                      \
        int crow = mloc * CSTR + wc * 64;                                      \
        float fl = (float)((rt * 64 + mloc) & 511);                            \
        float aa0 = fl * inv0, aa1 = fl * inv1;                                \
        float c0 = cosf(aa0), s0 = sinf(aa0);                                  \
        float c1 = cosf(aa1), s1 = sinf(aa1);                                  \
        float e0 = A0[(reg)], o0 = A2[(reg)];                                  \
        float e1 = A1[(reg)], o1 = A3[(reg)];                                  \
        smemq.C[crow + c]      = f2bf(e0 * c0 - o0 * s0);                      \
        smemq.C[crow + 32 + c] = f2bf(e0 * s0 + o0 * c0);                      \
        smemq.C[crow + 16 + c] = f2bf(e1 * c1 - o1 * s1);                      \
        smemq.C[crow + 48 + c] = f2bf(e1 * s1 + o1 * c1);                      \
    }
#define QROPE_ROW(i, A0, A1, A2, A3)                                           \
    QROPE_REG(i, 0, A0, A1, A2, A3) QROPE_REG(i, 1, A0, A1, A2, A3)            \
    QROPE_REG(i, 2, A0, A1, A2, A3) QROPE_REG(i, 3, A0, A1, A2, A3)

// V: bounce transposed — Ct[dcol][l_local], stride 72
#define QVSECT_REG(i, j, reg, Acc)                                             \
    smemq.Ct[(wc * 64 + (j) * 16 + c) * 72 + (wr * 32 + (i) * 16 + quad * 4 + (reg))] = f2bf(Acc[(reg)]);
#define QVSECT_TILE(i, j, Acc)                                                 \
    QVSECT_REG(i, j, 0, Acc) QVSECT_REG(i, j, 1, Acc)                          \
    QVSECT_REG(i, j, 2, Acc) QVSECT_REG(i, j, 3, Acc)

__global__ __launch_bounds__(256, 1)
void qkv_gemm_mfma(const unsigned short* __restrict__ q_ln,
                   const unsigned short* __restrict__ kv_ln,
                   const unsigned short* __restrict__ Wb,
                   unsigned short* __restrict__ qo,
                   unsigned short* __restrict__ ko,
                   unsigned short* __restrict__ vo) {
    int bid = blockIdx.x;                     // 0..1535
    int wg = (bid & 7) * 192 + (bid >> 3);    // XCD-contiguous (bijective, 1536%8==0)
    int st = wg >> 5, in = wg & 31;           // 48 super-tiles of 32 blocks
    int stc = st >> 4, str = st & 15;         // ct-major: stc 0..2 (= section), str 0..15
    int ct = stc * 8 + (in & 7);              // 0..23
    int rt = str * 4 + (in >> 3);             // 0..63
    int n0 = ct * 128;
    int section = stc;                        // 0=q 1=k 2=v
    const unsigned short* A = (section == 0) ? q_ln : kv_ln;

    __shared__ SmemQD smemq;
    int tid = threadIdx.x;
    int wave = tid >> 6, lane = tid & 63, quad = lane >> 4, c = lane & 15;
    int wr = wave >> 1, wc = wave & 1;
    int x7 = c & 7;

    // staging source: thread t covers row t>>3, slot t&7 holds chunk (t&7)^((t>>3)&7)
    int soff = (tid >> 3) * 1024 + (((tid & 7) ^ ((tid >> 3) & 7)) * 8);
    const unsigned short* Ab = A + (size_t)(rt * 64) * 1024 + soff;
    const unsigned short* Bb = Wb + (size_t)n0 * 1024 + soff;
    int stW = wave * 512;
    unsigned short* A0 = smemq.ab.A[0];
    unsigned short* A1 = smemq.ab.A[1];
    unsigned short* B0 = smemq.ab.B[0];
    unsigned short* B1 = smemq.ab.B[1];

    f32x4 c00 = (f32x4)0.f, c01 = (f32x4)0.f, c02 = (f32x4)0.f, c03 = (f32x4)0.f;
    f32x4 c10 = (f32x4)0.f, c11 = (f32x4)0.f, c12 = (f32x4)0.f, c13 = (f32x4)0.f;

    // Counted-vmcnt dbuf pipeline (R20): 16 steps of BK=64.
    // Steady state: 12 loads in flight; wait only the older 6 (current buffer).
    QSTAGE(A0, B0, 0)
    QSTAGE(A1, B1, 64)
    VMW(6); RBAR();                               // buf0 ready
    for (int kt2 = 0; kt2 < 8; ++kt2) {
        QKH(A0, B0, 0) QKH(A0, B0, 1)             // compute even step 2*kt2
        RBAR();                                   // all waves done reading buf0
        if (kt2 < 7) { QSTAGE(A0, B0, (kt2 * 2 + 2) * 64) VMW(6); }
        else         { VMW(0); }                  // last odd step's loads must land
        RBAR();                                   // buf1 ready
        QKH(A1, B1, 0) QKH(A1, B1, 1)             // compute odd step 2*kt2+1
        RBAR();                                   // all waves done reading buf1
        if (kt2 < 7) { QSTAGE(A1, B1, (kt2 * 2 + 3) * 64) VMW(6); }
        RBAR();                                   // buf0 ready (next iter)
    }

    // epilogue (union reuse; trailing RBAR above guarantees no wave still reads A/B)
    if (section == 2) {
        QVSECT_TILE(0, 0, c00) QVSECT_TILE(0, 1, c01) QVSECT_TILE(0, 2, c02) QVSECT_TILE(0, 3, c03)
        QVSECT_TILE(1, 0, c10) QVSECT_TILE(1, 1, c11) QVSECT_TILE(1, 2, c12) QVSECT_TILE(1, 3, c13)
        __syncthreads();
        // store: 128 d-rows x 64 contiguous l
        int dr = tid >> 1, hh = tid & 1;
        int h = ((n0 & 1023) >> 6) + (dr >> 6);
        int d = dr & 63;
        int mmb = rt * 64;
        int bb = mmb >> 9, ll0 = mmb & 511;
        unsigned short* orow = vo + (((size_t)bb * NHEADS + h) * HDIM + d) * SEQ + ll0 + hh * 32;
        const unsigned short* csrc = &smemq.Ct[dr * 72 + hh * 32];
        #pragma unroll
        for (int kc = 0; kc < 4; ++kc)
            *(u16x8*)(orow + kc * 8) = *(const u16x8*)(csrc + kc * 8);
        return;
    }

    float inv0 = expf(-0.2878231366f * (float)c);          // 10000^(-c/32)
    float inv1 = expf(-0.2878231366f * (float)(16 + c));
    QROPE_ROW(0, c00, c01, c02, c03)
    QROPE_ROW(1, c10, c11, c12, c13)
    __syncthreads();

    unsigned short* outp = (section == 0) ? qo : ko;
    int rr = tid >> 2;                  // row 0..63
    int ch = (tid >> 1) & 1;            // head-half 0/1
    int sub = tid & 1;                  // 32-short half within head
    int mm = rt * 64 + rr;
    int bb = mm >> 9, ll = mm & 511;
    int h = ((n0 & 1023) >> 6) + ch;
    unsigned short* orow = outp + (((size_t)bb * NHEADS + h) * SEQ + ll) * HDIM + sub * 32;
    const unsigned short* csrc = &smemq.C[rr * CSTR + ch * 64 + sub * 32];
    #pragma unroll
    for (int kc = 0; kc < 4; ++kc)
        *(u16x8*)(orow + kc * 8) = *(const u16x8*)(csrc + kc * 8);
}

// ---------------------------------------------------------------------------
// Projection 1 (MFMA, 64x128 tile, BK=128): t = att @ Wout^T + b_out -> bf16
// grid (8, 64) = 512 blocks
// ---------------------------------------------------------------------------
#define O1_REG(mb, reg, n, Acc)                                                \
    t_bf[(size_t)((mb) + (reg)) * 1024 + (n)] = f2bf(Acc[(reg)] + bo);
#define O1_TILE(i, j, Acc)                                                     \
    {                                                                          \
        int n = ct * 128 + wc * 64 + (j) * 16 + c;                             \
        float bo = b_out[n];                                                   \
        int mb = rt * 64 + wr * 32 + (i) * 16 + quad * 4;                      \
        O1_REG(mb, 0, n, Acc) O1_REG(mb, 1, n, Acc)                            \
        O1_REG(mb, 2, n, Acc) O1_REG(mb, 3, n, Acc)                            \
    }

__global__ __launch_bounds__(256, 1)
void out_gemm1_mfma(const unsigned short* __restrict__ att,
                    const unsigned short* __restrict__ Wob,
                    const float* __restrict__ b_out,
                    unsigned short* __restrict__ t_bf) {
    int ct = blockIdx.x, rt = blockIdx.y;
    __shared__ Smem64B smem2;
    unsigned short* As2 = smem2.A;
    unsigned short* Bs2 = smem2.B;
    int tid = threadIdx.x;

    GEMM_BODY_64B(att, Wob)

    O1_TILE(0, 0, c00) O1_TILE(0, 1, c01) O1_TILE(0, 2, c02) O1_TILE(0, 3, c03)
    O1_TILE(1, 0, c10) O1_TILE(1, 1, c11) O1_TILE(1, 2, c12) O1_TILE(1, 3, c13)
}

// ---------------------------------------------------------------------------
// Projection 2 (MFMA, 64x128 tile, BK=128): gz = t_bf @ Wgate^T + b_gate;
// out = sigmoid(gz)*t + (1-sigmoid)*residual   (t read back as bf16)
// ---------------------------------------------------------------------------
#define O2_REG(mb, reg, n, Acc)                                                \
    {                                                                          \
        float gz = Acc[(reg)] + bg;                                            \
        float g = 1.0f / (1.0f + expf(-gz));                                   \
        size_t idx = (size_t)((mb) + (reg)) * 1024 + (n);                      \
        float tv = bf2f(t_bf[idx]);                                            \
        float rv = residual[idx];                                              \
        out[idx] = g * tv + (1.0f - g) * rv;                                   \
    }
#define O2_TILE(i, j, Acc)                                                     \
    {                                                                          \
        int n = ct * 128 + wc * 64 + (j) * 16 + c;                             \
        float bg = b_gate[n];                                                  \
        int mb = rt * 64 + wr * 32 + (i) * 16 + quad * 4;                      \
        O2_REG(mb, 0, n, Acc) O2_REG(mb, 1, n, Acc)                            \
        O2_REG(mb, 2, n, Acc) O2_REG(mb, 3, n, Acc)                            \
    }

__global__ __launch_bounds__(256, 1)
void out_gemm2_mfma(const unsigned short* __restrict__ t_bf,
                    const unsigned short* __restrict__ Wgb,
                    const float* __restrict__ b_gate,
                    const float* __restrict__ residual,
                    float* __restrict__ out) {
    int ct = blockIdx.x, rt = blockIdx.y;
    __shared__ Smem64B smem2;
    unsigned short* As2 = smem2.A;
    unsigned short* Bs2 = smem2.B;
    int tid = threadIdx.x;

    GEMM_BODY_64B(t_bf, Wgb)

    O2_TILE(0, 0, c00) O2_TILE(0, 1, c01) O2_TILE(0, 2, c02) O2_TILE(0, 3, c03)
    O2_TILE(1, 0, c10) O2_TILE(1, 1, c11) O2_TILE(1, 2, c12) O2_TILE(1, 3, c13)
}

// ---------------------------------------------------------------------------
// Flash attention (R20), bf16 MFMA (16x16x32). 128-row Q tile, 8 waves.
// R12: unnormalized streaming softmax. R15: K/Vt via global_load_lds + XOR
// swizzle. R18: KVBLK stays 64. R20: Ks/Vs double-buffered + counted vmcnt(2)
// pipeline (raw s_barrier); Ps/lf are same-wave-ordered, unchanged.
// LDS 51 KB -> still 2 blocks/CU (grid 512 = 2/CU).
// ---------------------------------------------------------------------------
#define KSTR 72   // Ps stride only

static __device__ __forceinline__ void attn_step(
    const unsigned short* __restrict__ KsB, const unsigned short* __restrict__ VsB,
    int kv0, const float* __restrict__ bias, unsigned short* __restrict__ Ps,
    int q0, int wb, int quad, int c, int p0, int p1,
    bf16x8 aq0, bf16x8 aq1, f32x4 (&oacc)[4], float (&lrow)[4])
{
    f32x4 sacc[4];
    #pragma unroll
    for (int nt = 0; nt < 4; ++nt) {
        const unsigned short* kbase = &KsB[(nt * 16 + c) * 64];
        bf16x8 b0 = *(const bf16x8*)(kbase + p0);
        bf16x8 b1 = *(const bf16x8*)(kbase + p1);
        f32x4 a = (f32x4)0.f;
        a = __builtin_amdgcn_mfma_f32_16x16x32_bf16(aq0, b0, a, 0, 0, 0);
        a = __builtin_amdgcn_mfma_f32_16x16x32_bf16(aq1, b1, a, 0, 0, 0);
        sacc[nt] = a;
    }
    const float* bbase = bias + (size_t)(q0 + wb + quad * 4) * 512 + kv0 + c;
    float tsum[4];
    #pragma unroll
    for (int r = 0; r < 4; ++r) tsum[r] = 0.f;
    #pragma unroll
    for (int nt = 0; nt < 4; ++nt)
        #pragma unroll
        for (int r = 0; r < 4; ++r) {
            float p = __expf(sacc[nt][r] * SCALE + bbase[(size_t)r * 512 + nt * 16]);
            tsum[r] += p;
            Ps[(wb + quad * 4 + r) * KSTR + nt * 16 + c] = f2bf(p);
        }
    #pragma unroll
    for (int r = 0; r < 4; ++r) {
        float t = tsum[r];
        t += __shfl_xor(t, 1);
        t += __shfl_xor(t, 2);
        t += __shfl_xor(t, 4);
        t += __shfl_xor(t, 8);
        lrow[r] += t;
    }
    bf16x8 pb0 = *(const bf16x8*)&Ps[(wb + c) * KSTR + quad * 8];
    bf16x8 pb1 = *(const bf16x8*)&Ps[(wb + c) * KSTR + 32 + quad * 8];
    #pragma unroll
    for (int t = 0; t < 4; ++t) {
        const unsigned short* vbase = &VsB[(t * 16 + c) * 64];
        bf16x8 a0 = *(const bf16x8*)(vbase + p0);
        bf16x8 a1 = *(const bf16x8*)(vbase + p1);
        oacc[t] = __builtin_amdgcn_mfma_f32_16x16x32_bf16(a0, pb0, oacc[t], 0, 0, 0);
        oacc[t] = __builtin_amdgcn_mfma_f32_16x16x32_bf16(a1, pb1, oacc[t], 0, 0, 0);
    }
}

// stage KV tile kvt into buffer BUF (2 loads/lane)
#define ASTAGE(BUF, kvt)                                                       \
    GLOAD16(kgb + (size_t)((kvt) * 64) * HDIM, Ks[BUF] + wave * 512);          \
    GLOAD16(vgb + (kvt) * 64, Vs[BUF] + wave * 512);

__global__ __launch_bounds__(512)
void attn_kernel(const unsigned short* __restrict__ q,
                 const unsigned short* __restrict__ k,
                 const unsigned short* __restrict__ vt,
                 const float* __restrict__ bias,
                 unsigned short* __restrict__ attended) {
    int qt = blockIdx.x, h = blockIdx.y, b = blockIdx.z;
    __shared__ unsigned short Ks[2][64 * 64];
    __shared__ unsigned short Vs[2][64 * 64];
    __shared__ unsigned short Ps[128 * KSTR];
    __shared__ float lf[128];

    int tid = threadIdx.x;
    int wave = tid >> 6, lane = tid & 63;   // wave 0..7
    int quad = lane >> 4, c = lane & 15;
    int wb = wave * 16;                     // wave's q-row base, 0..112
    size_t headbase = (((size_t)b * NHEADS + h) * SEQ) * HDIM;  // == (b*16+h)*32768
    int q0 = qt * 128;

    const unsigned short* qrow = q + headbase + (size_t)(q0 + wb + c) * HDIM;
    bf16x8 aq0 = *(const bf16x8*)(qrow + quad * 8);
    bf16x8 aq1 = *(const bf16x8*)(qrow + 32 + quad * 8);

    // staging: wave w covers rows w*8..w*8+7 (8 rows x 64 shorts = 1 GLOAD16/lane)
    int srow = wave * 8 + (lane >> 3);
    int schunk = (lane & 7) ^ (srow & 7);
    const unsigned short* kgb = k + headbase + (size_t)srow * HDIM + schunk * 8;
    const unsigned short* vgb = vt + headbase + (size_t)srow * SEQ + schunk * 8;
    int x7 = c & 7;
    int p0 = (quad ^ x7) * 8;
    int p1 = ((4 + quad) ^ x7) * 8;

    f32x4 oacc[4];
    #pragma unroll
    for (int t = 0; t < 4; ++t) oacc[t] = (f32x4)0.f;
    float lrow[4];
    #pragma unroll
    for (int r = 0; r < 4; ++r) lrow[r] = 0.f;

    // Counted-vmcnt dbuf pipeline: 8 KV tiles of 64, 2 loads/stage.
    ASTAGE(0, 0)
    ASTAGE(1, 1)
    VMW(2); RBAR();                               // tile0 ready (Q loads also drained)
    for (int kt2 = 0; kt2 < 4; ++kt2) {
        attn_step(Ks[0], Vs[0], (kt2 * 2) * 64, bias, Ps,
                  q0, wb, quad, c, p0, p1, aq0, aq1, oacc, lrow);
        RBAR();                                   // all waves done reading buf0
        if (kt2 < 3) { ASTAGE(0, kt2 * 2 + 2) VMW(2); }
        else         { VMW(0); }                  // tile7's loads must land
        RBAR();                                   // buf1 ready
        attn_step(Ks[1], Vs[1], (kt2 * 2 + 1) * 64, bias, Ps,
                  q0, wb, quad, c, p0, p1, aq0, aq1, oacc, lrow);
        RBAR();                                   // all waves done reading buf1
        if (kt2 < 3) { ASTAGE(1, kt2 * 2 + 3) VMW(2); }
        RBAR();                                   // buf0 ready (next iter)
    }

    if (c == 0) {
        f32x4 lv;
        lv[0] = lrow[0]; lv[1] = lrow[1]; lv[2] = lrow[2]; lv[3] = lrow[3];
        *(f32x4*)&lf[wb + quad * 4] = lv;
    }
    float invl = 1.0f / lf[wb + c];
    unsigned short* drow = attended + ((size_t)b * SEQ + (q0 + wb + c)) * D_MODEL + h * HDIM;
    #pragma unroll
    for (int t = 0; t < 4; ++t) {
        ushort4 o;
        o.x = f2bf(oacc[t][0] * invl);
        o.y = f2bf(oacc[t][1] * invl);
        o.z = f2bf(oacc[t][2] * invl);
        o.w = f2bf(oacc[t][3] * invl);
        *(ushort4*)(drow + t * 16 + quad * 4) = o;
    }
}

extern "C" void kernel_launch(void* const* d_in, const int* in_sizes, int n_in,
                              void* d_out, int out_size, void* d_ws, size_t ws_size,
                              hipStream_t stream) {
    const float* dec    = (const float*)d_in[0];
    const float* enc    = (const float*)d_in[1];
    const float* Wqkv   = (const float*)d_in[2];
    const float* Wout   = (const float*)d_in[3];
    const float* b_out  = (const float*)d_in[4];
    const float* Wgate  = (const float*)d_in[5];
    const float* b_gate = (const float*)d_in[6];
    const float* gamma  = (const float*)d_in[7];
    const float* beta   = (const float*)d_in[8];
    float* out = (float*)d_out;

    char* ws = (char*)d_ws;
    const size_t MB = 1024 * 1024;
    unsigned short* q_ln    = (unsigned short*)(ws + 0 * MB);
    unsigned short* kv_ln   = (unsigned short*)(ws + 8 * MB);
    unsigned short* qb      = (unsigned short*)(ws + 16 * MB);
    unsigned short* kb      = (unsigned short*)(ws + 24 * MB);
    unsigned short* vb      = (unsigned short*)(ws + 32 * MB);   // V^T (B,H,64,L)
    unsigned short* Wqkv_bf = (unsigned short*)(ws + 40 * MB);
    float*          bias    = (float*)(ws + 46 * MB);
    unsigned short* att     = (unsigned short*)(ws + 0 * MB);    // q_ln dead after qkv
    unsigned short* t_bf    = (unsigned short*)(ws + 24 * MB);   // kb dead after attn

    // Hoisted weight-convert needs 4 MB of never-aliased space at 47..51 MB.
    bool hoist = (ws_size >= 51 * MB);
    unsigned short* Wout_bf  = (unsigned short*)(ws + (hoist ? 47 * MB : 32 * MB));
    unsigned short* Wgate_bf = (unsigned short*)(ws + (hoist ? 49 * MB : 34 * MB));

    prep_kernel<<<hoist ? 14336 : 12288, 256, 0, stream>>>(
        dec, enc, gamma, beta, Wqkv, Wout, Wgate,
        q_ln, kv_ln, bias, Wqkv_bf, Wout_bf, Wgate_bf);
    qkv_gemm_mfma<<<1536, 256, 0, stream>>>(q_ln, kv_ln, Wqkv_bf, qb, kb, vb);
    attn_kernel<<<dim3(4, 16, 8), 512, 0, stream>>>(qb, kb, vb, bias, att);
    if (!hoist)
        convert_og<<<2048, 256, 0, stream>>>(Wout, Wgate, Wout_bf, Wgate_bf);
    out_gemm1_mfma<<<dim3(8, 64), 256, 0, stream>>>(att, Wout_bf, b_out, t_bf);
    out_gemm2_mfma<<<dim3(8, 64), 256, 0, stream>>>(t_bf, Wgate_bf, b_gate, dec, out);
}

// Round 7
// 207.828 us; speedup vs baseline: 1.8078x; 1.0022x over previous
//
#include <hip/hip_runtime.h>
#include <hip/hip_bf16.h>

#define D_MODEL 1024
#define NHEADS 16
#define HDIM 64
#define BATCH 8
#define SEQ 512
#define NROWS 4096          // BATCH*SEQ
#define SCALE 0.125f
#define LN_EPS 1e-5f

typedef __attribute__((ext_vector_type(8))) short bf16x8;      // 8 bf16 (4 VGPRs)
typedef __attribute__((ext_vector_type(4))) float f32x4;
typedef __attribute__((ext_vector_type(8))) unsigned short u16x8;

static __device__ __forceinline__ float bf2f(unsigned short u) {
    return __uint_as_float(((unsigned int)u) << 16);
}
static __device__ __forceinline__ unsigned short f2bf(float f) {
    unsigned int x = __float_as_uint(f);
    unsigned int r = (x + 0x7fffu + ((x >> 16) & 1u)) >> 16;   // RNE
    return (unsigned short)r;
}

// async 16B/lane global->LDS DMA; LDS dest = wave-uniform base + lane*16
#define GLOAD16(gp, lp)                                                        \
    __builtin_amdgcn_global_load_lds(                                          \
        (const __attribute__((address_space(1))) void*)(gp),                   \
        (__attribute__((address_space(3))) void*)(lp), 16, 0, 0)

// R20: counted-vmcnt pipeline primitives (kept for attn).
#define VMW(n) asm volatile("s_waitcnt vmcnt(" #n ")" ::: "memory")
#define RBAR() __builtin_amdgcn_s_barrier()

// ---------------------------------------------------------------------------
// Bias helper: jax.image.resize(bias128, (512,512), 'bilinear')
// ---------------------------------------------------------------------------
static __device__ __forceinline__ float bias128(int a, int b) {
    float d = fabsf((float)(a - b));
    return expf(-d * 0.1f) - d * 0.05f;
}

// ---------------------------------------------------------------------------
// prep_kernel: fused LN (blocks 0..8191) + bias table (8192..9215) +
// Wqkv convert (9216..12287) + [hoisted Wout/Wgate convert (12288..14335)]
// ---------------------------------------------------------------------------
__global__ void prep_kernel(const float* __restrict__ dec, const float* __restrict__ enc,
                            const float* __restrict__ gamma, const float* __restrict__ beta,
                            const float* __restrict__ Wqkv,
                            const float* __restrict__ Wout, const float* __restrict__ Wgate,
                            unsigned short* __restrict__ q_ln, unsigned short* __restrict__ kv_ln,
                            float* __restrict__ bias, unsigned short* __restrict__ Wqkv_bf,
                            unsigned short* __restrict__ Wout_bf, unsigned short* __restrict__ Wgate_bf) {
    int blk = blockIdx.x;
    int t = threadIdx.x;
    if (blk >= 12288) {         // hoisted Wout/Wgate convert (only when launched)
        int idx = (blk - 12288) * 256 + t;
        const float* src; unsigned short* dst; int off;
        if (idx < 262144) { src = Wout; dst = Wout_bf; off = idx; }
        else              { src = Wgate; dst = Wgate_bf; off = idx - 262144; }
        float4 v = ((const float4*)src)[off];
        ushort4 u;
        u.x = f2bf(v.x); u.y = f2bf(v.y); u.z = f2bf(v.z); u.w = f2bf(v.w);
        ((ushort4*)dst)[off] = u;
        return;
    }
    if (blk >= 9216) {          // Wqkv convert
        int idx = (blk - 9216) * 256 + t;
        float4 v = ((const float4*)Wqkv)[idx];
        ushort4 u;
        u.x = f2bf(v.x); u.y = f2bf(v.y); u.z = f2bf(v.z); u.w = f2bf(v.w);
        ((ushort4*)Wqkv_bf)[idx] = u;
        return;
    }
    if (blk >= 8192) {          // bias
        int idx = (blk - 8192) * 256 + t;
        int qi = idx >> 9, kj = idx & 511;
        float fq = (qi + 0.5f) * 0.25f - 0.5f;
        float fk = (kj + 0.5f) * 0.25f - 0.5f;
        int iq = (int)floorf(fq); float tq = fq - (float)iq;
        int ik = (int)floorf(fk); float tk = fk - (float)ik;
        int iq0 = min(max(iq, 0), 127), iq1 = min(max(iq + 1, 0), 127);
        int ik0 = min(max(ik, 0), 127), ik1 = min(max(ik + 1, 0), 127);
        float v = (1.f - tq) * ((1.f - tk) * bias128(iq0, ik0) + tk * bias128(iq0, ik1))
                +        tq  * ((1.f - tk) * bias128(iq1, ik0) + tk * bias128(iq1, ik1));
        bias[idx] = v;
        return;
    }
    int row = blk;
    const float* src = (row < NROWS) ? dec + (size_t)row * D_MODEL
                                     : enc + (size_t)(row - NROWS) * D_MODEL;
    unsigned short* dst = (row < NROWS) ? q_ln + (size_t)row * D_MODEL
                                        : kv_ln + (size_t)(row - NROWS) * D_MODEL;
    float4 x = ((const float4*)src)[t];
    float s  = x.x + x.y + x.z + x.w;
    float ss = x.x * x.x + x.y * x.y + x.z * x.z + x.w * x.w;
    #pragma unroll
    for (int off = 32; off > 0; off >>= 1) {
        s  += __shfl_down(s, off);
        ss += __shfl_down(ss, off);
    }
    __shared__ float red_s[4], red_ss[4];
    int wid = t >> 6, lane = t & 63;
    if (lane == 0) { red_s[wid] = s; red_ss[wid] = ss; }
    __syncthreads();
    if (t == 0) {
        float S = red_s[0] + red_s[1] + red_s[2] + red_s[3];
        float SS = red_ss[0] + red_ss[1] + red_ss[2] + red_ss[3];
        red_s[0] = S; red_ss[0] = SS;
    }
    __syncthreads();
    float mu  = red_s[0] * (1.0f / 1024.0f);
    float var = red_ss[0] * (1.0f / 1024.0f) - mu * mu;
    float rstd = rsqrtf(var + LN_EPS);
    float4 g = ((const float4*)gamma)[t];
    float4 bb = ((const float4*)beta)[t];
    ushort4 u;
    u.x = f2bf((x.x - mu) * rstd * g.x + bb.x);
    u.y = f2bf((x.y - mu) * rstd * g.y + bb.y);
    u.z = f2bf((x.z - mu) * rstd * g.z + bb.z);
    u.w = f2bf((x.w - mu) * rstd * g.w + bb.w);
    ((ushort4*)dst)[t] = u;
}

// ---------------------------------------------------------------------------
// Wout + Wgate fp32 -> bf16 (fallback path when ws too small to hoist)
// ---------------------------------------------------------------------------
__global__ void convert_og(const float* __restrict__ Wout, const float* __restrict__ Wgate,
                           unsigned short* __restrict__ Wout_bf, unsigned short* __restrict__ Wgate_bf) {
    int idx = blockIdx.x * 256 + threadIdx.x;
    const float* src; unsigned short* dst; int off;
    if (idx < 262144) { src = (const float*)Wout; dst = Wout_bf; off = idx; }
    else              { src = (const float*)Wgate; dst = Wgate_bf; off = idx - 262144; }
    float4 v = ((const float4*)src)[off];
    ushort4 u;
    u.x = f2bf(v.x); u.y = f2bf(v.y); u.z = f2bf(v.z); u.w = f2bf(v.w);
    ((ushort4*)dst)[off] = u;
}

// ===========================================================================
// MFMA GEMM cores (bf16). Permanent lessons:
// R7/R16: accumulators and frags NAMED scalars (arrays spill to scratch).
// R9: global_load_lds + XOR swizzle (0 conflicts).
// R17: 128^2 tile latency-bound at K=1024. R18: attn KVBLK=128 regressed.
// R19: XCD ct-major swizzle: FETCH 73->30MB (kept).
// R20 NULL on qkv: counted-vmcnt dbuf == drain0 dbuf == R0 (49us all) —
// in-block pipelining is NOT the qkv limiter.
// R21 (this round): qkv LDS 48KB -> 24KB (single-buffer BK=64) so 6 blocks/CU
// fit (grid 1536 = 6/CU, 24 waves/CU): cross-block TLP hides the per-block
// barrier stalls (m114 mechanism). Occupancy was 22% with 48KB.
// ===========================================================================
#define CSTR 136   // C-bounce row stride (multiple of 8 -> 16B-aligned rows)

struct alignas(16) Smem64B {
    unsigned short A[64 * 128];     // 16 KB
    unsigned short B[128 * 128];    // 32 KB
};

#define MF(a, b, d) __builtin_amdgcn_mfma_f32_16x16x32_bf16((a), (b), (d), 0, 0, 0)

#define GEMM_KH2B(kh)                                                          \
    {                                                                          \
        int pofs = (((kh) * 4 + quad) ^ c) * 8;                                \
        const unsigned short* Arow_ = &As2[(wr * 32 + c) * 128 + pofs];        \
        const unsigned short* Brow_ = &Bs2[(wc * 64 + c) * 128 + pofs];        \
        bf16x8 f0 = *(const bf16x8*)(Arow_);                                   \
        bf16x8 f1 = *(const bf16x8*)(Arow_ + 2048);                            \
        bf16x8 g0 = *(const bf16x8*)(Brow_);                                   \
        bf16x8 g1 = *(const bf16x8*)(Brow_ + 2048);                            \
        bf16x8 g2 = *(const bf16x8*)(Brow_ + 4096);                            \
        bf16x8 g3 = *(const bf16x8*)(Brow_ + 6144);                            \
        c00 = MF(f0, g0, c00); c01 = MF(f0, g1, c01); c02 = MF(f0, g2, c02); c03 = MF(f0, g3, c03); \
        c10 = MF(f1, g0, c10); c11 = MF(f1, g1, c11); c12 = MF(f1, g2, c12); c13 = MF(f1, g3, c13); \
    }

#define GEMM_BODY_64B(Aptr, Bptr)                                              \
    int wave = tid >> 6, lane = tid & 63, quad = lane >> 4, c = lane & 15;     \
    int wr = wave >> 1, wc = wave & 1;                                         \
    int l4 = lane >> 4, l15 = lane & 15;                                       \
    const unsigned short* Abase = (Aptr) + (size_t)(rt * 64) * 1024;           \
    const unsigned short* Bbase = (Bptr) + (size_t)(ct * 128) * 1024;          \
    int aoff0 = (wave * 16 +  0 + l4) * 1024 + ((l15 ^ ( 0 + l4)) * 8);        \
    int aoff1 = (wave * 16 +  4 + l4) * 1024 + ((l15 ^ ( 4 + l4)) * 8);        \
    int aoff2 = (wave * 16 +  8 + l4) * 1024 + ((l15 ^ ( 8 + l4)) * 8);        \
    int aoff3 = (wave * 16 + 12 + l4) * 1024 + ((l15 ^ (12 + l4)) * 8);        \
    int boff0 = (wave * 32 +  0 + l4) * 1024 + ((l15 ^ (( 0 + l4) & 15)) * 8); \
    int boff1 = (wave * 32 +  4 + l4) * 1024 + ((l15 ^ (( 4 + l4) & 15)) * 8); \
    int boff2 = (wave * 32 +  8 + l4) * 1024 + ((l15 ^ (( 8 + l4) & 15)) * 8); \
    int boff3 = (wave * 32 + 12 + l4) * 1024 + ((l15 ^ ((12 + l4) & 15)) * 8); \
    int boff4 = (wave * 32 + 16 + l4) * 1024 + ((l15 ^ ((16 + l4) & 15)) * 8); \
    int boff5 = (wave * 32 + 20 + l4) * 1024 + ((l15 ^ ((20 + l4) & 15)) * 8); \
    int boff6 = (wave * 32 + 24 + l4) * 1024 + ((l15 ^ ((24 + l4) & 15)) * 8); \
    int boff7 = (wave * 32 + 28 + l4) * 1024 + ((l15 ^ ((28 + l4) & 15)) * 8); \
    unsigned short* AsW = As2 + wave * 2048;                                   \
    unsigned short* BsW = Bs2 + wave * 4096;                                   \
    f32x4 c00 = (f32x4)0.f, c01 = (f32x4)0.f, c02 = (f32x4)0.f, c03 = (f32x4)0.f; \
    f32x4 c10 = (f32x4)0.f, c11 = (f32x4)0.f, c12 = (f32x4)0.f, c13 = (f32x4)0.f; \
    for (int kt = 0; kt < 8; ++kt) {                                           \
        int k0 = kt * 128;                                                     \
        __syncthreads();                                                       \
        GLOAD16(Abase + aoff0 + k0, AsW);                                      \
        GLOAD16(Abase + aoff1 + k0, AsW + 512);                                \
        GLOAD16(Abase + aoff2 + k0, AsW + 1024);                               \
        GLOAD16(Abase + aoff3 + k0, AsW + 1536);                               \
        GLOAD16(Bbase + boff0 + k0, BsW);                                      \
        GLOAD16(Bbase + boff1 + k0, BsW + 512);                                \
        GLOAD16(Bbase + boff2 + k0, BsW + 1024);                               \
        GLOAD16(Bbase + boff3 + k0, BsW + 1536);                               \
        GLOAD16(Bbase + boff4 + k0, BsW + 2048);                               \
        GLOAD16(Bbase + boff5 + k0, BsW + 2560);                               \
        GLOAD16(Bbase + boff6 + k0, BsW + 3072);                               \
        GLOAD16(Bbase + boff7 + k0, BsW + 3584);                               \
        __syncthreads();                                                       \
        GEMM_KH2B(0)                                                           \
        GEMM_KH2B(1)                                                           \
        GEMM_KH2B(2)                                                           \
        GEMM_KH2B(3)                                                           \
    }

// ---------------------------------------------------------------------------
// QKV GEMM (R21): 64x128 tile, BK=64 SINGLE-buffer (24 KB LDS -> 6 blocks/CU),
// fused RoPE. Q/K: (B,H,L,64). V: transposed (B,H,64,L) (R15).
// Grid 1536: XCD-contiguous swizzle, ct-major super-tiles (8ct x 4rt).
// ---------------------------------------------------------------------------
union alignas(16) SmemQS {
    struct { unsigned short A[64 * 64]; unsigned short B[128 * 64]; } ab;  // 24 KB
    unsigned short C[64 * CSTR];    // q/k bounce: 64 rows x 136 (17.4 KB)
    unsigned short Ct[128 * 72];    // v bounce (transposed): 128 d-rows x 72 (18.4 KB)
};

// one K-half (K=32) of a BK=64 step: 6 frag loads + 8 MFMA
#define QKH(pA, pB, kh)                                                        \
    {                                                                          \
        int pofs = (((kh) * 4 + quad) ^ x7) * 8;                               \
        const unsigned short* Ar_ = (pA) + (wr * 32 + c) * 64 + pofs;          \
        const unsigned short* Br_ = (pB) + (wc * 64 + c) * 64 + pofs;          \
        bf16x8 f0 = *(const bf16x8*)(Ar_);                                     \
        bf16x8 f1 = *(const bf16x8*)(Ar_ + 1024);                              \
        bf16x8 g0 = *(const bf16x8*)(Br_);                                     \
        bf16x8 g1 = *(const bf16x8*)(Br_ + 1024);                              \
        bf16x8 g2 = *(const bf16x8*)(Br_ + 2048);                              \
        bf16x8 g3 = *(const bf16x8*)(Br_ + 3072);                              \
        c00 = MF(f0, g0, c00); c01 = MF(f0, g1, c01); c02 = MF(f0, g2, c02); c03 = MF(f0, g3, c03); \
        c10 = MF(f1, g0, c10); c11 = MF(f1, g1, c11); c12 = MF(f1, g2, c12); c13 = MF(f1, g3, c13); \
    }

#define QROPE_REG(i, reg, A0, A1, A2, A3)                                      \
    {                                                                          \
        int mloc = wr * 32 + (i) * 16 + quad * 4 + (reg);                      \
        int crow = mloc * CSTR + wc * 64;                                      \
        float fl = (float)((rt * 64 + mloc) & 511);                            \
        float aa0 = fl * inv0, aa1 = fl * inv1;                                \
        float c0 = cosf(aa0), s0 = sinf(aa0);                                  \
        float c1 = cosf(aa1), s1 = sinf(aa1);                                  \
        float e0 = A0[(reg)], o0 = A2[(reg)];                                  \
        float e1 = A1[(reg)], o1 = A3[(reg)];                                  \
        smemq.C[crow + c]      = f2bf(e0 * c0 - o0 * s0);                      \
        smemq.C[crow + 32 + c] = f2bf(e0 * s0 + o0 * c0);                      \
        smemq.C[crow + 16 + c] = f2bf(e1 * c1 - o1 * s1);                      \
        smemq.C[crow + 48 + c] = f2bf(e1 * s1 + o1 * c1);                      \
    }
#define QROPE_ROW(i, A0, A1, A2, A3)                                           \
    QROPE_REG(i, 0, A0, A1, A2, A3) QROPE_REG(i, 1, A0, A1, A2, A3)            \
    QROPE_REG(i, 2, A0, A1, A2, A3) QROPE_REG(i, 3, A0, A1, A2, A3)

// V: bounce transposed — Ct[dcol][l_local], stride 72
#define QVSECT_REG(i, j, reg, Acc)                                             \
    smemq.Ct[(wc * 64 + (j) * 16 + c) * 72 + (wr * 32 + (i) * 16 + quad * 4 + (reg))] = f2bf(Acc[(reg)]);
#define QVSECT_TILE(i, j, Acc)                                                 \
    QVSECT_REG(i, j, 0, Acc) QVSECT_REG(i, j, 1, Acc)                          \
    QVSECT_REG(i, j, 2, Acc) QVSECT_REG(i, j, 3, Acc)

__global__ __launch_bounds__(256, 6)
void qkv_gemm_mfma(const unsigned short* __restrict__ q_ln,
                   const unsigned short* __restrict__ kv_ln,
                   const unsigned short* __restrict__ Wb,
                   unsigned short* __restrict__ qo,
                   unsigned short* __restrict__ ko,
                   unsigned short* __restrict__ vo) {
    int bid = blockIdx.x;                     // 0..1535
    int wg = (bid & 7) * 192 + (bid >> 3);    // XCD-contiguous (bijective, 1536%8==0)
    int st = wg >> 5, in = wg & 31;           // 48 super-tiles of 32 blocks
    int stc = st >> 4, str = st & 15;         // ct-major: stc 0..2 (= section), str 0..15
    int ct = stc * 8 + (in & 7);              // 0..23
    int rt = str * 4 + (in >> 3);             // 0..63
    int n0 = ct * 128;
    int section = stc;                        // 0=q 1=k 2=v
    const unsigned short* A = (section == 0) ? q_ln : kv_ln;

    __shared__ SmemQS smemq;
    unsigned short* As2 = smemq.ab.A;
    unsigned short* Bs2 = smemq.ab.B;
    int tid = threadIdx.x;
    int wave = tid >> 6, lane = tid & 63, quad = lane >> 4, c = lane & 15;
    int wr = wave >> 1, wc = wave & 1;
    int x7 = c & 7;

    // staging source: thread t covers row t>>3, slot t&7 holds chunk (t&7)^((t>>3)&7)
    int soff = (tid >> 3) * 1024 + (((tid & 7) ^ ((tid >> 3) & 7)) * 8);
    const unsigned short* Ab = A + (size_t)(rt * 64) * 1024 + soff;
    const unsigned short* Bb = Wb + (size_t)n0 * 1024 + soff;
    int stW = wave * 512;

    f32x4 c00 = (f32x4)0.f, c01 = (f32x4)0.f, c02 = (f32x4)0.f, c03 = (f32x4)0.f;
    f32x4 c10 = (f32x4)0.f, c11 = (f32x4)0.f, c12 = (f32x4)0.f, c13 = (f32x4)0.f;

    // Single-buffer BK=64 K-loop (16 steps): cross-block TLP (6 blocks/CU)
    // hides the per-step stalls; no in-block pipeline (R20 proved it null).
    for (int kt = 0; kt < 16; ++kt) {
        int k0 = kt * 64;
        __syncthreads();
        GLOAD16(Ab + k0,          As2 + stW);
        GLOAD16(Ab + 32768 + k0,  As2 + stW + 2048);
        GLOAD16(Bb + k0,          Bs2 + stW);
        GLOAD16(Bb + 32768 + k0,  Bs2 + stW + 2048);
        GLOAD16(Bb + 65536 + k0,  Bs2 + stW + 4096);
        GLOAD16(Bb + 98304 + k0,  Bs2 + stW + 6144);
        __syncthreads();
        QKH(As2, Bs2, 0)
        QKH(As2, Bs2, 1)
    }

    __syncthreads();                    // all waves done reading As/Bs (union reuse)

    if (section == 2) {
        QVSECT_TILE(0, 0, c00) QVSECT_TILE(0, 1, c01) QVSECT_TILE(0, 2, c02) QVSECT_TILE(0, 3, c03)
        QVSECT_TILE(1, 0, c10) QVSECT_TILE(1, 1, c11) QVSECT_TILE(1, 2, c12) QVSECT_TILE(1, 3, c13)
        __syncthreads();
        // store: 128 d-rows x 64 contiguous l
        int dr = tid >> 1, hh = tid & 1;
        int h = ((n0 & 1023) >> 6) + (dr >> 6);
        int d = dr & 63;
        int mmb = rt * 64;
        int bb = mmb >> 9, ll0 = mmb & 511;
        unsigned short* orow = vo + (((size_t)bb * NHEADS + h) * HDIM + d) * SEQ + ll0 + hh * 32;
        const unsigned short* csrc = &smemq.Ct[dr * 72 + hh * 32];
        #pragma unroll
        for (int kc = 0; kc < 4; ++kc)
            *(u16x8*)(orow + kc * 8) = *(const u16x8*)(csrc + kc * 8);
        return;
    }

    float inv0 = expf(-0.2878231366f * (float)c);          // 10000^(-c/32)
    float inv1 = expf(-0.2878231366f * (float)(16 + c));
    QROPE_ROW(0, c00, c01, c02, c03)
    QROPE_ROW(1, c10, c11, c12, c13)
    __syncthreads();

    unsigned short* outp = (section == 0) ? qo : ko;
    int rr = tid >> 2;                  // row 0..63
    int ch = (tid >> 1) & 1;            // head-half 0/1
    int sub = tid & 1;                  // 32-short half within head
    int mm = rt * 64 + rr;
    int bb = mm >> 9, ll = mm & 511;
    int h = ((n0 & 1023) >> 6) + ch;
    unsigned short* orow = outp + (((size_t)bb * NHEADS + h) * SEQ + ll) * HDIM + sub * 32;
    const unsigned short* csrc = &smemq.C[rr * CSTR + ch * 64 + sub * 32];
    #pragma unroll
    for (int kc = 0; kc < 4; ++kc)
        *(u16x8*)(orow + kc * 8) = *(const u16x8*)(csrc + kc * 8);
}

// ---------------------------------------------------------------------------
// Projection 1 (MFMA, 64x128 tile, BK=128): t = att @ Wout^T + b_out -> bf16
// grid (8, 64) = 512 blocks
// ---------------------------------------------------------------------------
#define O1_REG(mb, reg, n, Acc)                                                \
    t_bf[(size_t)((mb) + (reg)) * 1024 + (n)] = f2bf(Acc[(reg)] + bo);
#define O1_TILE(i, j, Acc)                                                     \
    {                                                                          \
        int n = ct * 128 + wc * 64 + (j) * 16 + c;                             \
        float bo = b_out[n];                                                   \
        int mb = rt * 64 + wr * 32 + (i) * 16 + quad * 4;                      \
        O1_REG(mb, 0, n, Acc) O1_REG(mb, 1, n, Acc)                            \
        O1_REG(mb, 2, n, Acc) O1_REG(mb, 3, n, Acc)                            \
    }

__global__ __launch_bounds__(256, 1)
void out_gemm1_mfma(const unsigned short* __restrict__ att,
                    const unsigned short* __restrict__ Wob,
                    const float* __restrict__ b_out,
                    unsigned short* __restrict__ t_bf) {
    int ct = blockIdx.x, rt = blockIdx.y;
    __shared__ Smem64B smem2;
    unsigned short* As2 = smem2.A;
    unsigned short* Bs2 = smem2.B;
    int tid = threadIdx.x;

    GEMM_BODY_64B(att, Wob)

    O1_TILE(0, 0, c00) O1_TILE(0, 1, c01) O1_TILE(0, 2, c02) O1_TILE(0, 3, c03)
    O1_TILE(1, 0, c10) O1_TILE(1, 1, c11) O1_TILE(1, 2, c12) O1_TILE(1, 3, c13)
}

// ---------------------------------------------------------------------------
// Projection 2 (MFMA, 64x128 tile, BK=128): gz = t_bf @ Wgate^T + b_gate;
// out = sigmoid(gz)*t + (1-sigmoid)*residual   (t read back as bf16)
// ---------------------------------------------------------------------------
#define O2_REG(mb, reg, n, Acc)                                                \
    {                                                                          \
        float gz = Acc[(reg)] + bg;                                            \
        float g = 1.0f / (1.0f + expf(-gz));                                   \
        size_t idx = (size_t)((mb) + (reg)) * 1024 + (n);                      \
        float tv = bf2f(t_bf[idx]);                                            \
        float rv = residual[idx];                                              \
        out[idx] = g * tv + (1.0f - g) * rv;                                   \
    }
#define O2_TILE(i, j, Acc)                                                     \
    {                                                                          \
        int n = ct * 128 + wc * 64 + (j) * 16 + c;                             \
        float bg = b_gate[n];                                                  \
        int mb = rt * 64 + wr * 32 + (i) * 16 + quad * 4;                      \
        O2_REG(mb, 0, n, Acc) O2_REG(mb, 1, n, Acc)                            \
        O2_REG(mb, 2, n, Acc) O2_REG(mb, 3, n, Acc)                            \
    }

__global__ __launch_bounds__(256, 1)
void out_gemm2_mfma(const unsigned short* __restrict__ t_bf,
                    const unsigned short* __restrict__ Wgb,
                    const float* __restrict__ b_gate,
                    const float* __restrict__ residual,
                    float* __restrict__ out) {
    int ct = blockIdx.x, rt = blockIdx.y;
    __shared__ Smem64B smem2;
    unsigned short* As2 = smem2.A;
    unsigned short* Bs2 = smem2.B;
    int tid = threadIdx.x;

    GEMM_BODY_64B(t_bf, Wgb)

    O2_TILE(0, 0, c00) O2_TILE(0, 1, c01) O2_TILE(0, 2, c02) O2_TILE(0, 3, c03)
    O2_TILE(1, 0, c10) O2_TILE(1, 1, c11) O2_TILE(1, 2, c12) O2_TILE(1, 3, c13)
}

// ---------------------------------------------------------------------------
// Flash attention (R20), bf16 MFMA (16x16x32). 128-row Q tile, 8 waves.
// R12: unnormalized streaming softmax. R15: K/Vt via global_load_lds + XOR
// swizzle. R18: KVBLK stays 64. R20: Ks/Vs double-buffered + counted vmcnt(2)
// pipeline (raw s_barrier); Ps/lf are same-wave-ordered, unchanged.
// ---------------------------------------------------------------------------
#define KSTR 72   // Ps stride only

static __device__ __forceinline__ void attn_step(
    const unsigned short* __restrict__ KsB, const unsigned short* __restrict__ VsB,
    int kv0, const float* __restrict__ bias, unsigned short* __restrict__ Ps,
    int q0, int wb, int quad, int c, int p0, int p1,
    bf16x8 aq0, bf16x8 aq1, f32x4 (&oacc)[4], float (&lrow)[4])
{
    f32x4 sacc[4];
    #pragma unroll
    for (int nt = 0; nt < 4; ++nt) {
        const unsigned short* kbase = &KsB[(nt * 16 + c) * 64];
        bf16x8 b0 = *(const bf16x8*)(kbase + p0);
        bf16x8 b1 = *(const bf16x8*)(kbase + p1);
        f32x4 a = (f32x4)0.f;
        a = __builtin_amdgcn_mfma_f32_16x16x32_bf16(aq0, b0, a, 0, 0, 0);
        a = __builtin_amdgcn_mfma_f32_16x16x32_bf16(aq1, b1, a, 0, 0, 0);
        sacc[nt] = a;
    }
    const float* bbase = bias + (size_t)(q0 + wb + quad * 4) * 512 + kv0 + c;
    float tsum[4];
    #pragma unroll
    for (int r = 0; r < 4; ++r) tsum[r] = 0.f;
    #pragma unroll
    for (int nt = 0; nt < 4; ++nt)
        #pragma unroll
        for (int r = 0; r < 4; ++r) {
            float p = __expf(sacc[nt][r] * SCALE + bbase[(size_t)r * 512 + nt * 16]);
            tsum[r] += p;
            Ps[(wb + quad * 4 + r) * KSTR + nt * 16 + c] = f2bf(p);
        }
    #pragma unroll
    for (int r = 0; r < 4; ++r) {
        float t = tsum[r];
        t += __shfl_xor(t, 1);
        t += __shfl_xor(t, 2);
        t += __shfl_xor(t, 4);
        t += __shfl_xor(t, 8);
        lrow[r] += t;
    }
    bf16x8 pb0 = *(const bf16x8*)&Ps[(wb + c) * KSTR + quad * 8];
    bf16x8 pb1 = *(const bf16x8*)&Ps[(wb + c) * KSTR + 32 + quad * 8];
    #pragma unroll
    for (int t = 0; t < 4; ++t) {
        const unsigned short* vbase = &VsB[(t * 16 + c) * 64];
        bf16x8 a0 = *(const bf16x8*)(vbase + p0);
        bf16x8 a1 = *(const bf16x8*)(vbase + p1);
        oacc[t] = __builtin_amdgcn_mfma_f32_16x16x32_bf16(a0, pb0, oacc[t], 0, 0, 0);
        oacc[t] = __builtin_amdgcn_mfma_f32_16x16x32_bf16(a1, pb1, oacc[t], 0, 0, 0);
    }
}

// stage KV tile kvt into buffer BUF (2 loads/lane)
#define ASTAGE(BUF, kvt)                                                       \
    GLOAD16(kgb + (size_t)((kvt) * 64) * HDIM, Ks[BUF] + wave * 512);          \
    GLOAD16(vgb + (kvt) * 64, Vs[BUF] + wave * 512);

__global__ __launch_bounds__(512)
void attn_kernel(const unsigned short* __restrict__ q,
                 const unsigned short* __restrict__ k,
                 const unsigned short* __restrict__ vt,
                 const float* __restrict__ bias,
                 unsigned short* __restrict__ attended) {
    int qt = blockIdx.x, h = blockIdx.y, b = blockIdx.z;
    __shared__ unsigned short Ks[2][64 * 64];
    __shared__ unsigned short Vs[2][64 * 64];
    __shared__ unsigned short Ps[128 * KSTR];
    __shared__ float lf[128];

    int tid = threadIdx.x;
    int wave = tid >> 6, lane = tid & 63;   // wave 0..7
    int quad = lane >> 4, c = lane & 15;
    int wb = wave * 16;                     // wave's q-row base, 0..112
    size_t headbase = (((size_t)b * NHEADS + h) * SEQ) * HDIM;  // == (b*16+h)*32768
    int q0 = qt * 128;

    const unsigned short* qrow = q + headbase + (size_t)(q0 + wb + c) * HDIM;
    bf16x8 aq0 = *(const bf16x8*)(qrow + quad * 8);
    bf16x8 aq1 = *(const bf16x8*)(qrow + 32 + quad * 8);

    // staging: wave w covers rows w*8..w*8+7 (8 rows x 64 shorts = 1 GLOAD16/lane)
    int srow = wave * 8 + (lane >> 3);
    int schunk = (lane & 7) ^ (srow & 7);
    const unsigned short* kgb = k + headbase + (size_t)srow * HDIM + schunk * 8;
    const unsigned short* vgb = vt + headbase + (size_t)srow * SEQ + schunk * 8;
    int x7 = c & 7;
    int p0 = (quad ^ x7) * 8;
    int p1 = ((4 + quad) ^ x7) * 8;

    f32x4 oacc[4];
    #pragma unroll
    for (int t = 0; t < 4; ++t) oacc[t] = (f32x4)0.f;
    float lrow[4];
    #pragma unroll
    for (int r = 0; r < 4; ++r) lrow[r] = 0.f;

    // Counted-vmcnt dbuf pipeline: 8 KV tiles of 64, 2 loads/stage.
    ASTAGE(0, 0)
    ASTAGE(1, 1)
    VMW(2); RBAR();                               // tile0 ready (Q loads also drained)
    for (int kt2 = 0; kt2 < 4; ++kt2) {
        attn_step(Ks[0], Vs[0], (kt2 * 2) * 64, bias, Ps,
                  q0, wb, quad, c, p0, p1, aq0, aq1, oacc, lrow);
        RBAR();                                   // all waves done reading buf0
        if (kt2 < 3) { ASTAGE(0, kt2 * 2 + 2) VMW(2); }
        else         { VMW(0); }                  // tile7's loads must land
        RBAR();                                   // buf1 ready
        attn_step(Ks[1], Vs[1], (kt2 * 2 + 1) * 64, bias, Ps,
                  q0, wb, quad, c, p0, p1, aq0, aq1, oacc, lrow);
        RBAR();                                   // all waves done reading buf1
        if (kt2 < 3) { ASTAGE(1, kt2 * 2 + 3) VMW(2); }
        RBAR();                                   // buf0 ready (next iter)
    }

    if (c == 0) {
        f32x4 lv;
        lv[0] = lrow[0]; lv[1] = lrow[1]; lv[2] = lrow[2]; lv[3] = lrow[3];
        *(f32x4*)&lf[wb + quad * 4] = lv;
    }
    float invl = 1.0f / lf[wb + c];
    unsigned short* drow = attended + ((size_t)b * SEQ + (q0 + wb + c)) * D_MODEL + h * HDIM;
    #pragma unroll
    for (int t = 0; t < 4; ++t) {
        ushort4 o;
        o.x = f2bf(oacc[t][0] * invl);
        o.y = f2bf(oacc[t][1] * invl);
        o.z = f2bf(oacc[t][2] * invl);
        o.w = f2bf(oacc[t][3] * invl);
        *(ushort4*)(drow + t * 16 + quad * 4) = o;
    }
}

extern "C" void kernel_launch(void* const* d_in, const int* in_sizes, int n_in,
                              void* d_out, int out_size, void* d_ws, size_t ws_size,
                              hipStream_t stream) {
    const float* dec    = (const float*)d_in[0];
    const float* enc    = (const float*)d_in[1];
    const float* Wqkv   = (const float*)d_in[2];
    const float* Wout   = (const float*)d_in[3];
    const float* b_out  = (const float*)d_in[4];
    const float* Wgate  = (const float*)d_in[5];
    const float* b_gate = (const float*)d_in[6];
    const float* gamma  = (const float*)d_in[7];
    const float* beta   = (const float*)d_in[8];
    float* out = (float*)d_out;

    char* ws = (char*)d_ws;
    const size_t MB = 1024 * 1024;
    unsigned short* q_ln    = (unsigned short*)(ws + 0 * MB);
    unsigned short* kv_ln   = (unsigned short*)(ws + 8 * MB);
    unsigned short* qb      = (unsigned short*)(ws + 16 * MB);
    unsigned short* kb      = (unsigned short*)(ws + 24 * MB);
    unsigned short* vb      = (unsigned short*)(ws + 32 * MB);   // V^T (B,H,64,L)
    unsigned short* Wqkv_bf = (unsigned short*)(ws + 40 * MB);
    float*          bias    = (float*)(ws + 46 * MB);
    unsigned short* att     = (unsigned short*)(ws + 0 * MB);    // q_ln dead after qkv
    unsigned short* t_bf    = (unsigned short*)(ws + 24 * MB);   // kb dead after attn

    // Hoisted weight-convert needs 4 MB of never-aliased space at 47..51 MB.
    bool hoist = (ws_size >= 51 * MB);
    unsigned short* Wout_bf  = (unsigned short*)(ws + (hoist ? 47 * MB : 32 * MB));
    unsigned short* Wgate_bf = (unsigned short*)(ws + (hoist ? 49 * MB : 34 * MB));

    prep_kernel<<<hoist ? 14336 : 12288, 256, 0, stream>>>(
        dec, enc, gamma, beta, Wqkv, Wout, Wgate,
        q_ln, kv_ln, bias, Wqkv_bf, Wout_bf, Wgate_bf);
    qkv_gemm_mfma<<<1536, 256, 0, stream>>>(q_ln, kv_ln, Wqkv_bf, qb, kb, vb);
    attn_kernel<<<dim3(4, 16, 8), 512, 0, stream>>>(qb, kb, vb, bias, att);
    if (!hoist)
        convert_og<<<2048, 256, 0, stream>>>(Wout, Wgate, Wout_bf, Wgate_bf);
    out_gemm1_mfma<<<dim3(8, 64), 256, 0, stream>>>(att, Wout_bf, b_out, t_bf);
    out_gemm2_mfma<<<dim3(8, 64), 256, 0, stream>>>(t_bf, Wgate_bf, b_gate, dec, out);
}

// Round 9
// 203.051 us; speedup vs baseline: 1.8504x; 1.0235x over previous
//
#include <hip/hip_runtime.h>
#include <hip/hip_bf16.h>

#define D_MODEL 1024
#define NHEADS 16
#define HDIM 64
#define BATCH 8
#define SEQ 512
#define NROWS 4096          // BATCH*SEQ
#define SCALE 0.125f
#define LN_EPS 1e-5f

typedef __attribute__((ext_vector_type(8))) short bf16x8;      // 8 bf16 (4 VGPRs)
typedef __attribute__((ext_vector_type(4))) float f32x4;
typedef __attribute__((ext_vector_type(8))) unsigned short u16x8;

static __device__ __forceinline__ float bf2f(unsigned short u) {
    return __uint_as_float(((unsigned int)u) << 16);
}
static __device__ __forceinline__ unsigned short f2bf(float f) {
    unsigned int x = __float_as_uint(f);
    unsigned int r = (x + 0x7fffu + ((x >> 16) & 1u)) >> 16;   // RNE
    return (unsigned short)r;
}

// async 16B/lane global->LDS DMA; LDS dest = wave-uniform base + lane*16
#define GLOAD16(gp, lp)                                                        \
    __builtin_amdgcn_global_load_lds(                                          \
        (const __attribute__((address_space(1))) void*)(gp),                   \
        (__attribute__((address_space(3))) void*)(lp), 16, 0, 0)

// R20: counted-vmcnt pipeline primitives (kept for attn).
#define VMW(n) asm volatile("s_waitcnt vmcnt(" #n ")" ::: "memory")
#define RBAR() __builtin_amdgcn_s_barrier()

// ---------------------------------------------------------------------------
// Bias helper: jax.image.resize(bias128, (512,512), 'bilinear')
// ---------------------------------------------------------------------------
static __device__ __forceinline__ float bias128(int a, int b) {
    float d = fabsf((float)(a - b));
    return expf(-d * 0.1f) - d * 0.05f;
}

// ---------------------------------------------------------------------------
// prep_kernel (R22): LN wave-per-row (blocks 0..2047, 4 rows/block, NO
// barriers/LDS) + bias (2048..3071) + Wqkv convert (3072..6143) +
// [hoisted Wout/Wgate convert (6144..8191)]
// ---------------------------------------------------------------------------
__global__ void prep_kernel(const float* __restrict__ dec, const float* __restrict__ enc,
                            const float* __restrict__ gamma, const float* __restrict__ beta,
                            const float* __restrict__ Wqkv,
                            const float* __restrict__ Wout, const float* __restrict__ Wgate,
                            unsigned short* __restrict__ q_ln, unsigned short* __restrict__ kv_ln,
                            float* __restrict__ bias, unsigned short* __restrict__ Wqkv_bf,
                            unsigned short* __restrict__ Wout_bf, unsigned short* __restrict__ Wgate_bf) {
    int blk = blockIdx.x;
    int t = threadIdx.x;
    if (blk >= 6144) {          // hoisted Wout/Wgate convert (only when launched)
        int idx = (blk - 6144) * 256 + t;
        const float* src; unsigned short* dst; int off;
        if (idx < 262144) { src = Wout; dst = Wout_bf; off = idx; }
        else              { src = Wgate; dst = Wgate_bf; off = idx - 262144; }
        float4 v = ((const float4*)src)[off];
        ushort4 u;
        u.x = f2bf(v.x); u.y = f2bf(v.y); u.z = f2bf(v.z); u.w = f2bf(v.w);
        ((ushort4*)dst)[off] = u;
        return;
    }
    if (blk >= 3072) {          // Wqkv convert
        int idx = (blk - 3072) * 256 + t;
        float4 v = ((const float4*)Wqkv)[idx];
        ushort4 u;
        u.x = f2bf(v.x); u.y = f2bf(v.y); u.z = f2bf(v.z); u.w = f2bf(v.w);
        ((ushort4*)Wqkv_bf)[idx] = u;
        return;
    }
    if (blk >= 2048) {          // bias
        int idx = (blk - 2048) * 256 + t;
        int qi = idx >> 9, kj = idx & 511;
        float fq = (qi + 0.5f) * 0.25f - 0.5f;
        float fk = (kj + 0.5f) * 0.25f - 0.5f;
        int iq = (int)floorf(fq); float tq = fq - (float)iq;
        int ik = (int)floorf(fk); float tk = fk - (float)ik;
        int iq0 = min(max(iq, 0), 127), iq1 = min(max(iq + 1, 0), 127);
        int ik0 = min(max(ik, 0), 127), ik1 = min(max(ik + 1, 0), 127);
        float v = (1.f - tq) * ((1.f - tk) * bias128(iq0, ik0) + tk * bias128(iq0, ik1))
                +        tq  * ((1.f - tk) * bias128(iq1, ik0) + tk * bias128(iq1, ik1));
        bias[idx] = v;
        return;
    }
    // LN: wave-per-row, shuffle-only reduction (R22)
    int row = blk * 4 + (t >> 6);
    int lane = t & 63;
    const float* src = (row < NROWS) ? dec + (size_t)row * D_MODEL
                                     : enc + (size_t)(row - NROWS) * D_MODEL;
    unsigned short* dst = (row < NROWS) ? q_ln + (size_t)row * D_MODEL
                                        : kv_ln + (size_t)(row - NROWS) * D_MODEL;
    float4 x0 = ((const float4*)src)[lane];
    float4 x1 = ((const float4*)src)[lane + 64];
    float4 x2 = ((const float4*)src)[lane + 128];
    float4 x3 = ((const float4*)src)[lane + 192];
    float s  = x0.x + x0.y + x0.z + x0.w + x1.x + x1.y + x1.z + x1.w
             + x2.x + x2.y + x2.z + x2.w + x3.x + x3.y + x3.z + x3.w;
    float ss = x0.x * x0.x + x0.y * x0.y + x0.z * x0.z + x0.w * x0.w
             + x1.x * x1.x + x1.y * x1.y + x1.z * x1.z + x1.w * x1.w
             + x2.x * x2.x + x2.y * x2.y + x2.z * x2.z + x2.w * x2.w
             + x3.x * x3.x + x3.y * x3.y + x3.z * x3.z + x3.w * x3.w;
    #pragma unroll
    for (int off = 32; off > 0; off >>= 1) {
        s  += __shfl_down(s, off);
        ss += __shfl_down(ss, off);
    }
    s  = __shfl(s, 0);
    ss = __shfl(ss, 0);
    float mu  = s * (1.0f / 1024.0f);
    float var = ss * (1.0f / 1024.0f) - mu * mu;
    float rstd = rsqrtf(var + LN_EPS);
    #pragma unroll
    for (int j = 0; j < 4; ++j) {
        float4 xv = (j == 0) ? x0 : (j == 1) ? x1 : (j == 2) ? x2 : x3;
        float4 g  = ((const float4*)gamma)[lane + j * 64];
        float4 bb = ((const float4*)beta)[lane + j * 64];
        ushort4 u;
        u.x = f2bf((xv.x - mu) * rstd * g.x + bb.x);
        u.y = f2bf((xv.y - mu) * rstd * g.y + bb.y);
        u.z = f2bf((xv.z - mu) * rstd * g.z + bb.z);
        u.w = f2bf((xv.w - mu) * rstd * g.w + bb.w);
        ((ushort4*)dst)[lane + j * 64] = u;
    }
}

// ---------------------------------------------------------------------------
// Wout + Wgate fp32 -> bf16 (fallback path when ws too small to hoist)
// ---------------------------------------------------------------------------
__global__ void convert_og(const float* __restrict__ Wout, const float* __restrict__ Wgate,
                           unsigned short* __restrict__ Wout_bf, unsigned short* __restrict__ Wgate_bf) {
    int idx = blockIdx.x * 256 + threadIdx.x;
    const float* src; unsigned short* dst; int off;
    if (idx < 262144) { src = (const float*)Wout; dst = Wout_bf; off = idx; }
    else              { src = (const float*)Wgate; dst = Wgate_bf; off = idx - 262144; }
    float4 v = ((const float4*)src)[off];
    ushort4 u;
    u.x = f2bf(v.x); u.y = f2bf(v.y); u.z = f2bf(v.z); u.w = f2bf(v.w);
    ((ushort4*)dst)[off] = u;
}

// ===========================================================================
// MFMA GEMM cores (bf16). Permanent lessons:
// R7/R16: accumulators and frags NAMED scalars (arrays spill to scratch).
// R9: global_load_lds + XOR swizzle (0 conflicts).
// R17: 128^2 tile latency-bound at K=1024. R18: attn KVBLK=128 regressed.
// R19: XCD ct-major swizzle: FETCH 73->30MB. R20 NULL: counted-vmcnt == drain0
// on qkv (in-block pipelining not the limiter). R21 WIN: qkv LDS 48->24KB,
// 6 blocks/CU: occupancy 22.6->41%, dur 49.2->44.0 (-11%).
// R22 (this round): same occupancy mechanism on out_gemm1/2 (2 blocks/CU was
// the worst in the stack): 64x64 tile, BK=64 single-buffer 16KB LDS, grid
// 1024 = 4 blocks/CU, XCD-contiguous swizzle. prep LN -> wave-per-row.
// ===========================================================================
#define CSTR 136   // C-bounce row stride (multiple of 8 -> 16B-aligned rows)

#define MF(a, b, d) __builtin_amdgcn_mfma_f32_16x16x32_bf16((a), (b), (d), 0, 0, 0)

// ---------------------------------------------------------------------------
// QKV GEMM (R21): 64x128 tile, BK=64 SINGLE-buffer (24 KB LDS -> 6 blocks/CU),
// fused RoPE. Q/K: (B,H,L,64). V: transposed (B,H,64,L) (R15).
// Grid 1536: XCD-contiguous swizzle, ct-major super-tiles (8ct x 4rt).
// ---------------------------------------------------------------------------
union alignas(16) SmemQS {
    struct { unsigned short A[64 * 64]; unsigned short B[128 * 64]; } ab;  // 24 KB
    unsigned short C[64 * CSTR];    // q/k bounce: 64 rows x 136 (17.4 KB)
    unsigned short Ct[128 * 72];    // v bounce (transposed): 128 d-rows x 72 (18.4 KB)
};

// one K-half (K=32) of a BK=64 step: 6 frag loads + 8 MFMA
#define QKH(pA, pB, kh)                                                        \
    {                                                                          \
        int pofs = (((kh) * 4 + quad) ^ x7) * 8;                               \
        const unsigned short* Ar_ = (pA) + (wr * 32 + c) * 64 + pofs;          \
        const unsigned short* Br_ = (pB) + (wc * 64 + c) * 64 + pofs;          \
        bf16x8 f0 = *(const bf16x8*)(Ar_);                                     \
        bf16x8 f1 = *(const bf16x8*)(Ar_ + 1024);                              \
        bf16x8 g0 = *(const bf16x8*)(Br_);                                     \
        bf16x8 g1 = *(const bf16x8*)(Br_ + 1024);                              \
        bf16x8 g2 = *(const bf16x8*)(Br_ + 2048);                              \
        bf16x8 g3 = *(const bf16x8*)(Br_ + 3072);                              \
        c00 = MF(f0, g0, c00); c01 = MF(f0, g1, c01); c02 = MF(f0, g2, c02); c03 = MF(f0, g3, c03); \
        c10 = MF(f1, g0, c10); c11 = MF(f1, g1, c11); c12 = MF(f1, g2, c12); c13 = MF(f1, g3, c13); \
    }

#define QROPE_REG(i, reg, A0, A1, A2, A3)                                      \
    {                                                                          \
        int mloc = wr * 32 + (i) * 16 + quad * 4 + (reg);                      \
        int crow = mloc * CSTR + wc * 64;                                      \
        float fl = (float)((rt * 64 + mloc) & 511);                            \
        float aa0 = fl * inv0, aa1 = fl * inv1;                                \
        float c0 = cosf(aa0), s0 = sinf(aa0);                                  \
        float c1 = cosf(aa1), s1 = sinf(aa1);                                  \
        float e0 = A0[(reg)], o0 = A2[(reg)];                                  \
        float e1 = A1[(reg)], o1 = A3[(reg)];                                  \
        smemq.C[crow + c]      = f2bf(e0 * c0 - o0 * s0);                      \
        smemq.C[crow + 32 + c] = f2bf(e0 * s0 + o0 * c0);                      \
        smemq.C[crow + 16 + c] = f2bf(e1 * c1 - o1 * s1);                      \
        smemq.C[crow + 48 + c] = f2bf(e1 * s1 + o1 * c1);                      \
    }
#define QROPE_ROW(i, A0, A1, A2, A3)                                           \
    QROPE_REG(i, 0, A0, A1, A2, A3) QROPE_REG(i, 1, A0, A1, A2, A3)            \
    QROPE_REG(i, 2, A0, A1, A2, A3) QROPE_REG(i, 3, A0, A1, A2, A3)

// V: bounce transposed — Ct[dcol][l_local], stride 72
#define QVSECT_REG(i, j, reg, Acc)                                             \
    smemq.Ct[(wc * 64 + (j) * 16 + c) * 72 + (wr * 32 + (i) * 16 + quad * 4 + (reg))] = f2bf(Acc[(reg)]);
#define QVSECT_TILE(i, j, Acc)                                                 \
    QVSECT_REG(i, j, 0, Acc) QVSECT_REG(i, j, 1, Acc)                          \
    QVSECT_REG(i, j, 2, Acc) QVSECT_REG(i, j, 3, Acc)

__global__ __launch_bounds__(256, 6)
void qkv_gemm_mfma(const unsigned short* __restrict__ q_ln,
                   const unsigned short* __restrict__ kv_ln,
                   const unsigned short* __restrict__ Wb,
                   unsigned short* __restrict__ qo,
                   unsigned short* __restrict__ ko,
                   unsigned short* __restrict__ vo) {
    int bid = blockIdx.x;                     // 0..1535
    int wg = (bid & 7) * 192 + (bid >> 3);    // XCD-contiguous (bijective, 1536%8==0)
    int st = wg >> 5, in = wg & 31;           // 48 super-tiles of 32 blocks
    int stc = st >> 4, str = st & 15;         // ct-major: stc 0..2 (= section), str 0..15
    int ct = stc * 8 + (in & 7);              // 0..23
    int rt = str * 4 + (in >> 3);             // 0..63
    int n0 = ct * 128;
    int section = stc;                        // 0=q 1=k 2=v
    const unsigned short* A = (section == 0) ? q_ln : kv_ln;

    __shared__ SmemQS smemq;
    unsigned short* As2 = smemq.ab.A;
    unsigned short* Bs2 = smemq.ab.B;
    int tid = threadIdx.x;
    int wave = tid >> 6, lane = tid & 63, quad = lane >> 4, c = lane & 15;
    int wr = wave >> 1, wc = wave & 1;
    int x7 = c & 7;

    // staging source: thread t covers row t>>3, slot t&7 holds chunk (t&7)^((t>>3)&7)
    int soff = (tid >> 3) * 1024 + (((tid & 7) ^ ((tid >> 3) & 7)) * 8);
    const unsigned short* Ab = A + (size_t)(rt * 64) * 1024 + soff;
    const unsigned short* Bb = Wb + (size_t)n0 * 1024 + soff;
    int stW = wave * 512;

    f32x4 c00 = (f32x4)0.f, c01 = (f32x4)0.f, c02 = (f32x4)0.f, c03 = (f32x4)0.f;
    f32x4 c10 = (f32x4)0.f, c11 = (f32x4)0.f, c12 = (f32x4)0.f, c13 = (f32x4)0.f;

    // Single-buffer BK=64 K-loop (16 steps): cross-block TLP (6 blocks/CU)
    // hides the per-step stalls; no in-block pipeline (R20 proved it null).
    for (int kt = 0; kt < 16; ++kt) {
        int k0 = kt * 64;
        __syncthreads();
        GLOAD16(Ab + k0,          As2 + stW);
        GLOAD16(Ab + 32768 + k0,  As2 + stW + 2048);
        GLOAD16(Bb + k0,          Bs2 + stW);
        GLOAD16(Bb + 32768 + k0,  Bs2 + stW + 2048);
        GLOAD16(Bb + 65536 + k0,  Bs2 + stW + 4096);
        GLOAD16(Bb + 98304 + k0,  Bs2 + stW + 6144);
        __syncthreads();
        QKH(As2, Bs2, 0)
        QKH(As2, Bs2, 1)
    }

    __syncthreads();                    // all waves done reading As/Bs (union reuse)

    if (section == 2) {
        QVSECT_TILE(0, 0, c00) QVSECT_TILE(0, 1, c01) QVSECT_TILE(0, 2, c02) QVSECT_TILE(0, 3, c03)
        QVSECT_TILE(1, 0, c10) QVSECT_TILE(1, 1, c11) QVSECT_TILE(1, 2, c12) QVSECT_TILE(1, 3, c13)
        __syncthreads();
        // store: 128 d-rows x 64 contiguous l
        int dr = tid >> 1, hh = tid & 1;
        int h = ((n0 & 1023) >> 6) + (dr >> 6);
        int d = dr & 63;
        int mmb = rt * 64;
        int bb = mmb >> 9, ll0 = mmb & 511;
        unsigned short* orow = vo + (((size_t)bb * NHEADS + h) * HDIM + d) * SEQ + ll0 + hh * 32;
        const unsigned short* csrc = &smemq.Ct[dr * 72 + hh * 32];
        #pragma unroll
        for (int kc = 0; kc < 4; ++kc)
            *(u16x8*)(orow + kc * 8) = *(const u16x8*)(csrc + kc * 8);
        return;
    }

    float inv0 = expf(-0.2878231366f * (float)c);          // 10000^(-c/32)
    float inv1 = expf(-0.2878231366f * (float)(16 + c));
    QROPE_ROW(0, c00, c01, c02, c03)
    QROPE_ROW(1, c10, c11, c12, c13)
    __syncthreads();

    unsigned short* outp = (section == 0) ? qo : ko;
    int rr = tid >> 2;                  // row 0..63
    int ch = (tid >> 1) & 1;            // head-half 0/1
    int sub = tid & 1;                  // 32-short half within head
    int mm = rt * 64 + rr;
    int bb = mm >> 9, ll = mm & 511;
    int h = ((n0 & 1023) >> 6) + ch;
    unsigned short* orow = outp + (((size_t)bb * NHEADS + h) * SEQ + ll) * HDIM + sub * 32;
    const unsigned short* csrc = &smemq.C[rr * CSTR + ch * 64 + sub * 32];
    #pragma unroll
    for (int kc = 0; kc < 4; ++kc)
        *(u16x8*)(orow + kc * 8) = *(const u16x8*)(csrc + kc * 8);
}

// ---------------------------------------------------------------------------
// Out-projection GEMMs (R22): 64x64 tile, BK=64 single-buffer (16 KB LDS),
// grid 1024 (1-D, XCD-contiguous swizzle: XCD x gets rt in [x*8,(x+1)*8),
// per-XCD set = 1 MB A + 2 MB B <= 4 MB L2). 4 blocks/CU (was 2).
// Wave tile 32x32 (2x2 16x16 frags, named c00..c11 per R7/R16).
// ---------------------------------------------------------------------------
struct alignas(16) SmemOG {
    unsigned short A[64 * 64];      // 8 KB
    unsigned short B[64 * 64];      // 8 KB
};

#define OG_KH(kh)                                                              \
    {                                                                          \
        int pofs = (((kh) * 4 + quad) ^ x7) * 8;                               \
        const unsigned short* Ar_ = smemog.A + (wr * 32 + c) * 64 + pofs;      \
        const unsigned short* Br_ = smemog.B + (wc * 32 + c) * 64 + pofs;      \
        bf16x8 f0 = *(const bf16x8*)(Ar_);                                     \
        bf16x8 f1 = *(const bf16x8*)(Ar_ + 1024);                              \
        bf16x8 g0 = *(const bf16x8*)(Br_);                                     \
        bf16x8 g1 = *(const bf16x8*)(Br_ + 1024);                              \
        c00 = MF(f0, g0, c00); c01 = MF(f0, g1, c01);                          \
        c10 = MF(f1, g0, c10); c11 = MF(f1, g1, c11);                          \
    }

#define OG_BODY(Aptr, Bptr)                                                    \
    int bid = blockIdx.x;                     /* 0..1023 */                    \
    int wg = (bid & 7) * 128 + (bid >> 3);    /* XCD-contiguous, bijective */  \
    int ct = wg & 15, rt = wg >> 4;                                            \
    int tid = threadIdx.x;                                                     \
    int wave = tid >> 6, lane = tid & 63, quad = lane >> 4, c = lane & 15;     \
    int wr = wave >> 1, wc = wave & 1;                                         \
    int x7 = c & 7;                                                            \
    int soff = (tid >> 3) * 1024 + (((tid & 7) ^ ((tid >> 3) & 7)) * 8);       \
    const unsigned short* Ab = (Aptr) + (size_t)(rt * 64) * 1024 + soff;       \
    const unsigned short* Bb = (Bptr) + (size_t)(ct * 64) * 1024 + soff;       \
    int stW = wave * 512;                                                      \
    f32x4 c00 = (f32x4)0.f, c01 = (f32x4)0.f;                                  \
    f32x4 c10 = (f32x4)0.f, c11 = (f32x4)0.f;                                  \
    for (int kt = 0; kt < 16; ++kt) {                                          \
        int k0 = kt * 64;                                                      \
        __syncthreads();                                                       \
        GLOAD16(Ab + k0,          smemog.A + stW);                             \
        GLOAD16(Ab + 32768 + k0,  smemog.A + stW + 2048);                      \
        GLOAD16(Bb + k0,          smemog.B + stW);                             \
        GLOAD16(Bb + 32768 + k0,  smemog.B + stW + 2048);                      \
        __syncthreads();                                                       \
        OG_KH(0)                                                               \
        OG_KH(1)                                                               \
    }

#define O1_REG(mb, reg, n, Acc)                                                \
    t_bf[(size_t)((mb) + (reg)) * 1024 + (n)] = f2bf(Acc[(reg)] + bo);
#define O1_TILE(i, j, Acc)                                                     \
    {                                                                          \
        int n = ct * 64 + wc * 32 + (j) * 16 + c;                              \
        float bo = b_out[n];                                                   \
        int mb = rt * 64 + wr * 32 + (i) * 16 + quad * 4;                      \
        O1_REG(mb, 0, n, Acc) O1_REG(mb, 1, n, Acc)                            \
        O1_REG(mb, 2, n, Acc) O1_REG(mb, 3, n, Acc)                            \
    }

__global__ __launch_bounds__(256, 4)
void out_gemm1_mfma(const unsigned short* __restrict__ att,
                    const unsigned short* __restrict__ Wob,
                    const float* __restrict__ b_out,
                    unsigned short* __restrict__ t_bf) {
    __shared__ SmemOG smemog;
    OG_BODY(att, Wob)
    O1_TILE(0, 0, c00) O1_TILE(0, 1, c01)
    O1_TILE(1, 0, c10) O1_TILE(1, 1, c11)
}

#define O2_REG(mb, reg, n, Acc)                                                \
    {                                                                          \
        float gz = Acc[(reg)] + bg;                                            \
        float g = 1.0f / (1.0f + expf(-gz));                                   \
        size_t idx = (size_t)((mb) + (reg)) * 1024 + (n);                      \
        float tv = bf2f(t_bf[idx]);                                            \
        float rv = residual[idx];                                              \
        out[idx] = g * tv + (1.0f - g) * rv;                                   \
    }
#define O2_TILE(i, j, Acc)                                                     \
    {                                                                          \
        int n = ct * 64 + wc * 32 + (j) * 16 + c;                              \
        float bg = b_gate[n];                                                  \
        int mb = rt * 64 + wr * 32 + (i) * 16 + quad * 4;                      \
        O2_REG(mb, 0, n, Acc) O2_REG(mb, 1, n, Acc)                            \
        O2_REG(mb, 2, n, Acc) O2_REG(mb, 3, n, Acc)                            \
    }

__global__ __launch_bounds__(256, 4)
void out_gemm2_mfma(const unsigned short* __restrict__ t_bf,
                    const unsigned short* __restrict__ Wgb,
                    const float* __restrict__ b_gate,
                    const float* __restrict__ residual,
                    float* __restrict__ out) {
    __shared__ SmemOG smemog;
    OG_BODY(t_bf, Wgb)
    O2_TILE(0, 0, c00) O2_TILE(0, 1, c01)
    O2_TILE(1, 0, c10) O2_TILE(1, 1, c11)
}

// ---------------------------------------------------------------------------
// Flash attention (R20), bf16 MFMA (16x16x32). 128-row Q tile, 8 waves.
// R12: unnormalized streaming softmax. R15: K/Vt via global_load_lds + XOR
// swizzle. R18: KVBLK stays 64. R20: Ks/Vs double-buffered + counted vmcnt(2)
// pipeline (raw s_barrier); Ps/lf are same-wave-ordered, unchanged.
// ---------------------------------------------------------------------------
#define KSTR 72   // Ps stride only

static __device__ __forceinline__ void attn_step(
    const unsigned short* __restrict__ KsB, const unsigned short* __restrict__ VsB,
    int kv0, const float* __restrict__ bias, unsigned short* __restrict__ Ps,
    int q0, int wb, int quad, int c, int p0, int p1,
    bf16x8 aq0, bf16x8 aq1, f32x4 (&oacc)[4], float (&lrow)[4])
{
    f32x4 sacc[4];
    #pragma unroll
    for (int nt = 0; nt < 4; ++nt) {
        const unsigned short* kbase = &KsB[(nt * 16 + c) * 64];
        bf16x8 b0 = *(const bf16x8*)(kbase + p0);
        bf16x8 b1 = *(const bf16x8*)(kbase + p1);
        f32x4 a = (f32x4)0.f;
        a = __builtin_amdgcn_mfma_f32_16x16x32_bf16(aq0, b0, a, 0, 0, 0);
        a = __builtin_amdgcn_mfma_f32_16x16x32_bf16(aq1, b1, a, 0, 0, 0);
        sacc[nt] = a;
    }
    const float* bbase = bias + (size_t)(q0 + wb + quad * 4) * 512 + kv0 + c;
    float tsum[4];
    #pragma unroll
    for (int r = 0; r < 4; ++r) tsum[r] = 0.f;
    #pragma unroll
    for (int nt = 0; nt < 4; ++nt)
        #pragma unroll
        for (int r = 0; r < 4; ++r) {
            float p = __expf(sacc[nt][r] * SCALE + bbase[(size_t)r * 512 + nt * 16]);
            tsum[r] += p;
            Ps[(wb + quad * 4 + r) * KSTR + nt * 16 + c] = f2bf(p);
        }
    #pragma unroll
    for (int r = 0; r < 4; ++r) {
        float t = tsum[r];
        t += __shfl_xor(t, 1);
        t += __shfl_xor(t, 2);
        t += __shfl_xor(t, 4);
        t += __shfl_xor(t, 8);
        lrow[r] += t;
    }
    bf16x8 pb0 = *(const bf16x8*)&Ps[(wb + c) * KSTR + quad * 8];
    bf16x8 pb1 = *(const bf16x8*)&Ps[(wb + c) * KSTR + 32 + quad * 8];
    #pragma unroll
    for (int t = 0; t < 4; ++t) {
        const unsigned short* vbase = &VsB[(t * 16 + c) * 64];
        bf16x8 a0 = *(const bf16x8*)(vbase + p0);
        bf16x8 a1 = *(const bf16x8*)(vbase + p1);
        oacc[t] = __builtin_amdgcn_mfma_f32_16x16x32_bf16(a0, pb0, oacc[t], 0, 0, 0);
        oacc[t] = __builtin_amdgcn_mfma_f32_16x16x32_bf16(a1, pb1, oacc[t], 0, 0, 0);
    }
}

// stage KV tile kvt into buffer BUF (2 loads/lane)
#define ASTAGE(BUF, kvt)                                                       \
    GLOAD16(kgb + (size_t)((kvt) * 64) * HDIM, Ks[BUF] + wave * 512);          \
    GLOAD16(vgb + (kvt) * 64, Vs[BUF] + wave * 512);

__global__ __launch_bounds__(512)
void attn_kernel(const unsigned short* __restrict__ q,
                 const unsigned short* __restrict__ k,
                 const unsigned short* __restrict__ vt,
                 const float* __restrict__ bias,
                 unsigned short* __restrict__ attended) {
    int qt = blockIdx.x, h = blockIdx.y, b = blockIdx.z;
    __shared__ unsigned short Ks[2][64 * 64];
    __shared__ unsigned short Vs[2][64 * 64];
    __shared__ unsigned short Ps[128 * KSTR];
    __shared__ float lf[128];

    int tid = threadIdx.x;
    int wave = tid >> 6, lane = tid & 63;   // wave 0..7
    int quad = lane >> 4, c = lane & 15;
    int wb = wave * 16;                     // wave's q-row base, 0..112
    size_t headbase = (((size_t)b * NHEADS + h) * SEQ) * HDIM;  // == (b*16+h)*32768
    int q0 = qt * 128;

    const unsigned short* qrow = q + headbase + (size_t)(q0 + wb + c) * HDIM;
    bf16x8 aq0 = *(const bf16x8*)(qrow + quad * 8);
    bf16x8 aq1 = *(const bf16x8*)(qrow + 32 + quad * 8);

    // staging: wave w covers rows w*8..w*8+7 (8 rows x 64 shorts = 1 GLOAD16/lane)
    int srow = wave * 8 + (lane >> 3);
    int schunk = (lane & 7) ^ (srow & 7);
    const unsigned short* kgb = k + headbase + (size_t)srow * HDIM + schunk * 8;
    const unsigned short* vgb = vt + headbase + (size_t)srow * SEQ + schunk * 8;
    int x7 = c & 7;
    int p0 = (quad ^ x7) * 8;
    int p1 = ((4 + quad) ^ x7) * 8;

    f32x4 oacc[4];
    #pragma unroll
    for (int t = 0; t < 4; ++t) oacc[t] = (f32x4)0.f;
    float lrow[4];
    #pragma unroll
    for (int r = 0; r < 4; ++r) lrow[r] = 0.f;

    // Counted-vmcnt dbuf pipeline: 8 KV tiles of 64, 2 loads/stage.
    ASTAGE(0, 0)
    ASTAGE(1, 1)
    VMW(2); RBAR();                               // tile0 ready (Q loads also drained)
    for (int kt2 = 0; kt2 < 4; ++kt2) {
        attn_step(Ks[0], Vs[0], (kt2 * 2) * 64, bias, Ps,
                  q0, wb, quad, c, p0, p1, aq0, aq1, oacc, lrow);
        RBAR();                                   // all waves done reading buf0
        if (kt2 < 3) { ASTAGE(0, kt2 * 2 + 2) VMW(2); }
        else         { VMW(0); }                  // tile7's loads must land
        RBAR();                                   // buf1 ready
        attn_step(Ks[1], Vs[1], (kt2 * 2 + 1) * 64, bias, Ps,
                  q0, wb, quad, c, p0, p1, aq0, aq1, oacc, lrow);
        RBAR();                                   // all waves done reading buf1
        if (kt2 < 3) { ASTAGE(1, kt2 * 2 + 3) VMW(2); }
        RBAR();                                   // buf0 ready (next iter)
    }

    if (c == 0) {
        f32x4 lv;
        lv[0] = lrow[0]; lv[1] = lrow[1]; lv[2] = lrow[2]; lv[3] = lrow[3];
        *(f32x4*)&lf[wb + quad * 4] = lv;
    }
    float invl = 1.0f / lf[wb + c];
    unsigned short* drow = attended + ((size_t)b * SEQ + (q0 + wb + c)) * D_MODEL + h * HDIM;
    #pragma unroll
    for (int t = 0; t < 4; ++t) {
        ushort4 o;
        o.x = f2bf(oacc[t][0] * invl);
        o.y = f2bf(oacc[t][1] * invl);
        o.z = f2bf(oacc[t][2] * invl);
        o.w = f2bf(oacc[t][3] * invl);
        *(ushort4*)(drow + t * 16 + quad * 4) = o;
    }
}

extern "C" void kernel_launch(void* const* d_in, const int* in_sizes, int n_in,
                              void* d_out, int out_size, void* d_ws, size_t ws_size,
                              hipStream_t stream) {
    const float* dec    = (const float*)d_in[0];
    const float* enc    = (const float*)d_in[1];
    const float* Wqkv   = (const float*)d_in[2];
    const float* Wout   = (const float*)d_in[3];
    const float* b_out  = (const float*)d_in[4];
    const float* Wgate  = (const float*)d_in[5];
    const float* b_gate = (const float*)d_in[6];
    const float* gamma  = (const float*)d_in[7];
    const float* beta   = (const float*)d_in[8];
    float* out = (float*)d_out;

    char* ws = (char*)d_ws;
    const size_t MB = 1024 * 1024;
    unsigned short* q_ln    = (unsigned short*)(ws + 0 * MB);
    unsigned short* kv_ln   = (unsigned short*)(ws + 8 * MB);
    unsigned short* qb      = (unsigned short*)(ws + 16 * MB);
    unsigned short* kb      = (unsigned short*)(ws + 24 * MB);
    unsigned short* vb      = (unsigned short*)(ws + 32 * MB);   // V^T (B,H,64,L)
    unsigned short* Wqkv_bf = (unsigned short*)(ws + 40 * MB);
    float*          bias    = (float*)(ws + 46 * MB);
    unsigned short* att     = (unsigned short*)(ws + 0 * MB);    // q_ln dead after qkv
    unsigned short* t_bf    = (unsigned short*)(ws + 24 * MB);   // kb dead after attn

    // Hoisted weight-convert needs 4 MB of never-aliased space at 47..51 MB.
    bool hoist = (ws_size >= 51 * MB);
    unsigned short* Wout_bf  = (unsigned short*)(ws + (hoist ? 47 * MB : 32 * MB));
    unsigned short* Wgate_bf = (unsigned short*)(ws + (hoist ? 49 * MB : 34 * MB));

    prep_kernel<<<hoist ? 8192 : 6144, 256, 0, stream>>>(
        dec, enc, gamma, beta, Wqkv, Wout, Wgate,
        q_ln, kv_ln, bias, Wqkv_bf, Wout_bf, Wgate_bf);
    qkv_gemm_mfma<<<1536, 256, 0, stream>>>(q_ln, kv_ln, Wqkv_bf, qb, kb, vb);
    attn_kernel<<<dim3(4, 16, 8), 512, 0, stream>>>(qb, kb, vb, bias, att);
    if (!hoist)
        convert_og<<<2048, 256, 0, stream>>>(Wout, Wgate, Wout_bf, Wgate_bf);
    out_gemm1_mfma<<<1024, 256, 0, stream>>>(att, Wout_bf, b_out, t_bf);
    out_gemm2_mfma<<<1024, 256, 0, stream>>>(t_bf, Wgate_bf, b_gate, dec, out);
}